// Round 3
// baseline (3381.361 us; speedup 1.0000x reference)
//
#include <hip/hip_runtime.h>
#include <cmath>

#define NB   8
#define NPG  128
#define NN   1024
#define KNB  64
#define HD   600
#define GG   50
#define LL   6
#define EE   (NN*KNB)     // 65536 edges
#define CHN  256          // nodes per chunk
#define CHE  (CHN*KNB)    // 16384 edges per chunk
#define WROW 640          // padded weight rows (n)
#define WCOL 608          // padded weight cols (k)

typedef __attribute__((ext_vector_type(8))) short short8;
typedef __attribute__((ext_vector_type(4))) float f32x4;

__device__ __forceinline__ short f2b(float f) {
  union { float f; unsigned u; } v; v.f = f;
  unsigned u = v.u;
  u += 0x7fffu + ((u >> 16) & 1u);
  return (short)(u >> 16);
}

__device__ __forceinline__ float sspf(float x) {
  float sp = (x > 20.0f) ? x : log1pf(expf(x));
  return sp - 0.69314718055994531f;
}

// ---------------- graph build: one block per node ----------------
__global__ __launch_bounds__(128) void build_graph_k(const float* __restrict__ pos,
        int* __restrict__ nbr, float* __restrict__ dist, float* __restrict__ cval) {
#pragma clang fp contract(off)
  __shared__ float d2s[128];
  __shared__ int scnt;
  int i = blockIdx.x;
  int li = i & 127;
  int base = i - li;
  int j = threadIdx.x;
  if (j == 0) scnt = 0;
  float px = pos[3*i], py = pos[3*i+1], pz = pos[3*i+2];
  int gj = base + j;
  float dx = px - pos[3*gj], dy = py - pos[3*gj+1], dz = pz - pos[3*gj+2];
  float d2 = dx*dx + dy*dy + dz*dz;
  bool valid = (j != li) && (d2 <= 100.0f);
  d2s[j] = valid ? d2 : 3.0e38f;
  __syncthreads();
  if (valid) {
    atomicAdd(&scnt, 1);
    int rank = 0;
    for (int j2 = 0; j2 < 128; ++j2) {
      float o = d2s[j2];
      rank += (o < d2 || (o == d2 && j2 < j)) ? 1 : 0;
    }
    if (rank < KNB) {
      int e = i*KNB + rank;
      nbr[e] = gj;
      float d = sqrtf(d2);
      dist[e] = d;
      cval[e] = 0.5f * (cosf(d * 0.31415926535897931f) + 1.0f);
    }
  }
  __syncthreads();
  int cnt = scnt; if (cnt > KNB) cnt = KNB;
  if (j < KNB && j >= cnt) {
    int e = i*KNB + j;
    nbr[e] = i; dist[e] = 0.0f; cval[e] = 0.0f;
  }
}

// ---------------- gaussian smearing -> bf16, K padded to 64 ----------------
__global__ __launch_bounds__(256) void ea_k(const float* __restrict__ dist,
                                            short* __restrict__ eab) {
  int idx = blockIdx.x*256 + threadIdx.x;
  if (idx >= EE*64) return;
  int e = idx >> 6, g = idx & 63;
  float v = 0.0f;
  if (g < GG) {
    const float step = 10.0f/49.0f;
    const float coeff = -0.5f/(step*step);
    float dd = dist[e] - step*(float)g;
    v = expf(coeff*dd*dd);
  }
  eab[idx] = f2b(v);
}

// ---------------- w1 (edge first weight): fp32 [50][600] -> bf16 [640][64], all layers ----------------
__global__ __launch_bounds__(256) void conv_w1_k(const float* __restrict__ w1,
                                                 short* __restrict__ w1b) {
  int idx = blockIdx.x*256 + threadIdx.x;
  if (idx >= LL*WROW*64) return;
  int l = idx / (WROW*64); int rem = idx - l*WROW*64;
  int n = rem >> 6, k = rem & 63;
  float v = (n < HD && k < GG) ? w1[(size_t)l*GG*HD + (size_t)k*HD + n] : 0.0f;
  w1b[idx] = f2b(v);
}

// ---------------- per-layer weights: 4x fp32 [600][600] -> bf16 [4][640][608] ----------------
__global__ __launch_bounds__(256) void conv_nw_k(const float* __restrict__ s0,
    const float* __restrict__ s1, const float* __restrict__ s2,
    const float* __restrict__ s3, short* __restrict__ dst) {
  int idx = blockIdx.x*256 + threadIdx.x;
  if (idx >= 4*WROW*WCOL) return;
  int w = idx / (WROW*WCOL); int rem = idx - w*(WROW*WCOL);
  int n = rem / WCOL, k = rem - n*WCOL;
  float v = 0.0f;
  if (n < HD && k < HD) {
    const float* s = (w == 0) ? s0 : (w == 1) ? s1 : (w == 2) ? s2 : s3;
    v = s[(size_t)k*HD + n];
  }
  dst[idx] = f2b(v);
}

// ---------------- embedding: h fp32 [1024][600] + h_b bf16 [1024][608] ----------------
__global__ __launch_bounds__(256) void embed_k(const int* __restrict__ z,
        const float* __restrict__ emb, float* __restrict__ h, short* __restrict__ hb) {
  int i = blockIdx.x;
  int zi = z[i];
  for (int j = threadIdx.x; j < WCOL; j += 256) {
    float v = (j < HD) ? emb[(size_t)zi*HD + j] : 0.0f;
    if (j < HD) h[(size_t)i*HD + j] = v;
    hb[(size_t)i*WCOL + j] = f2b(v);
  }
}

// ---------------- unified 128x128 MFMA kernel ----------------
// 4 waves in 2x2; each wave computes 64x64 via 4x4 grid of 16x16x32 MFMAs.
// A: bf16 [M][lda]; Bw: bf16 [n][ldb] (n padded to 640, k pads zeroed).
// MODE 0: tout = bf16(ssp(acc+bias)), stride 608, col pads zeroed  (edge t)
// MODE 1: msgb[node] = bf16(sum_e (acc+bias)*cval*x1[nbr])         (edge agg; 2 nodes/block)
// MODE 2: outf = acc (fp32, stride 600, no bias)                   (x1)
// MODE 3: outb = bf16(ssp(acc+bias)), stride 608, pads zeroed      (lin2)
// MODE 4: outf += acc+bias (fp32 stride 600); outb = bf16(outf')   (int_lin residual)
template<int MODE>
__global__ __launch_bounds__(256) void mfma128_k(
    const short* __restrict__ A, int lda, int Kd,
    const short* __restrict__ Bw, int ldb,
    const float* __restrict__ bias,
    short* __restrict__ outb, float* __restrict__ outf,
    const float* __restrict__ cval, const int* __restrict__ nbr,
    const float* __restrict__ x1g, short* __restrict__ msgb, int nodeBase) {
  __shared__ __align__(16) short As[128*40];
  __shared__ __align__(16) short Bs[128*40];
  __shared__ float cvs[128];
  __shared__ int nbs[128];
  int tid = threadIdx.x;
  int lane = tid & 63, wv = tid >> 6;
  int wr = wv >> 1, wc = wv & 1;
  int col = lane & 15, quad = lane >> 4;
  int m0 = blockIdx.x * 128;
  int n0 = blockIdx.y * 128;
  f32x4 acc[4][4] = {};
  if (MODE == 1 && tid < 128) {
    int eg = (nodeBase + blockIdx.x*2)*KNB + tid;
    cvs[tid] = cval[eg];
    nbs[tid] = nbr[eg];
  }
  for (int k0 = 0; k0 < Kd; k0 += 32) {
    #pragma unroll
    for (int rep = 0; rep < 2; ++rep) {
      int s = tid + rep*256;
      int row = s >> 2, seg = s & 3;
      *(short8*)&As[row*40 + seg*8] =
          *(const short8*)(A + (size_t)(m0 + row)*lda + k0 + seg*8);
      *(short8*)&Bs[row*40 + seg*8] =
          *(const short8*)(Bw + (size_t)(n0 + row)*ldb + k0 + seg*8);
    }
    __syncthreads();
    short8 af[4], bf[4];
    #pragma unroll
    for (int mt = 0; mt < 4; ++mt)
      af[mt] = *(const short8*)&As[(wr*64 + mt*16 + col)*40 + quad*8];
    #pragma unroll
    for (int jt = 0; jt < 4; ++jt)
      bf[jt] = *(const short8*)&Bs[(wc*64 + jt*16 + col)*40 + quad*8];
    #pragma unroll
    for (int mt = 0; mt < 4; ++mt)
      #pragma unroll
      for (int jt = 0; jt < 4; ++jt)
        acc[mt][jt] = __builtin_amdgcn_mfma_f32_16x16x32_bf16(af[mt], bf[jt], acc[mt][jt], 0, 0, 0);
    __syncthreads();
  }
  if (MODE == 0 || MODE == 3) {
    #pragma unroll
    for (int jt = 0; jt < 4; ++jt) {
      int j = n0 + wc*64 + jt*16 + col;
      if (j >= WCOL) continue;
      float bj = (j < HD) ? bias[j] : 0.0f;
      #pragma unroll
      for (int mt = 0; mt < 4; ++mt)
        #pragma unroll
        for (int r = 0; r < 4; ++r) {
          int row = m0 + wr*64 + mt*16 + quad*4 + r;
          short v = (j < HD) ? f2b(sspf(acc[mt][jt][r] + bj)) : (short)0;
          outb[(size_t)row*WCOL + j] = v;
        }
    }
  } else if (MODE == 2) {
    #pragma unroll
    for (int jt = 0; jt < 4; ++jt) {
      int j = n0 + wc*64 + jt*16 + col;
      if (j >= HD) continue;
      #pragma unroll
      for (int mt = 0; mt < 4; ++mt)
        #pragma unroll
        for (int r = 0; r < 4; ++r) {
          int row = m0 + wr*64 + mt*16 + quad*4 + r;
          outf[(size_t)row*HD + j] = acc[mt][jt][r];
        }
    }
  } else if (MODE == 4) {
    #pragma unroll
    for (int jt = 0; jt < 4; ++jt) {
      int j = n0 + wc*64 + jt*16 + col;
      if (j >= WCOL) continue;
      float bj = (j < HD) ? bias[j] : 0.0f;
      #pragma unroll
      for (int mt = 0; mt < 4; ++mt)
        #pragma unroll
        for (int r = 0; r < 4; ++r) {
          int row = m0 + wr*64 + mt*16 + quad*4 + r;
          if (j < HD) {
            float nv = outf[(size_t)row*HD + j] + acc[mt][jt][r] + bj;
            outf[(size_t)row*HD + j] = nv;
            outb[(size_t)row*WCOL + j] = f2b(nv);
          } else {
            outb[(size_t)row*WCOL + j] = 0;
          }
        }
    }
  } else { // MODE 1: edge aggregation, 2 nodes per block (wave-row = node)
    int node = nodeBase + blockIdx.x*2 + wr;
    #pragma unroll
    for (int jt = 0; jt < 4; ++jt) {
      int j = n0 + wc*64 + jt*16 + col;
      bool jok = j < HD;
      float bj = jok ? bias[j] : 0.0f;
      float s = 0.0f;
      #pragma unroll
      for (int mt = 0; mt < 4; ++mt)
        #pragma unroll
        for (int r = 0; r < 4; ++r) {
          int e = wr*64 + mt*16 + quad*4 + r;
          float Ce = cvs[e];
          if (jok && Ce != 0.0f) {
            float xv = x1g[(size_t)nbs[e]*HD + j];
            s += (acc[mt][jt][r] + bj) * Ce * xv;
          }
        }
      s += __shfl_xor(s, 16);
      s += __shfl_xor(s, 32);
      if (quad == 0 && jok) msgb[(size_t)node*WCOL + j] = f2b(s);
    }
  }
}

// ---------------- pooling + output ----------------
__global__ __launch_bounds__(256) void pool_mean_k(const float* __restrict__ h,
                                                   float* __restrict__ pooled) {
  int b = blockIdx.x;
  int c = blockIdx.y*256 + threadIdx.x;
  if (c >= HD) return;
  float s = 0.0f;
  for (int n = 0; n < NPG; ++n) s += h[(size_t)(b*NPG + n)*HD + c];
  pooled[(size_t)b*HD + c] = s * (1.0f/128.0f);
}

__global__ __launch_bounds__(256) void pool_out_k(const float* __restrict__ pooled,
    const float* __restrict__ pw, const float* __restrict__ pb,
    float* __restrict__ out) {
  int b = blockIdx.x;
  int j = blockIdx.y*256 + threadIdx.x;
  if (j >= HD) return;
  float s = pb[j];
  for (int c = 0; c < HD; ++c) s += pooled[(size_t)b*HD + c] * pw[(size_t)c*HD + j];
  out[(size_t)b*HD + j] = s;
}

// ---------------- launch ----------------
extern "C" void kernel_launch(void* const* d_in, const int* in_sizes, int n_in,
                              void* d_out, int out_size, void* d_ws, size_t ws_size,
                              hipStream_t stream) {
  const int*   z    = (const int*)d_in[0];
  const float* pos  = (const float*)d_in[1];
  const float* emb  = (const float*)d_in[2];
  const float* w1   = (const float*)d_in[3];
  const float* b1   = (const float*)d_in[4];
  const float* w2   = (const float*)d_in[5];
  const float* b2   = (const float*)d_in[6];
  const float* l1w  = (const float*)d_in[7];
  const float* l2w  = (const float*)d_in[8];
  const float* l2b  = (const float*)d_in[9];
  const float* ilw  = (const float*)d_in[10];
  const float* ilb  = (const float*)d_in[11];
  const float* pw   = (const float*)d_in[12];
  const float* pb   = (const float*)d_in[13];
  float* ws = (float*)d_ws;
  // workspace layout (float offsets) — total 10,346,496 f = 41.4 MB
  int*   nbr   = (int*)ws;                   // 65536
  float* cv    = ws + 65536;                 // 65536
  float* dist  = ws + 131072;                // 65536
  float* pooled= ws + 196608;                // 4800 (pad to 8192)
  float* h     = ws + 204800;                // 614400
  float* x1    = ws + 819200;                // 614400
  short* h_b   = (short*)(ws + 1433600);     // 1024*608 shorts = 311296 f
  short* msg_b = (short*)(ws + 1744896);     // 311296 f
  short* mtmp_b= (short*)(ws + 2056192);     // 311296 f
  short* eab   = (short*)(ws + 2367488);     // 65536*64 shorts = 2097152 f
  short* w1b   = (short*)(ws + 4464640);     // 6*640*64 shorts = 122880 f
  short* nwb   = (short*)(ws + 4587520);     // 4*640*608 shorts = 778240 f
  short* tbuf  = (short*)(ws + 5365760);     // 16384*608 shorts = 4980736 f
  float* out   = (float*)d_out;

  build_graph_k<<<NN, 128, 0, stream>>>(pos, nbr, dist, cv);
  ea_k<<<(EE*64 + 255)/256, 256, 0, stream>>>(dist, eab);
  conv_w1_k<<<(LL*WROW*64 + 255)/256, 256, 0, stream>>>(w1, w1b);
  embed_k<<<NN, 256, 0, stream>>>(z, emb, h, h_b);

  const size_t WSZ = (size_t)WROW*WCOL;      // 389120 shorts per weight
  dim3 gnode(8, 5), gedge(128, 5);
  for (int l = 0; l < LL; ++l) {
    conv_nw_k<<<(4*WROW*WCOL + 255)/256, 256, 0, stream>>>(
        l1w + (size_t)l*360000, l2w + (size_t)l*360000,
        ilw + (size_t)l*360000, w2 + (size_t)l*360000, nwb);
    // x1 = h @ lin1_w[l]
    mfma128_k<2><<<gnode, 256, 0, stream>>>(h_b, WCOL, WCOL, nwb + 0*WSZ, WCOL,
        nullptr, nullptr, x1, nullptr, nullptr, nullptr, nullptr, 0);
    for (int c = 0; c < 4; ++c) {
      // t = ssp(ea @ mlp_w1[l] + b1) -> bf16 tbuf
      mfma128_k<0><<<gedge, 256, 0, stream>>>(
          eab + (size_t)c*CHE*64, 64, 64, w1b + (size_t)l*WROW*64, 64,
          b1 + (size_t)l*HD, tbuf, nullptr, nullptr, nullptr, nullptr, nullptr, 0);
      // msg_b = bf16(sum_e C*(t@w2+b2)*x1[nbr])
      mfma128_k<1><<<gedge, 256, 0, stream>>>(
          tbuf, WCOL, WCOL, nwb + 3*WSZ, WCOL,
          b2 + (size_t)l*HD, nullptr, nullptr, cv, nbr, x1, msg_b, c*CHN);
    }
    // mtmp_b = bf16(ssp(msg @ lin2_w[l] + lin2_b[l]))
    mfma128_k<3><<<gnode, 256, 0, stream>>>(msg_b, WCOL, WCOL, nwb + 1*WSZ, WCOL,
        l2b + (size_t)l*HD, mtmp_b, nullptr, nullptr, nullptr, nullptr, nullptr, 0);
    // h += mtmp @ int_lin_w[l] + int_lin_b[l]; h_b = bf16(h)
    mfma128_k<4><<<gnode, 256, 0, stream>>>(mtmp_b, WCOL, WCOL, nwb + 2*WSZ, WCOL,
        ilb + (size_t)l*HD, h_b, h, nullptr, nullptr, nullptr, nullptr, 0);
  }
  pool_mean_k<<<dim3(NB, 3), 256, 0, stream>>>(h, pooled);
  pool_out_k<<<dim3(NB, 3), 256, 0, stream>>>(pooled, pw, pb, out);
}

// Round 4
// 1997.674 us; speedup vs baseline: 1.6926x; 1.6926x over previous
//
#include <hip/hip_runtime.h>
#include <cmath>

#define NB   8
#define NPG  128
#define NN   1024
#define KNB  64
#define HD   600
#define GG   50
#define LL   6
#define EE   (NN*KNB)     // 65536 edges
#define WROW 640          // padded weight rows (n)
#define WCOL 608          // padded weight cols (k)

typedef __attribute__((ext_vector_type(8))) short short8;
typedef __attribute__((ext_vector_type(4))) float f32x4;

__device__ __forceinline__ short f2b(float f) {
  union { float f; unsigned u; } v; v.f = f;
  unsigned u = v.u;
  u += 0x7fffu + ((u >> 16) & 1u);
  return (short)(u >> 16);
}

__device__ __forceinline__ float sspf(float x) {
  float sp = (x > 20.0f) ? x : log1pf(expf(x));
  return sp - 0.69314718055994531f;
}

// ---------------- graph build: one block per node ----------------
__global__ __launch_bounds__(128) void build_graph_k(const float* __restrict__ pos,
        int* __restrict__ nbr, float* __restrict__ dist, float* __restrict__ cval) {
#pragma clang fp contract(off)
  __shared__ float d2s[128];
  __shared__ int scnt;
  int i = blockIdx.x;
  int li = i & 127;
  int base = i - li;
  int j = threadIdx.x;
  if (j == 0) scnt = 0;
  float px = pos[3*i], py = pos[3*i+1], pz = pos[3*i+2];
  int gj = base + j;
  float dx = px - pos[3*gj], dy = py - pos[3*gj+1], dz = pz - pos[3*gj+2];
  float d2 = dx*dx + dy*dy + dz*dz;
  bool valid = (j != li) && (d2 <= 100.0f);
  d2s[j] = valid ? d2 : 3.0e38f;
  __syncthreads();
  if (valid) {
    atomicAdd(&scnt, 1);
    int rank = 0;
    for (int j2 = 0; j2 < 128; ++j2) {
      float o = d2s[j2];
      rank += (o < d2 || (o == d2 && j2 < j)) ? 1 : 0;
    }
    if (rank < KNB) {
      int e = i*KNB + rank;
      nbr[e] = gj;
      float d = sqrtf(d2);
      dist[e] = d;
      cval[e] = 0.5f * (cosf(d * 0.31415926535897931f) + 1.0f);
    }
  }
  __syncthreads();
  int cnt = scnt; if (cnt > KNB) cnt = KNB;
  if (j < KNB && j >= cnt) {
    int e = i*KNB + j;
    nbr[e] = i; dist[e] = 0.0f; cval[e] = 0.0f;
  }
}

// ---------------- gaussian smearing -> bf16, K padded to 64 ----------------
__global__ __launch_bounds__(256) void ea_k(const float* __restrict__ dist,
                                            short* __restrict__ eab) {
  int idx = blockIdx.x*256 + threadIdx.x;
  if (idx >= EE*64) return;
  int e = idx >> 6, g = idx & 63;
  float v = 0.0f;
  if (g < GG) {
    const float step = 10.0f/49.0f;
    const float coeff = -0.5f/(step*step);
    float dd = dist[e] - step*(float)g;
    v = expf(coeff*dd*dd);
  }
  eab[idx] = f2b(v);
}

// ---------------- w1: fp32 [50][600] -> bf16 [640][64], all layers ----------------
__global__ __launch_bounds__(256) void conv_w1_k(const float* __restrict__ w1,
                                                 short* __restrict__ w1b) {
  int idx = blockIdx.x*256 + threadIdx.x;
  if (idx >= LL*WROW*64) return;
  int l = idx / (WROW*64); int rem = idx - l*WROW*64;
  int n = rem >> 6, k = rem & 63;
  float v = (n < HD && k < GG) ? w1[(size_t)l*GG*HD + (size_t)k*HD + n] : 0.0f;
  w1b[idx] = f2b(v);
}

// ---------------- per-layer weights: 4x fp32 [600][600] -> bf16 [4][640][608] ----------------
__global__ __launch_bounds__(256) void conv_nw_k(const float* __restrict__ s0,
    const float* __restrict__ s1, const float* __restrict__ s2,
    const float* __restrict__ s3, short* __restrict__ dst) {
  int idx = blockIdx.x*256 + threadIdx.x;
  if (idx >= 4*WROW*WCOL) return;
  int w = idx / (WROW*WCOL); int rem = idx - w*(WROW*WCOL);
  int n = rem / WCOL, k = rem - n*WCOL;
  float v = 0.0f;
  if (n < HD && k < HD) {
    const float* s = (w == 0) ? s0 : (w == 1) ? s1 : (w == 2) ? s2 : s3;
    v = s[(size_t)k*HD + n];
  }
  dst[idx] = f2b(v);
}

// ---------------- embedding: h fp32 + h_b bf16 ----------------
__global__ __launch_bounds__(256) void embed_k(const int* __restrict__ z,
        const float* __restrict__ emb, float* __restrict__ h, short* __restrict__ hb) {
  int i = blockIdx.x;
  int zi = z[i];
  for (int j = threadIdx.x; j < WCOL; j += 256) {
    float v = (j < HD) ? emb[(size_t)zi*HD + j] : 0.0f;
    if (j < HD) h[(size_t)i*HD + j] = v;
    hb[(size_t)i*WCOL + j] = f2b(v);
  }
}

// ---------------- edge 128x128 MFMA kernel (2x2 waves of 64x64) ----------------
// MODE 0: tout = bf16(ssp(acc+bias)), stride 608, col pads zeroed  (edge t)
// MODE 1: msgb[node] = bf16(sum_e (acc+bias)*cval*x1[nbr])         (2 nodes/block)
template<int MODE>
__global__ __launch_bounds__(256) void mfma128_k(
    const short* __restrict__ A, int lda, int Kd,
    const short* __restrict__ Bw, int ldb,
    const float* __restrict__ bias,
    short* __restrict__ outb,
    const float* __restrict__ cval, const int* __restrict__ nbr,
    const float* __restrict__ x1g, short* __restrict__ msgb, int nodeBase) {
  __shared__ __align__(16) short As[128*40];
  __shared__ __align__(16) short Bs[128*40];
  __shared__ float cvs[128];
  __shared__ int nbs[128];
  int tid = threadIdx.x;
  int lane = tid & 63, wv = tid >> 6;
  int wr = wv >> 1, wc = wv & 1;
  int col = lane & 15, quad = lane >> 4;
  int m0 = blockIdx.x * 128;
  int n0 = blockIdx.y * 128;
  f32x4 acc[4][4] = {};
  if (MODE == 1 && tid < 128) {
    int eg = (nodeBase + blockIdx.x*2)*KNB + tid;
    cvs[tid] = cval[eg];
    nbs[tid] = nbr[eg];
  }
  for (int k0 = 0; k0 < Kd; k0 += 32) {
    #pragma unroll
    for (int rep = 0; rep < 2; ++rep) {
      int s = tid + rep*256;
      int row = s >> 2, seg = s & 3;
      *(short8*)&As[row*40 + seg*8] =
          *(const short8*)(A + (size_t)(m0 + row)*lda + k0 + seg*8);
      *(short8*)&Bs[row*40 + seg*8] =
          *(const short8*)(Bw + (size_t)(n0 + row)*ldb + k0 + seg*8);
    }
    __syncthreads();
    short8 af[4], bf[4];
    #pragma unroll
    for (int mt = 0; mt < 4; ++mt)
      af[mt] = *(const short8*)&As[(wr*64 + mt*16 + col)*40 + quad*8];
    #pragma unroll
    for (int jt = 0; jt < 4; ++jt)
      bf[jt] = *(const short8*)&Bs[(wc*64 + jt*16 + col)*40 + quad*8];
    #pragma unroll
    for (int mt = 0; mt < 4; ++mt)
      #pragma unroll
      for (int jt = 0; jt < 4; ++jt)
        acc[mt][jt] = __builtin_amdgcn_mfma_f32_16x16x32_bf16(af[mt], bf[jt], acc[mt][jt], 0, 0, 0);
    __syncthreads();
  }
  if (MODE == 0) {
    #pragma unroll
    for (int jt = 0; jt < 4; ++jt) {
      int j = n0 + wc*64 + jt*16 + col;
      if (j >= WCOL) continue;
      float bj = (j < HD) ? bias[j] : 0.0f;
      #pragma unroll
      for (int mt = 0; mt < 4; ++mt)
        #pragma unroll
        for (int r = 0; r < 4; ++r) {
          int row = m0 + wr*64 + mt*16 + quad*4 + r;
          short v = (j < HD) ? f2b(sspf(acc[mt][jt][r] + bj)) : (short)0;
          outb[(size_t)row*WCOL + j] = v;
        }
    }
  } else { // MODE 1
    int node = nodeBase + blockIdx.x*2 + wr;
    #pragma unroll
    for (int jt = 0; jt < 4; ++jt) {
      int j = n0 + wc*64 + jt*16 + col;
      bool jok = j < HD;
      float bj = jok ? bias[j] : 0.0f;
      float s = 0.0f;
      #pragma unroll
      for (int mt = 0; mt < 4; ++mt)
        #pragma unroll
        for (int r = 0; r < 4; ++r) {
          int e = wr*64 + mt*16 + quad*4 + r;
          float Ce = cvs[e];
          if (jok && Ce != 0.0f) {
            float xv = x1g[(size_t)nbs[e]*HD + j];
            s += (acc[mt][jt][r] + bj) * Ce * xv;
          }
        }
      s += __shfl_xor(s, 16);
      s += __shfl_xor(s, 32);
      if (quad == 0 && jok) msgb[(size_t)node*WCOL + j] = f2b(s);
    }
  }
}

// ---------------- node GEMM: split-K MFMA, 64x64 tile, grid (16,10,2) ----------------
// A: bf16 [1024][608] (k pads zero or harmless), Bw: bf16 [640][608].
// z=0: k 0..320 -> P0 ; z=1: k 320..608 -> P1. P fp32 [1024][600].
__global__ __launch_bounds__(256) void mfma_nk(
    const short* __restrict__ A, const short* __restrict__ Bw,
    float* __restrict__ P0, float* __restrict__ P1) {
  __shared__ __align__(16) short As[64*40];
  __shared__ __align__(16) short Bs[64*40];
  int tid = threadIdx.x;
  int lane = tid & 63, wv = tid >> 6;
  int wr = wv >> 1, wc = wv & 1;
  int col = lane & 15, quad = lane >> 4;
  int m0 = blockIdx.x * 64;
  int n0 = blockIdx.y * 64;
  int kz = blockIdx.z;
  int k0 = kz ? 320 : 0;
  int kend = kz ? 608 : 320;
  float* __restrict__ P = kz ? P1 : P0;
  f32x4 acc[2][2] = {};
  int row = tid >> 2, seg = tid & 3;
  for (int kk = k0; kk < kend; kk += 32) {
    *(short8*)&As[row*40 + seg*8] =
        *(const short8*)(A + (size_t)(m0 + row)*WCOL + kk + seg*8);
    *(short8*)&Bs[row*40 + seg*8] =
        *(const short8*)(Bw + (size_t)(n0 + row)*WCOL + kk + seg*8);
    __syncthreads();
    short8 af[2], bf[2];
    #pragma unroll
    for (int mt = 0; mt < 2; ++mt)
      af[mt] = *(const short8*)&As[(wr*32 + mt*16 + col)*40 + quad*8];
    #pragma unroll
    for (int jt = 0; jt < 2; ++jt)
      bf[jt] = *(const short8*)&Bs[(wc*32 + jt*16 + col)*40 + quad*8];
    #pragma unroll
    for (int mt = 0; mt < 2; ++mt)
      #pragma unroll
      for (int jt = 0; jt < 2; ++jt)
        acc[mt][jt] = __builtin_amdgcn_mfma_f32_16x16x32_bf16(af[mt], bf[jt], acc[mt][jt], 0, 0, 0);
    __syncthreads();
  }
  #pragma unroll
  for (int jt = 0; jt < 2; ++jt) {
    int j = n0 + wc*32 + jt*16 + col;
    if (j >= HD) continue;
    #pragma unroll
    for (int mt = 0; mt < 2; ++mt)
      #pragma unroll
      for (int r = 0; r < 4; ++r) {
        int rw = m0 + wr*32 + mt*16 + quad*4 + r;
        P[(size_t)rw*HD + j] = acc[mt][jt][r];
      }
  }
}

// ---------------- node epilogues ----------------
// x1 = p0+p1
__global__ __launch_bounds__(256) void ep_x1_k(const float* __restrict__ p0,
    const float* __restrict__ p1, float* __restrict__ x1) {
  int idx = blockIdx.x*256 + threadIdx.x;
  if (idx >= NN*HD) return;
  x1[idx] = p0[idx] + p1[idx];
}
// outb = bf16(ssp(p0+p1+bias)), [1024][608] pads zero
__global__ __launch_bounds__(256) void ep_ssp_k(const float* __restrict__ p0,
    const float* __restrict__ p1, const float* __restrict__ bias,
    short* __restrict__ outb) {
  int idx = blockIdx.x*256 + threadIdx.x;
  if (idx >= NN*WCOL) return;
  int row = idx / WCOL, j = idx - row*WCOL;
  short v = 0;
  if (j < HD) {
    size_t o = (size_t)row*HD + j;
    v = f2b(sspf(p0[o] + p1[o] + bias[j]));
  }
  outb[idx] = v;
}
// h += p0+p1+bias ; hb = bf16(h), pads zero
__global__ __launch_bounds__(256) void ep_res_k(const float* __restrict__ p0,
    const float* __restrict__ p1, const float* __restrict__ bias,
    float* __restrict__ h, short* __restrict__ hb) {
  int idx = blockIdx.x*256 + threadIdx.x;
  if (idx >= NN*WCOL) return;
  int row = idx / WCOL, j = idx - row*WCOL;
  short v = 0;
  if (j < HD) {
    size_t o = (size_t)row*HD + j;
    float nv = h[o] + p0[o] + p1[o] + bias[j];
    h[o] = nv;
    v = f2b(nv);
  }
  hb[idx] = v;
}

// ---------------- pooling + output ----------------
__global__ __launch_bounds__(256) void pool_mean_k(const float* __restrict__ h,
                                                   float* __restrict__ pooled) {
  int b = blockIdx.x;
  int c = blockIdx.y*256 + threadIdx.x;
  if (c >= HD) return;
  float s = 0.0f;
  for (int n = 0; n < NPG; ++n) s += h[(size_t)(b*NPG + n)*HD + c];
  pooled[(size_t)b*HD + c] = s * (1.0f/128.0f);
}

__global__ __launch_bounds__(256) void pool_out_k(const float* __restrict__ pooled,
    const float* __restrict__ pw, const float* __restrict__ pb,
    float* __restrict__ out) {
  int b = blockIdx.x;
  int j = blockIdx.y*256 + threadIdx.x;
  if (j >= HD) return;
  float s = pb[j];
  for (int c = 0; c < HD; ++c) s += pooled[(size_t)b*HD + c] * pw[(size_t)c*HD + j];
  out[(size_t)b*HD + j] = s;
}

// ---------------- launch ----------------
extern "C" void kernel_launch(void* const* d_in, const int* in_sizes, int n_in,
                              void* d_out, int out_size, void* d_ws, size_t ws_size,
                              hipStream_t stream) {
  const int*   z    = (const int*)d_in[0];
  const float* pos  = (const float*)d_in[1];
  const float* emb  = (const float*)d_in[2];
  const float* w1   = (const float*)d_in[3];
  const float* b1   = (const float*)d_in[4];
  const float* w2   = (const float*)d_in[5];
  const float* b2   = (const float*)d_in[6];
  const float* l1w  = (const float*)d_in[7];
  const float* l2w  = (const float*)d_in[8];
  const float* l2b  = (const float*)d_in[9];
  const float* ilw  = (const float*)d_in[10];
  const float* ilb  = (const float*)d_in[11];
  const float* pw   = (const float*)d_in[12];
  const float* pb   = (const float*)d_in[13];
  float* ws = (float*)d_ws;
  // workspace layout (float offsets)
  int*   nbr   = (int*)ws;                   // 65536
  float* cv    = ws + 65536;                 // 65536
  float* dist  = ws + 131072;                // 65536
  float* pooled= ws + 196608;                // 8192 pad
  float* h     = ws + 204800;                // 614400
  float* x1    = ws + 819200;                // 614400
  short* h_b   = (short*)(ws + 1433600);     // 311296 f
  short* msg_b = (short*)(ws + 1744896);     // 311296 f
  short* mtmp_b= (short*)(ws + 2056192);     // 311296 f
  short* eab   = (short*)(ws + 2367488);     // 2097152 f
  short* w1b   = (short*)(ws + 4464640);     // 122880 f
  short* nwb   = (short*)(ws + 4587520);     // 778240 f
  float* p0    = ws + 5365760;               // 614400
  float* p1    = ws + 5980160;               // 614400
  short* tbuf  = (short*)(ws + 6594560);     // EPC*608 shorts
  float* out   = (float*)d_out;

  // dynamic edge chunking by workspace size
  int EPC;  // edges per chunk
  if      (ws_size >= (size_t)26517504*4) EPC = 65536;  // full batch, ~106 MB
  else if (ws_size >= (size_t)11575296*4) EPC = 16384;  // ~46.3 MB
  else                                    EPC = 8192;   // ~36.3 MB
  int nch = EE / EPC;

  build_graph_k<<<NN, 128, 0, stream>>>(pos, nbr, dist, cv);
  ea_k<<<(EE*64 + 255)/256, 256, 0, stream>>>(dist, eab);
  conv_w1_k<<<(LL*WROW*64 + 255)/256, 256, 0, stream>>>(w1, w1b);
  embed_k<<<NN, 256, 0, stream>>>(z, emb, h, h_b);

  const size_t WSZ = (size_t)WROW*WCOL;
  dim3 gnode(16, 10, 2), gedge(EPC/128, 5);
  int epb608 = (NN*WCOL + 255)/256, epb600 = (NN*HD + 255)/256;
  for (int l = 0; l < LL; ++l) {
    conv_nw_k<<<(4*WROW*WCOL + 255)/256, 256, 0, stream>>>(
        l1w + (size_t)l*360000, l2w + (size_t)l*360000,
        ilw + (size_t)l*360000, w2 + (size_t)l*360000, nwb);
    // x1 = h @ lin1_w[l]
    mfma_nk<<<gnode, 256, 0, stream>>>(h_b, nwb + 0*WSZ, p0, p1);
    ep_x1_k<<<epb600, 256, 0, stream>>>(p0, p1, x1);
    for (int c = 0; c < nch; ++c) {
      // t = ssp(ea @ mlp_w1[l] + b1) -> bf16 tbuf
      mfma128_k<0><<<gedge, 256, 0, stream>>>(
          eab + (size_t)c*EPC*64, 64, 64, w1b + (size_t)l*WROW*64, 64,
          b1 + (size_t)l*HD, tbuf, nullptr, nullptr, nullptr, nullptr, 0);
      // msg_b = bf16(sum_e C*(t@w2+b2)*x1[nbr])
      mfma128_k<1><<<gedge, 256, 0, stream>>>(
          tbuf, WCOL, WCOL, nwb + 3*WSZ, WCOL,
          b2 + (size_t)l*HD, nullptr, cv, nbr, x1, msg_b, c*(EPC/KNB));
    }
    // mtmp_b = bf16(ssp(msg @ lin2_w[l] + lin2_b[l]))
    mfma_nk<<<gnode, 256, 0, stream>>>(msg_b, nwb + 1*WSZ, p0, p1);
    ep_ssp_k<<<epb608, 256, 0, stream>>>(p0, p1, l2b + (size_t)l*HD, mtmp_b);
    // h += mtmp @ int_lin_w[l] + int_lin_b[l]; h_b = bf16(h)
    mfma_nk<<<gnode, 256, 0, stream>>>(mtmp_b, nwb + 2*WSZ, p0, p1);
    ep_res_k<<<epb608, 256, 0, stream>>>(p0, p1, ilb + (size_t)l*HD, h, h_b);
  }
  pool_mean_k<<<dim3(NB, 3), 256, 0, stream>>>(h, pooled);
  pool_out_k<<<dim3(NB, 3), 256, 0, stream>>>(pooled, pw, pb, out);
}

// Round 5
// 1252.065 us; speedup vs baseline: 2.7006x; 1.5955x over previous
//
#include <hip/hip_runtime.h>
#include <cmath>

#define NB   8
#define NPG  128
#define NN   1024
#define KNB  64
#define HD   600
#define GG   50
#define LL   6
#define EE   (NN*KNB)     // 65536 edges
#define WROW 640          // padded weight rows (n)
#define WCOL 608          // padded weight cols (k)
#define TSLD 616          // LDS t-tile row stride (shorts); 1232B rows: 16B aligned, 2-way banks

typedef __attribute__((ext_vector_type(8))) short short8;
typedef __attribute__((ext_vector_type(4))) float f32x4;

__device__ __forceinline__ short f2b(float f) {
  union { float f; unsigned u; } v; v.f = f;
  unsigned u = v.u;
  u += 0x7fffu + ((u >> 16) & 1u);
  return (short)(u >> 16);
}

// fast shifted softplus: max(x,0)+log(1+e^-|x|)-ln2 ; __expf/__logf are v_exp/v_log
__device__ __forceinline__ float ssp_fast(float x) {
  return fmaxf(x, 0.0f) + __logf(1.0f + __expf(-fabsf(x))) - 0.69314718055994531f;
}

// ---------------- graph build: one block per node ----------------
__global__ __launch_bounds__(128) void build_graph_k(const float* __restrict__ pos,
        int* __restrict__ nbr, float* __restrict__ dist, float* __restrict__ cval) {
#pragma clang fp contract(off)
  __shared__ float d2s[128];
  __shared__ int scnt;
  int i = blockIdx.x;
  int li = i & 127;
  int base = i - li;
  int j = threadIdx.x;
  if (j == 0) scnt = 0;
  float px = pos[3*i], py = pos[3*i+1], pz = pos[3*i+2];
  int gj = base + j;
  float dx = px - pos[3*gj], dy = py - pos[3*gj+1], dz = pz - pos[3*gj+2];
  float d2 = dx*dx + dy*dy + dz*dz;
  bool valid = (j != li) && (d2 <= 100.0f);
  d2s[j] = valid ? d2 : 3.0e38f;
  __syncthreads();
  if (valid) {
    atomicAdd(&scnt, 1);
    int rank = 0;
    for (int j2 = 0; j2 < 128; ++j2) {
      float o = d2s[j2];
      rank += (o < d2 || (o == d2 && j2 < j)) ? 1 : 0;
    }
    if (rank < KNB) {
      int e = i*KNB + rank;
      nbr[e] = gj;
      float d = sqrtf(d2);
      dist[e] = d;
      cval[e] = 0.5f * (cosf(d * 0.31415926535897931f) + 1.0f);
    }
  }
  __syncthreads();
  int cnt = scnt; if (cnt > KNB) cnt = KNB;
  if (j < KNB && j >= cnt) {
    int e = i*KNB + j;
    nbr[e] = i; dist[e] = 0.0f; cval[e] = 0.0f;
  }
}

// ---------------- gaussian smearing -> bf16, K padded to 64 ----------------
__global__ __launch_bounds__(256) void ea_k(const float* __restrict__ dist,
                                            short* __restrict__ eab) {
  int idx = blockIdx.x*256 + threadIdx.x;
  if (idx >= EE*64) return;
  int e = idx >> 6, g = idx & 63;
  float v = 0.0f;
  if (g < GG) {
    const float step = 10.0f/49.0f;
    const float coeff = -0.5f/(step*step);
    float dd = dist[e] - step*(float)g;
    v = __expf(coeff*dd*dd);
  }
  eab[idx] = f2b(v);
}

// ---------------- w1: fp32 [50][600] -> bf16 [640][64], all layers ----------------
__global__ __launch_bounds__(256) void conv_w1_k(const float* __restrict__ w1,
                                                 short* __restrict__ w1b) {
  int idx = blockIdx.x*256 + threadIdx.x;
  if (idx >= LL*WROW*64) return;
  int l = idx / (WROW*64); int rem = idx - l*WROW*64;
  int n = rem >> 6, k = rem & 63;
  float v = (n < HD && k < GG) ? w1[(size_t)l*GG*HD + (size_t)k*HD + n] : 0.0f;
  w1b[idx] = f2b(v);
}

// ---------------- per-layer weights: 4x fp32 [600][600] -> bf16 [4][640][608] ----------------
__global__ __launch_bounds__(256) void conv_nw_k(const float* __restrict__ s0,
    const float* __restrict__ s1, const float* __restrict__ s2,
    const float* __restrict__ s3, short* __restrict__ dst) {
  int idx = blockIdx.x*256 + threadIdx.x;
  if (idx >= 4*WROW*WCOL) return;
  int w = idx / (WROW*WCOL); int rem = idx - w*(WROW*WCOL);
  int n = rem / WCOL, k = rem - n*WCOL;
  float v = 0.0f;
  if (n < HD && k < HD) {
    const float* s = (w == 0) ? s0 : (w == 1) ? s1 : (w == 2) ? s2 : s3;
    v = s[(size_t)k*HD + n];
  }
  dst[idx] = f2b(v);
}

// ---------------- embedding: h fp32 + h_b bf16 ----------------
__global__ __launch_bounds__(256) void embed_k(const int* __restrict__ z,
        const float* __restrict__ emb, float* __restrict__ h, short* __restrict__ hb) {
  int i = blockIdx.x;
  int zi = z[i];
  for (int j = threadIdx.x; j < WCOL; j += 256) {
    float v = (j < HD) ? emb[(size_t)zi*HD + j] : 0.0f;
    if (j < HD) h[(size_t)i*HD + j] = v;
    hb[(size_t)i*WCOL + j] = f2b(v);
  }
}

// ---------------- fused edge kernel ----------------
// block = 32 edges (half a node). Stage1: t = ssp(ea@w1+b1) -> LDS (32x616 bf16).
// Stage2: (t@w2+b2)*C*x1[nbr], summed over edges, atomicAdd into fp32 msg.
// B fragments load straight from global (w2b is L2-resident; full-64B-line access).
template<int NT>
__device__ __forceinline__ void edge_s1(const short* __restrict__ eab,
    const short* __restrict__ w1p, const float* __restrict__ b1p,
    short* Ts, int e0, int n0, int lane, int wv) {
  int col = lane & 15, quad = lane >> 4;
  int nbase = n0 + wv*(NT*16);
  f32x4 acc[2][NT] = {};
  #pragma unroll
  for (int k0 = 0; k0 < 64; k0 += 32) {
    short8 af[2], bf[NT];
    #pragma unroll
    for (int mt = 0; mt < 2; ++mt)
      af[mt] = *(const short8*)(eab + (size_t)(e0 + mt*16 + col)*64 + k0 + quad*8);
    #pragma unroll
    for (int nt = 0; nt < NT; ++nt)
      bf[nt] = *(const short8*)(w1p + (size_t)(nbase + nt*16 + col)*64 + k0 + quad*8);
    #pragma unroll
    for (int mt = 0; mt < 2; ++mt)
      #pragma unroll
      for (int nt = 0; nt < NT; ++nt)
        acc[mt][nt] = __builtin_amdgcn_mfma_f32_16x16x32_bf16(af[mt], bf[nt], acc[mt][nt], 0, 0, 0);
  }
  #pragma unroll
  for (int nt = 0; nt < NT; ++nt) {
    int n = nbase + nt*16 + col;
    if (n >= WCOL) continue;
    float bj = (n < HD) ? b1p[n] : 0.0f;   // pads: acc=0,b=0 -> ssp(0)=0
    #pragma unroll
    for (int mt = 0; mt < 2; ++mt)
      #pragma unroll
      for (int r = 0; r < 4; ++r)
        Ts[(mt*16 + quad*4 + r)*TSLD + n] = f2b(ssp_fast(acc[mt][nt][r] + bj));
  }
}

template<int NT>
__device__ __forceinline__ void edge_s2(const short* Ts,
    const short* __restrict__ w2p, const float* __restrict__ b2p,
    const float* cvs, const int* nbs, const float* __restrict__ x1,
    float* __restrict__ msg, int node, int n0, int lane, int wv) {
  int col = lane & 15, quad = lane >> 4;
  int nbase = n0 + wv*(NT*16);
  f32x4 acc[2][NT] = {};
  for (int k0 = 0; k0 < WCOL; k0 += 32) {
    short8 af[2], bf[NT];
    #pragma unroll
    for (int mt = 0; mt < 2; ++mt)
      af[mt] = *(const short8*)(Ts + (mt*16 + col)*TSLD + k0 + quad*8);
    #pragma unroll
    for (int nt = 0; nt < NT; ++nt)
      bf[nt] = *(const short8*)(w2p + (size_t)(nbase + nt*16 + col)*WCOL + k0 + quad*8);
    #pragma unroll
    for (int mt = 0; mt < 2; ++mt)
      #pragma unroll
      for (int nt = 0; nt < NT; ++nt)
        acc[mt][nt] = __builtin_amdgcn_mfma_f32_16x16x32_bf16(af[mt], bf[nt], acc[mt][nt], 0, 0, 0);
  }
  #pragma unroll
  for (int nt = 0; nt < NT; ++nt) {
    int j = nbase + nt*16 + col;
    if (j < HD) {   // quad-partners share col -> shfl-safe divergence
      float bj = b2p[j];
      float s = 0.0f;
      #pragma unroll
      for (int mt = 0; mt < 2; ++mt)
        #pragma unroll
        for (int r = 0; r < 4; ++r) {
          int e = mt*16 + quad*4 + r;
          s += (acc[mt][nt][r] + bj) * cvs[e] * x1[(size_t)nbs[e]*HD + j];
        }
      s += __shfl_xor(s, 16);
      s += __shfl_xor(s, 32);
      if (quad == 0) atomicAdd(&msg[(size_t)node*HD + j], s);
    }
  }
}

__global__ __launch_bounds__(256, 4) void fused_edge_k(
    const short* __restrict__ eab, const short* __restrict__ w1p,
    const short* __restrict__ w2p, const float* __restrict__ b1p,
    const float* __restrict__ b2p, const float* __restrict__ cval,
    const int* __restrict__ nbr, const float* __restrict__ x1,
    float* __restrict__ msg) {
  __shared__ __align__(16) short Ts[32*TSLD];   // 39424 B -> 4 blocks/CU
  __shared__ float cvs[32];
  __shared__ int nbs[32];
  int tid = threadIdx.x, lane = tid & 63, wv = tid >> 6;
  int hblk = blockIdx.x;         // half-node
  int e0 = hblk * 32;
  int node = hblk >> 1;
  if (tid < 32) { cvs[tid] = cval[e0 + tid]; nbs[tid] = nbr[e0 + tid]; }
  edge_s1<4>(eab, w1p, b1p, Ts, e0, 0,   lane, wv);
  edge_s1<4>(eab, w1p, b1p, Ts, e0, 256, lane, wv);
  edge_s1<2>(eab, w1p, b1p, Ts, e0, 512, lane, wv);
  __syncthreads();
  edge_s2<4>(Ts, w2p, b2p, cvs, nbs, x1, msg, node, 0,   lane, wv);
  edge_s2<4>(Ts, w2p, b2p, cvs, nbs, x1, msg, node, 256, lane, wv);
  edge_s2<2>(Ts, w2p, b2p, cvs, nbs, x1, msg, node, 512, lane, wv);
}

// ---------------- msg fp32 -> bf16 [1024][608] ----------------
__global__ __launch_bounds__(256) void msg2b_k(const float* __restrict__ msg,
                                               short* __restrict__ msgb) {
  int idx = blockIdx.x*256 + threadIdx.x;
  if (idx >= NN*WCOL) return;
  int row = idx / WCOL, j = idx - row*WCOL;
  msgb[idx] = (j < HD) ? f2b(msg[(size_t)row*HD + j]) : (short)0;
}

// ---------------- node GEMM: split-K MFMA, 64x64 tile, grid (16,10,2) ----------------
__global__ __launch_bounds__(256) void mfma_nk(
    const short* __restrict__ A, const short* __restrict__ Bw,
    float* __restrict__ P0, float* __restrict__ P1) {
  __shared__ __align__(16) short As[64*40];
  __shared__ __align__(16) short Bs[64*40];
  int tid = threadIdx.x;
  int lane = tid & 63, wv = tid >> 6;
  int wr = wv >> 1, wc = wv & 1;
  int col = lane & 15, quad = lane >> 4;
  int m0 = blockIdx.x * 64;
  int n0 = blockIdx.y * 64;
  int kz = blockIdx.z;
  int k0 = kz ? 320 : 0;
  int kend = kz ? 608 : 320;
  float* __restrict__ P = kz ? P1 : P0;
  f32x4 acc[2][2] = {};
  int row = tid >> 2, seg = tid & 3;
  for (int kk = k0; kk < kend; kk += 32) {
    *(short8*)&As[row*40 + seg*8] =
        *(const short8*)(A + (size_t)(m0 + row)*WCOL + kk + seg*8);
    *(short8*)&Bs[row*40 + seg*8] =
        *(const short8*)(Bw + (size_t)(n0 + row)*WCOL + kk + seg*8);
    __syncthreads();
    short8 af[2], bf[2];
    #pragma unroll
    for (int mt = 0; mt < 2; ++mt)
      af[mt] = *(const short8*)&As[(wr*32 + mt*16 + col)*40 + quad*8];
    #pragma unroll
    for (int jt = 0; jt < 2; ++jt)
      bf[jt] = *(const short8*)&Bs[(wc*32 + jt*16 + col)*40 + quad*8];
    #pragma unroll
    for (int mt = 0; mt < 2; ++mt)
      #pragma unroll
      for (int jt = 0; jt < 2; ++jt)
        acc[mt][jt] = __builtin_amdgcn_mfma_f32_16x16x32_bf16(af[mt], bf[jt], acc[mt][jt], 0, 0, 0);
    __syncthreads();
  }
  #pragma unroll
  for (int jt = 0; jt < 2; ++jt) {
    int j = n0 + wc*32 + jt*16 + col;
    if (j >= HD) continue;
    #pragma unroll
    for (int mt = 0; mt < 2; ++mt)
      #pragma unroll
      for (int r = 0; r < 4; ++r) {
        int rw = m0 + wr*32 + mt*16 + quad*4 + r;
        P[(size_t)rw*HD + j] = acc[mt][jt][r];
      }
  }
}

// ---------------- node epilogues ----------------
__global__ __launch_bounds__(256) void ep_x1_k(const float* __restrict__ p0,
    const float* __restrict__ p1, float* __restrict__ x1) {
  int idx = blockIdx.x*256 + threadIdx.x;
  if (idx >= NN*HD) return;
  x1[idx] = p0[idx] + p1[idx];
}
__global__ __launch_bounds__(256) void ep_ssp_k(const float* __restrict__ p0,
    const float* __restrict__ p1, const float* __restrict__ bias,
    short* __restrict__ outb) {
  int idx = blockIdx.x*256 + threadIdx.x;
  if (idx >= NN*WCOL) return;
  int row = idx / WCOL, j = idx - row*WCOL;
  short v = 0;
  if (j < HD) {
    size_t o = (size_t)row*HD + j;
    v = f2b(ssp_fast(p0[o] + p1[o] + bias[j]));
  }
  outb[idx] = v;
}
__global__ __launch_bounds__(256) void ep_res_k(const float* __restrict__ p0,
    const float* __restrict__ p1, const float* __restrict__ bias,
    float* __restrict__ h, short* __restrict__ hb) {
  int idx = blockIdx.x*256 + threadIdx.x;
  if (idx >= NN*WCOL) return;
  int row = idx / WCOL, j = idx - row*WCOL;
  short v = 0;
  if (j < HD) {
    size_t o = (size_t)row*HD + j;
    float nv = h[o] + p0[o] + p1[o] + bias[j];
    h[o] = nv;
    v = f2b(nv);
  }
  hb[idx] = v;
}

// ---------------- pooling + output ----------------
__global__ __launch_bounds__(256) void pool_mean_k(const float* __restrict__ h,
                                                   float* __restrict__ pooled) {
  int b = blockIdx.x;
  int c = blockIdx.y*256 + threadIdx.x;
  if (c >= HD) return;
  float s = 0.0f;
  for (int n = 0; n < NPG; ++n) s += h[(size_t)(b*NPG + n)*HD + c];
  pooled[(size_t)b*HD + c] = s * (1.0f/128.0f);
}

__global__ __launch_bounds__(256) void pool_out_k(const float* __restrict__ pooled,
    const float* __restrict__ pw, const float* __restrict__ pb,
    float* __restrict__ out) {
  int b = blockIdx.x;
  int j = blockIdx.y*256 + threadIdx.x;
  if (j >= HD) return;
  float s = pb[j];
  for (int c = 0; c < HD; ++c) s += pooled[(size_t)b*HD + c] * pw[(size_t)c*HD + j];
  out[(size_t)b*HD + j] = s;
}

// ---------------- launch ----------------
extern "C" void kernel_launch(void* const* d_in, const int* in_sizes, int n_in,
                              void* d_out, int out_size, void* d_ws, size_t ws_size,
                              hipStream_t stream) {
  const int*   z    = (const int*)d_in[0];
  const float* pos  = (const float*)d_in[1];
  const float* emb  = (const float*)d_in[2];
  const float* w1   = (const float*)d_in[3];
  const float* b1   = (const float*)d_in[4];
  const float* w2   = (const float*)d_in[5];
  const float* b2   = (const float*)d_in[6];
  const float* l1w  = (const float*)d_in[7];
  const float* l2w  = (const float*)d_in[8];
  const float* l2b  = (const float*)d_in[9];
  const float* ilw  = (const float*)d_in[10];
  const float* ilb  = (const float*)d_in[11];
  const float* pw   = (const float*)d_in[12];
  const float* pb   = (const float*)d_in[13];
  float* ws = (float*)d_ws;
  // workspace layout (float offsets) — total 7,208,960 f = 28.8 MB
  int*   nbr   = (int*)ws;                   // 65536
  float* cv    = ws + 65536;                 // 65536
  float* dist  = ws + 131072;                // 65536
  float* pooled= ws + 196608;                // 8192
  float* h     = ws + 204800;                // 614400
  float* x1    = ws + 819200;                // 614400
  float* msg   = ws + 1433600;               // 614400 (fp32 atomic target)
  short* h_b   = (short*)(ws + 2048000);     // 311296 f
  short* msg_b = (short*)(ws + 2359296);     // 311296 f
  short* mtmp_b= (short*)(ws + 2670592);     // 311296 f
  short* eab   = (short*)(ws + 2981888);     // 2097152 f
  short* w1b   = (short*)(ws + 5079040);     // 122880 f
  short* nwb   = (short*)(ws + 5201920);     // 778240 f
  float* p0    = ws + 5980160;               // 614400
  float* p1    = ws + 6594560;               // 614400
  float* out   = (float*)d_out;

  build_graph_k<<<NN, 128, 0, stream>>>(pos, nbr, dist, cv);
  ea_k<<<(EE*64 + 255)/256, 256, 0, stream>>>(dist, eab);
  conv_w1_k<<<(LL*WROW*64 + 255)/256, 256, 0, stream>>>(w1, w1b);
  embed_k<<<NN, 256, 0, stream>>>(z, emb, h, h_b);

  const size_t WSZ = (size_t)WROW*WCOL;
  dim3 gnode(16, 10, 2);
  int epb608 = (NN*WCOL + 255)/256, epb600 = (NN*HD + 255)/256;
  for (int l = 0; l < LL; ++l) {
    conv_nw_k<<<(4*WROW*WCOL + 255)/256, 256, 0, stream>>>(
        l1w + (size_t)l*360000, l2w + (size_t)l*360000,
        ilw + (size_t)l*360000, w2 + (size_t)l*360000, nwb);
    hipMemsetAsync(msg, 0, (size_t)NN*HD*sizeof(float), stream);
    // x1 = h @ lin1_w[l]
    mfma_nk<<<gnode, 256, 0, stream>>>(h_b, nwb + 0*WSZ, p0, p1);
    ep_x1_k<<<epb600, 256, 0, stream>>>(p0, p1, x1);
    // fused edge pipeline: msg += sum_e C*(ssp(ea@w1+b1)@w2+b2)*x1[nbr]
    fused_edge_k<<<2048, 256, 0, stream>>>(
        eab, w1b + (size_t)l*WROW*64, nwb + 3*WSZ,
        b1 + (size_t)l*HD, b2 + (size_t)l*HD, cv, nbr, x1, msg);
    msg2b_k<<<epb608, 256, 0, stream>>>(msg, msg_b);
    // mtmp_b = bf16(ssp(msg @ lin2_w[l] + lin2_b[l]))
    mfma_nk<<<gnode, 256, 0, stream>>>(msg_b, nwb + 1*WSZ, p0, p1);
    ep_ssp_k<<<epb608, 256, 0, stream>>>(p0, p1, l2b + (size_t)l*HD, mtmp_b);
    // h += mtmp @ int_lin_w[l] + int_lin_b[l]; h_b = bf16(h)
    mfma_nk<<<gnode, 256, 0, stream>>>(mtmp_b, nwb + 2*WSZ, p0, p1);
    ep_res_k<<<epb608, 256, 0, stream>>>(p0, p1, ilb + (size_t)l*HD, h, h_b);
  }
  pool_mean_k<<<dim3(NB, 3), 256, 0, stream>>>(h, pooled);
  pool_out_k<<<dim3(NB, 3), 256, 0, stream>>>(pooled, pw, pb, out);
}

// Round 6
// 781.942 us; speedup vs baseline: 4.3243x; 1.6012x over previous
//
#include <hip/hip_runtime.h>
#include <cmath>

#define NB   8
#define NPG  128
#define NN   1024
#define KNB  64
#define HD   600
#define GG   50
#define LL   6
#define EE   (NN*KNB)     // 65536 edges
#define WROW 640          // padded weight rows (n)
#define WCOL 608          // padded weight cols (k)
#define NKNOT 4096        // W(d) table knots over [0,10]

typedef __attribute__((ext_vector_type(8))) short short8;
typedef __attribute__((ext_vector_type(4))) float f32x4;

__device__ __forceinline__ short f2b(float f) {
  union { float f; unsigned u; } v; v.f = f;
  unsigned u = v.u;
  u += 0x7fffu + ((u >> 16) & 1u);
  return (short)(u >> 16);
}

// fast shifted softplus: max(x,0)+log(1+e^-|x|)-ln2
__device__ __forceinline__ float ssp_fast(float x) {
  return fmaxf(x, 0.0f) + __logf(1.0f + __expf(-fabsf(x))) - 0.69314718055994531f;
}

// ---------------- graph build: one block per node ----------------
__global__ __launch_bounds__(128) void build_graph_k(const float* __restrict__ pos,
        int* __restrict__ nbr, float* __restrict__ dist, float* __restrict__ cval) {
#pragma clang fp contract(off)
  __shared__ float d2s[128];
  __shared__ int scnt;
  int i = blockIdx.x;
  int li = i & 127;
  int base = i - li;
  int j = threadIdx.x;
  if (j == 0) scnt = 0;
  float px = pos[3*i], py = pos[3*i+1], pz = pos[3*i+2];
  int gj = base + j;
  float dx = px - pos[3*gj], dy = py - pos[3*gj+1], dz = pz - pos[3*gj+2];
  float d2 = dx*dx + dy*dy + dz*dz;
  bool valid = (j != li) && (d2 <= 100.0f);
  d2s[j] = valid ? d2 : 3.0e38f;
  __syncthreads();
  if (valid) {
    atomicAdd(&scnt, 1);
    int rank = 0;
    for (int j2 = 0; j2 < 128; ++j2) {
      float o = d2s[j2];
      rank += (o < d2 || (o == d2 && j2 < j)) ? 1 : 0;
    }
    if (rank < KNB) {
      int e = i*KNB + rank;
      nbr[e] = gj;
      float d = sqrtf(d2);
      dist[e] = d;
      cval[e] = 0.5f * (cosf(d * 0.31415926535897931f) + 1.0f);
    }
  }
  __syncthreads();
  int cnt = scnt; if (cnt > KNB) cnt = KNB;
  if (j < KNB && j >= cnt) {
    int e = i*KNB + j;
    nbr[e] = i; dist[e] = 0.0f; cval[e] = 0.0f;
  }
}

// ---------------- d-sample gaussian basis: bf16 [4096][64] ----------------
__global__ __launch_bounds__(256) void dsamp_k(short* __restrict__ basis) {
  int idx = blockIdx.x*256 + threadIdx.x;
  if (idx >= NKNOT*64) return;
  int i = idx >> 6, g = idx & 63;
  float v = 0.0f;
  if (g < GG) {
    const float step = 10.0f/49.0f;
    const float coeff = -0.5f/(step*step);
    float d = (float)i * (10.0f/(float)(NKNOT-1));
    float dd = d - step*(float)g;
    v = __expf(coeff*dd*dd);
  }
  basis[idx] = f2b(v);
}

// ---------------- w1: fp32 [50][600] -> bf16 [640][64], all layers ----------------
__global__ __launch_bounds__(256) void conv_w1_k(const float* __restrict__ w1,
                                                 short* __restrict__ w1b) {
  int idx = blockIdx.x*256 + threadIdx.x;
  if (idx >= LL*WROW*64) return;
  int l = idx / (WROW*64); int rem = idx - l*WROW*64;
  int n = rem >> 6, k = rem & 63;
  float v = (n < HD && k < GG) ? w1[(size_t)l*GG*HD + (size_t)k*HD + n] : 0.0f;
  w1b[idx] = f2b(v);
}

// ---------------- per-layer weights: 4x fp32 [600][600] -> bf16 [4][640][608] ----------------
__global__ __launch_bounds__(256) void conv_nw_k(const float* __restrict__ s0,
    const float* __restrict__ s1, const float* __restrict__ s2,
    const float* __restrict__ s3, short* __restrict__ dst) {
  int idx = blockIdx.x*256 + threadIdx.x;
  if (idx >= 4*WROW*WCOL) return;
  int w = idx / (WROW*WCOL); int rem = idx - w*(WROW*WCOL);
  int n = rem / WCOL, k = rem - n*WCOL;
  float v = 0.0f;
  if (n < HD && k < HD) {
    const float* s = (w == 0) ? s0 : (w == 1) ? s1 : (w == 2) ? s2 : s3;
    v = s[(size_t)k*HD + n];
  }
  dst[idx] = f2b(v);
}

// ---------------- embedding: h fp32 + h_b bf16 ----------------
__global__ __launch_bounds__(256) void embed_k(const int* __restrict__ z,
        const float* __restrict__ emb, float* __restrict__ h, short* __restrict__ hb) {
  int i = blockIdx.x;
  int zi = z[i];
  for (int j = threadIdx.x; j < WCOL; j += 256) {
    float v = (j < HD) ? emb[(size_t)zi*HD + j] : 0.0f;
    if (j < HD) h[(size_t)i*HD + j] = v;
    hb[(size_t)i*WCOL + j] = f2b(v);
  }
}

// ---------------- table GEMM: 128x128 tile, 2x2 waves of 64x64 ----------------
// MODE 0: outb = bf16(ssp(acc+bias)), stride 608, pads zero   (ttab = ssp(basis@w1+b1))
// MODE 2: outf = acc + bias, fp32 stride 600                  (wtab = ttab@w2 + b2)
template<int MODE>
__global__ __launch_bounds__(256) void tab_gemm_k(
    const short* __restrict__ A, int lda, int Kd,
    const short* __restrict__ Bw, int ldb,
    const float* __restrict__ bias,
    short* __restrict__ outb, float* __restrict__ outf) {
  __shared__ __align__(16) short As[128*40];
  __shared__ __align__(16) short Bs[128*40];
  int tid = threadIdx.x;
  int lane = tid & 63, wv = tid >> 6;
  int wr = wv >> 1, wc = wv & 1;
  int col = lane & 15, quad = lane >> 4;
  int m0 = blockIdx.x * 128;
  int n0 = blockIdx.y * 128;
  f32x4 acc[4][4] = {};
  for (int k0 = 0; k0 < Kd; k0 += 32) {
    #pragma unroll
    for (int rep = 0; rep < 2; ++rep) {
      int s = tid + rep*256;
      int row = s >> 2, seg = s & 3;
      *(short8*)&As[row*40 + seg*8] =
          *(const short8*)(A + (size_t)(m0 + row)*lda + k0 + seg*8);
      *(short8*)&Bs[row*40 + seg*8] =
          *(const short8*)(Bw + (size_t)(n0 + row)*ldb + k0 + seg*8);
    }
    __syncthreads();
    short8 af[4], bf[4];
    #pragma unroll
    for (int mt = 0; mt < 4; ++mt)
      af[mt] = *(const short8*)&As[(wr*64 + mt*16 + col)*40 + quad*8];
    #pragma unroll
    for (int jt = 0; jt < 4; ++jt)
      bf[jt] = *(const short8*)&Bs[(wc*64 + jt*16 + col)*40 + quad*8];
    #pragma unroll
    for (int mt = 0; mt < 4; ++mt)
      #pragma unroll
      for (int jt = 0; jt < 4; ++jt)
        acc[mt][jt] = __builtin_amdgcn_mfma_f32_16x16x32_bf16(af[mt], bf[jt], acc[mt][jt], 0, 0, 0);
    __syncthreads();
  }
  if (MODE == 0) {
    #pragma unroll
    for (int jt = 0; jt < 4; ++jt) {
      int j = n0 + wc*64 + jt*16 + col;
      if (j >= WCOL) continue;
      float bj = (j < HD) ? bias[j] : 0.0f;
      #pragma unroll
      for (int mt = 0; mt < 4; ++mt)
        #pragma unroll
        for (int r = 0; r < 4; ++r) {
          int row = m0 + wr*64 + mt*16 + quad*4 + r;
          short v = (j < HD) ? f2b(ssp_fast(acc[mt][jt][r] + bj)) : (short)0;
          outb[(size_t)row*WCOL + j] = v;
        }
    }
  } else {
    #pragma unroll
    for (int jt = 0; jt < 4; ++jt) {
      int j = n0 + wc*64 + jt*16 + col;
      if (j >= HD) continue;
      float bj = bias[j];
      #pragma unroll
      for (int mt = 0; mt < 4; ++mt)
        #pragma unroll
        for (int r = 0; r < 4; ++r) {
          int row = m0 + wr*64 + mt*16 + quad*4 + r;
          outf[(size_t)row*HD + j] = acc[mt][jt][r] + bj;
        }
    }
  }
}

// ---------------- gather: msg[node] = sum_e C_e * Wtab(d_e) (.) x1[nbr_e] ----------------
// one block per node; 320 threads; thread t owns float2 cols j=2t (t<300)
__global__ __launch_bounds__(320) void gather_k(const float* __restrict__ tab,
    const float* __restrict__ cval, const int* __restrict__ nbr,
    const float* __restrict__ dist, const float* __restrict__ x1,
    float* __restrict__ msg) {
  __shared__ float cvs[64];
  __shared__ int nbs[64];
  __shared__ int tix[64];
  __shared__ float tfr[64];
  int node = blockIdx.x, tid = threadIdx.x;
  if (tid < 64) {
    int e = node*KNB + tid;
    cvs[tid] = cval[e];
    nbs[tid] = nbr[e];
    float u = dist[e] * ((float)(NKNOT-1)/10.0f);
    int i = (int)u;
    if (i > NKNOT-2) i = NKNOT-2;
    tix[tid] = i;
    tfr[tid] = u - (float)i;
  }
  __syncthreads();
  int j = tid*2;
  bool ok = j < HD;
  float s0 = 0.0f, s1 = 0.0f;
  #pragma unroll 4
  for (int e = 0; e < KNB; ++e) {
    float Ce = cvs[e];
    if (Ce == 0.0f) continue;              // uniform (shared value)
    if (ok) {
      const float* w0 = tab + (size_t)tix[e]*HD + j;
      float f = tfr[e];
      float2 a = *(const float2*)w0;
      float2 b = *(const float2*)(w0 + HD);
      float2 xv = *(const float2*)(x1 + (size_t)nbs[e]*HD + j);
      s0 += Ce * (a.x + f*(b.x - a.x)) * xv.x;
      s1 += Ce * (a.y + f*(b.y - a.y)) * xv.y;
    }
  }
  if (ok) {
    msg[(size_t)node*HD + j]     = s0;
    msg[(size_t)node*HD + j + 1] = s1;
  }
}

// ---------------- msg fp32 -> bf16 [1024][608] ----------------
__global__ __launch_bounds__(256) void msg2b_k(const float* __restrict__ msg,
                                               short* __restrict__ msgb) {
  int idx = blockIdx.x*256 + threadIdx.x;
  if (idx >= NN*WCOL) return;
  int row = idx / WCOL, j = idx - row*WCOL;
  msgb[idx] = (j < HD) ? f2b(msg[(size_t)row*HD + j]) : (short)0;
}

// ---------------- node GEMM: split-K MFMA, 64x64 tile, grid (16,10,2) ----------------
__global__ __launch_bounds__(256) void mfma_nk(
    const short* __restrict__ A, const short* __restrict__ Bw,
    float* __restrict__ P0, float* __restrict__ P1) {
  __shared__ __align__(16) short As[64*40];
  __shared__ __align__(16) short Bs[64*40];
  int tid = threadIdx.x;
  int lane = tid & 63, wv = tid >> 6;
  int wr = wv >> 1, wc = wv & 1;
  int col = lane & 15, quad = lane >> 4;
  int m0 = blockIdx.x * 64;
  int n0 = blockIdx.y * 64;
  int kz = blockIdx.z;
  int k0 = kz ? 320 : 0;
  int kend = kz ? 608 : 320;
  float* __restrict__ P = kz ? P1 : P0;
  f32x4 acc[2][2] = {};
  int row = tid >> 2, seg = tid & 3;
  for (int kk = k0; kk < kend; kk += 32) {
    *(short8*)&As[row*40 + seg*8] =
        *(const short8*)(A + (size_t)(m0 + row)*WCOL + kk + seg*8);
    *(short8*)&Bs[row*40 + seg*8] =
        *(const short8*)(Bw + (size_t)(n0 + row)*WCOL + kk + seg*8);
    __syncthreads();
    short8 af[2], bf[2];
    #pragma unroll
    for (int mt = 0; mt < 2; ++mt)
      af[mt] = *(const short8*)&As[(wr*32 + mt*16 + col)*40 + quad*8];
    #pragma unroll
    for (int jt = 0; jt < 2; ++jt)
      bf[jt] = *(const short8*)&Bs[(wc*32 + jt*16 + col)*40 + quad*8];
    #pragma unroll
    for (int mt = 0; mt < 2; ++mt)
      #pragma unroll
      for (int jt = 0; jt < 2; ++jt)
        acc[mt][jt] = __builtin_amdgcn_mfma_f32_16x16x32_bf16(af[mt], bf[jt], acc[mt][jt], 0, 0, 0);
    __syncthreads();
  }
  #pragma unroll
  for (int jt = 0; jt < 2; ++jt) {
    int j = n0 + wc*32 + jt*16 + col;
    if (j >= HD) continue;
    #pragma unroll
    for (int mt = 0; mt < 2; ++mt)
      #pragma unroll
      for (int r = 0; r < 4; ++r) {
        int rw = m0 + wr*32 + mt*16 + quad*4 + r;
        P[(size_t)rw*HD + j] = acc[mt][jt][r];
      }
  }
}

// ---------------- node epilogues ----------------
__global__ __launch_bounds__(256) void ep_x1_k(const float* __restrict__ p0,
    const float* __restrict__ p1, float* __restrict__ x1) {
  int idx = blockIdx.x*256 + threadIdx.x;
  if (idx >= NN*HD) return;
  x1[idx] = p0[idx] + p1[idx];
}
__global__ __launch_bounds__(256) void ep_ssp_k(const float* __restrict__ p0,
    const float* __restrict__ p1, const float* __restrict__ bias,
    short* __restrict__ outb) {
  int idx = blockIdx.x*256 + threadIdx.x;
  if (idx >= NN*WCOL) return;
  int row = idx / WCOL, j = idx - row*WCOL;
  short v = 0;
  if (j < HD) {
    size_t o = (size_t)row*HD + j;
    v = f2b(ssp_fast(p0[o] + p1[o] + bias[j]));
  }
  outb[idx] = v;
}
__global__ __launch_bounds__(256) void ep_res_k(const float* __restrict__ p0,
    const float* __restrict__ p1, const float* __restrict__ bias,
    float* __restrict__ h, short* __restrict__ hb) {
  int idx = blockIdx.x*256 + threadIdx.x;
  if (idx >= NN*WCOL) return;
  int row = idx / WCOL, j = idx - row*WCOL;
  short v = 0;
  if (j < HD) {
    size_t o = (size_t)row*HD + j;
    float nv = h[o] + p0[o] + p1[o] + bias[j];
    h[o] = nv;
    v = f2b(nv);
  }
  hb[idx] = v;
}

// ---------------- pooling + output ----------------
__global__ __launch_bounds__(256) void pool_mean_k(const float* __restrict__ h,
                                                   float* __restrict__ pooled) {
  int b = blockIdx.x;
  int c = blockIdx.y*256 + threadIdx.x;
  if (c >= HD) return;
  float s = 0.0f;
  for (int n = 0; n < NPG; ++n) s += h[(size_t)(b*NPG + n)*HD + c];
  pooled[(size_t)b*HD + c] = s * (1.0f/128.0f);
}

__global__ __launch_bounds__(256) void pool_out_k(const float* __restrict__ pooled,
    const float* __restrict__ pw, const float* __restrict__ pb,
    float* __restrict__ out) {
  int b = blockIdx.x;
  int j = blockIdx.y*256 + threadIdx.x;
  if (j >= HD) return;
  float s = pb[j];
  for (int c = 0; c < HD; ++c) s += pooled[(size_t)b*HD + c] * pw[(size_t)c*HD + j];
  out[(size_t)b*HD + j] = s;
}

// ---------------- launch ----------------
extern "C" void kernel_launch(void* const* d_in, const int* in_sizes, int n_in,
                              void* d_out, int out_size, void* d_ws, size_t ws_size,
                              hipStream_t stream) {
  const int*   z    = (const int*)d_in[0];
  const float* pos  = (const float*)d_in[1];
  const float* emb  = (const float*)d_in[2];
  const float* w1   = (const float*)d_in[3];
  const float* b1   = (const float*)d_in[4];
  const float* w2   = (const float*)d_in[5];
  const float* b2   = (const float*)d_in[6];
  const float* l1w  = (const float*)d_in[7];
  const float* l2w  = (const float*)d_in[8];
  const float* l2b  = (const float*)d_in[9];
  const float* ilw  = (const float*)d_in[10];
  const float* ilb  = (const float*)d_in[11];
  const float* pw   = (const float*)d_in[12];
  const float* pb   = (const float*)d_in[13];
  float* ws = (float*)d_ws;
  // workspace layout (float offsets) — total 8,945,664 f = 35.8 MB
  int*   nbr   = (int*)ws;                   // 65536
  float* cv    = ws + 65536;                 // 65536
  float* dist  = ws + 131072;                // 65536
  float* pooled= ws + 196608;                // 8192
  float* h     = ws + 204800;                // 614400
  float* x1    = ws + 819200;                // 614400
  float* msg   = ws + 1433600;               // 614400
  short* h_b   = (short*)(ws + 2048000);     // 311296 f
  short* msg_b = (short*)(ws + 2359296);     // 311296 f
  short* mtmp_b= (short*)(ws + 2670592);     // 311296 f
  short* basis = (short*)(ws + 2981888);     // 4096*64 shorts = 131072 f
  short* ttab  = (short*)(ws + 3112960);     // 4096*608 shorts = 1245184 f
  float* wtab  = ws + 4358144;               // 4096*600 = 2457600 f
  short* w1b   = (short*)(ws + 6815744);     // 122880 f
  short* nwb   = (short*)(ws + 6938624);     // 778240 f
  float* p0    = ws + 7716864;               // 614400
  float* p1    = ws + 8331264;               // 614400
  float* out   = (float*)d_out;

  build_graph_k<<<NN, 128, 0, stream>>>(pos, nbr, dist, cv);
  dsamp_k<<<(NKNOT*64 + 255)/256, 256, 0, stream>>>(basis);
  conv_w1_k<<<(LL*WROW*64 + 255)/256, 256, 0, stream>>>(w1, w1b);
  embed_k<<<NN, 256, 0, stream>>>(z, emb, h, h_b);

  const size_t WSZ = (size_t)WROW*WCOL;
  dim3 gnode(16, 10, 2), gtab(32, 5);
  int epb608 = (NN*WCOL + 255)/256, epb600 = (NN*HD + 255)/256;
  for (int l = 0; l < LL; ++l) {
    conv_nw_k<<<(4*WROW*WCOL + 255)/256, 256, 0, stream>>>(
        l1w + (size_t)l*360000, l2w + (size_t)l*360000,
        ilw + (size_t)l*360000, w2 + (size_t)l*360000, nwb);
    // x1 = h @ lin1_w[l]
    mfma_nk<<<gnode, 256, 0, stream>>>(h_b, nwb + 0*WSZ, p0, p1);
    ep_x1_k<<<epb600, 256, 0, stream>>>(p0, p1, x1);
    // W(d) table: ttab = ssp(basis@w1+b1); wtab = ttab@w2 + b2
    tab_gemm_k<0><<<gtab, 256, 0, stream>>>(basis, 64, 64,
        w1b + (size_t)l*WROW*64, 64, b1 + (size_t)l*HD, ttab, nullptr);
    tab_gemm_k<2><<<gtab, 256, 0, stream>>>(ttab, WCOL, WCOL,
        nwb + 3*WSZ, WCOL, b2 + (size_t)l*HD, nullptr, wtab);
    // msg[node] = sum_e C_e * Wtab(d_e) (.) x1[nbr_e]
    gather_k<<<NN, 320, 0, stream>>>(wtab, cv, nbr, dist, x1, msg);
    msg2b_k<<<epb608, 256, 0, stream>>>(msg, msg_b);
    // mtmp_b = bf16(ssp(msg @ lin2_w[l] + lin2_b[l]))
    mfma_nk<<<gnode, 256, 0, stream>>>(msg_b, nwb + 1*WSZ, p0, p1);
    ep_ssp_k<<<epb608, 256, 0, stream>>>(p0, p1, l2b + (size_t)l*HD, mtmp_b);
    // h += mtmp @ int_lin_w[l] + int_lin_b[l]; h_b = bf16(h)
    mfma_nk<<<gnode, 256, 0, stream>>>(mtmp_b, nwb + 2*WSZ, p0, p1);
    ep_res_k<<<epb608, 256, 0, stream>>>(p0, p1, ilb + (size_t)l*HD, h, h_b);
  }
  pool_mean_k<<<dim3(NB, 3), 256, 0, stream>>>(h, pooled);
  pool_out_k<<<dim3(NB, 3), 256, 0, stream>>>(pooled, pw, pb, out);
}

// Round 7
// 627.149 us; speedup vs baseline: 5.3916x; 1.2468x over previous
//
#include <hip/hip_runtime.h>
#include <cmath>

#define NB   8
#define NPG  128
#define NN   1024
#define KNB  64
#define HD   600
#define GG   50
#define LL   6
#define EE   (NN*KNB)     // 65536 edges
#define WROW 640          // padded weight rows (n)
#define WCOL 608          // padded weight cols (k)
#define NKNOT 2048        // W(d) table knots over [0,10]

typedef __attribute__((ext_vector_type(8))) short short8;
typedef __attribute__((ext_vector_type(4))) float f32x4;

__device__ __forceinline__ short f2b(float f) {
  union { float f; unsigned u; } v; v.f = f;
  unsigned u = v.u;
  u += 0x7fffu + ((u >> 16) & 1u);
  return (short)(u >> 16);
}

// fast shifted softplus: max(x,0)+log(1+e^-|x|)-ln2
__device__ __forceinline__ float ssp_fast(float x) {
  return fmaxf(x, 0.0f) + __logf(1.0f + __expf(-fabsf(x))) - 0.69314718055994531f;
}

// ---------------- graph build: one block per node ----------------
__global__ __launch_bounds__(128) void build_graph_k(const float* __restrict__ pos,
        int* __restrict__ nbr, float* __restrict__ dist, float* __restrict__ cval) {
#pragma clang fp contract(off)
  __shared__ float d2s[128];
  __shared__ int scnt;
  int i = blockIdx.x;
  int li = i & 127;
  int base = i - li;
  int j = threadIdx.x;
  if (j == 0) scnt = 0;
  float px = pos[3*i], py = pos[3*i+1], pz = pos[3*i+2];
  int gj = base + j;
  float dx = px - pos[3*gj], dy = py - pos[3*gj+1], dz = pz - pos[3*gj+2];
  float d2 = dx*dx + dy*dy + dz*dz;
  bool valid = (j != li) && (d2 <= 100.0f);
  d2s[j] = valid ? d2 : 3.0e38f;
  __syncthreads();
  if (valid) {
    atomicAdd(&scnt, 1);
    int rank = 0;
    for (int j2 = 0; j2 < 128; ++j2) {
      float o = d2s[j2];
      rank += (o < d2 || (o == d2 && j2 < j)) ? 1 : 0;
    }
    if (rank < KNB) {
      int e = i*KNB + rank;
      nbr[e] = gj;
      float d = sqrtf(d2);
      dist[e] = d;
      cval[e] = 0.5f * (cosf(d * 0.31415926535897931f) + 1.0f);
    }
  }
  __syncthreads();
  int cnt = scnt; if (cnt > KNB) cnt = KNB;
  if (j < KNB && j >= cnt) {
    int e = i*KNB + j;
    nbr[e] = i; dist[e] = 0.0f; cval[e] = 0.0f;
  }
}

// ---------------- d-sample gaussian basis: bf16 [NKNOT][64] ----------------
__global__ __launch_bounds__(256) void dsamp_k(short* __restrict__ basis) {
  int idx = blockIdx.x*256 + threadIdx.x;
  if (idx >= NKNOT*64) return;
  int i = idx >> 6, g = idx & 63;
  float v = 0.0f;
  if (g < GG) {
    const float step = 10.0f/49.0f;
    const float coeff = -0.5f/(step*step);
    float d = (float)i * (10.0f/(float)(NKNOT-1));
    float dd = d - step*(float)g;
    v = __expf(coeff*dd*dd);
  }
  basis[idx] = f2b(v);
}

// ---------------- w1: fp32 [50][600] -> bf16 [640][64], all layers ----------------
__global__ __launch_bounds__(256) void conv_w1_k(const float* __restrict__ w1,
                                                 short* __restrict__ w1b) {
  int idx = blockIdx.x*256 + threadIdx.x;
  if (idx >= LL*WROW*64) return;
  int l = idx / (WROW*64); int rem = idx - l*WROW*64;
  int n = rem >> 6, k = rem & 63;
  float v = (n < HD && k < GG) ? w1[(size_t)l*GG*HD + (size_t)k*HD + n] : 0.0f;
  w1b[idx] = f2b(v);
}

// ---------------- all node/w2 weights: 24x fp32 [600][600] -> bf16 [640][608] ----------------
// layout: kind (0=l1w,1=l2w,2=ilw,3=w2) major, layer minor
__global__ __launch_bounds__(256) void conv_all_k(const float* __restrict__ l1w,
    const float* __restrict__ l2w, const float* __restrict__ ilw,
    const float* __restrict__ w2, short* __restrict__ dst) {
  int idx = blockIdx.x*256 + threadIdx.x;
  if (idx >= 24*WROW*WCOL) return;
  int w = idx / (WROW*WCOL); int rem = idx - w*(WROW*WCOL);
  int n = rem / WCOL, k = rem - n*WCOL;
  int kind = w / 6, l = w - kind*6;
  float v = 0.0f;
  if (n < HD && k < HD) {
    const float* s = (kind == 0) ? l1w : (kind == 1) ? l2w : (kind == 2) ? ilw : w2;
    v = s[(size_t)l*360000 + (size_t)k*HD + n];
  }
  dst[idx] = f2b(v);
}

// ---------------- embedding: h fp32 + h_b bf16 ----------------
__global__ __launch_bounds__(256) void embed_k(const int* __restrict__ z,
        const float* __restrict__ emb, float* __restrict__ h, short* __restrict__ hb) {
  int i = blockIdx.x;
  int zi = z[i];
  for (int j = threadIdx.x; j < WCOL; j += 256) {
    float v = (j < HD) ? emb[(size_t)zi*HD + j] : 0.0f;
    if (j < HD) h[(size_t)i*HD + j] = v;
    hb[(size_t)i*WCOL + j] = f2b(v);
  }
}

// ---------------- tabA: ttab_all[l] = bf16(ssp(basis@w1[l]+b1[l])) ----------------
// 128x128 tiles, all layers in one grid: blockIdx.x = l*(NKNOT/128)+mb
__global__ __launch_bounds__(256) void tabA_k(const short* __restrict__ basis,
    const short* __restrict__ w1b, const float* __restrict__ b1all,
    short* __restrict__ ttab_all) {
  const int MT = NKNOT/128;
  int l = blockIdx.x / MT;
  int mb = blockIdx.x - l*MT;
  const short* Bw = w1b + (size_t)l*WROW*64;
  const float* bias = b1all + (size_t)l*HD;
  short* outb = ttab_all + (size_t)l*NKNOT*WCOL;
  __shared__ __align__(16) short As[128*40];
  __shared__ __align__(16) short Bs[128*40];
  int tid = threadIdx.x;
  int lane = tid & 63, wv = tid >> 6;
  int wr = wv >> 1, wc = wv & 1;
  int col = lane & 15, quad = lane >> 4;
  int m0 = mb * 128;
  int n0 = blockIdx.y * 128;
  f32x4 acc[4][4] = {};
  for (int k0 = 0; k0 < 64; k0 += 32) {
    #pragma unroll
    for (int rep = 0; rep < 2; ++rep) {
      int s = tid + rep*256;
      int row = s >> 2, seg = s & 3;
      *(short8*)&As[row*40 + seg*8] =
          *(const short8*)(basis + (size_t)(m0 + row)*64 + k0 + seg*8);
      *(short8*)&Bs[row*40 + seg*8] =
          *(const short8*)(Bw + (size_t)(n0 + row)*64 + k0 + seg*8);
    }
    __syncthreads();
    short8 af[4], bf[4];
    #pragma unroll
    for (int mt = 0; mt < 4; ++mt)
      af[mt] = *(const short8*)&As[(wr*64 + mt*16 + col)*40 + quad*8];
    #pragma unroll
    for (int jt = 0; jt < 4; ++jt)
      bf[jt] = *(const short8*)&Bs[(wc*64 + jt*16 + col)*40 + quad*8];
    #pragma unroll
    for (int mt = 0; mt < 4; ++mt)
      #pragma unroll
      for (int jt = 0; jt < 4; ++jt)
        acc[mt][jt] = __builtin_amdgcn_mfma_f32_16x16x32_bf16(af[mt], bf[jt], acc[mt][jt], 0, 0, 0);
    __syncthreads();
  }
  #pragma unroll
  for (int jt = 0; jt < 4; ++jt) {
    int j = n0 + wc*64 + jt*16 + col;
    if (j >= WCOL) continue;
    float bj = (j < HD) ? b1all[(size_t)l*HD + j] : 0.0f;
    #pragma unroll
    for (int mt = 0; mt < 4; ++mt)
      #pragma unroll
      for (int r = 0; r < 4; ++r) {
        int row = m0 + wr*64 + mt*16 + quad*4 + r;
        short v = (j < HD) ? f2b(ssp_fast(acc[mt][jt][r] + bj)) : (short)0;
        outb[(size_t)row*WCOL + j] = v;
      }
  }
  (void)bias;
}

// ---------------- tabB: wtab_all[l] = ttab_all[l]@w2[l] + b2[l], fp32 ----------------
// 64x64 tiles (2x2 waves of 32x32), K=608, all layers: blockIdx.x = l*(NKNOT/64)+mb
__global__ __launch_bounds__(256) void tabB_k(const short* __restrict__ ttab_all,
    const short* __restrict__ nwall, const float* __restrict__ b2all,
    float* __restrict__ wtab_all) {
  const int MT = NKNOT/64;
  int l = blockIdx.x / MT;
  int mb = blockIdx.x - l*MT;
  const short* A  = ttab_all + (size_t)l*NKNOT*WCOL;
  const short* Bw = nwall + (size_t)(18 + l)*WROW*WCOL;   // kind=3 (w2)
  float* P = wtab_all + (size_t)l*NKNOT*HD;
  __shared__ __align__(16) short As[64*40];
  __shared__ __align__(16) short Bs[64*40];
  int tid = threadIdx.x;
  int lane = tid & 63, wv = tid >> 6;
  int wr = wv >> 1, wc = wv & 1;
  int col = lane & 15, quad = lane >> 4;
  int m0 = mb * 64;
  int n0 = blockIdx.y * 64;
  f32x4 acc[2][2] = {};
  int row = tid >> 2, seg = tid & 3;
  for (int kk = 0; kk < WCOL; kk += 32) {
    *(short8*)&As[row*40 + seg*8] =
        *(const short8*)(A + (size_t)(m0 + row)*WCOL + kk + seg*8);
    *(short8*)&Bs[row*40 + seg*8] =
        *(const short8*)(Bw + (size_t)(n0 + row)*WCOL + kk + seg*8);
    __syncthreads();
    short8 af[2], bf[2];
    #pragma unroll
    for (int mt = 0; mt < 2; ++mt)
      af[mt] = *(const short8*)&As[(wr*32 + mt*16 + col)*40 + quad*8];
    #pragma unroll
    for (int jt = 0; jt < 2; ++jt)
      bf[jt] = *(const short8*)&Bs[(wc*32 + jt*16 + col)*40 + quad*8];
    #pragma unroll
    for (int mt = 0; mt < 2; ++mt)
      #pragma unroll
      for (int jt = 0; jt < 2; ++jt)
        acc[mt][jt] = __builtin_amdgcn_mfma_f32_16x16x32_bf16(af[mt], bf[jt], acc[mt][jt], 0, 0, 0);
    __syncthreads();
  }
  #pragma unroll
  for (int jt = 0; jt < 2; ++jt) {
    int j = n0 + wc*32 + jt*16 + col;
    if (j >= HD) continue;
    float bj = b2all[(size_t)l*HD + j];
    #pragma unroll
    for (int mt = 0; mt < 2; ++mt)
      #pragma unroll
      for (int r = 0; r < 4; ++r) {
        int rw = m0 + wr*32 + mt*16 + quad*4 + r;
        P[(size_t)rw*HD + j] = acc[mt][jt][r] + bj;
      }
  }
}

// ---------------- gather: msg_b[node] = bf16(sum_e C_e * Wtab(d_e) (.) x1[nbr_e]) ----------------
__global__ __launch_bounds__(320) void gather_k(const float* __restrict__ tab,
    const float* __restrict__ cval, const int* __restrict__ nbr,
    const float* __restrict__ dist, const float* __restrict__ x1,
    short* __restrict__ msgb) {
  __shared__ float cvs[64];
  __shared__ int nbs[64];
  __shared__ int tix[64];
  __shared__ float tfr[64];
  int node = blockIdx.x, tid = threadIdx.x;
  if (tid < 64) {
    int e = node*KNB + tid;
    cvs[tid] = cval[e];
    nbs[tid] = nbr[e];
    float u = dist[e] * ((float)(NKNOT-1)/10.0f);
    int i = (int)u;
    if (i > NKNOT-2) i = NKNOT-2;
    tix[tid] = i;
    tfr[tid] = u - (float)i;
  }
  __syncthreads();
  int j = tid*2;
  if (j >= WCOL) return;
  if (j >= HD) {                       // zero the bf16 pads
    *(unsigned*)&msgb[(size_t)node*WCOL + j] = 0u;
    return;
  }
  float s0 = 0.0f, s1 = 0.0f;
  #pragma unroll 4
  for (int e = 0; e < KNB; ++e) {
    float Ce = cvs[e];
    if (Ce == 0.0f) continue;          // uniform per-wave (shared value)
    const float* w0 = tab + (size_t)tix[e]*HD + j;
    float f = tfr[e];
    float2 a = *(const float2*)w0;
    float2 b = *(const float2*)(w0 + HD);
    float2 xv = *(const float2*)(x1 + (size_t)nbs[e]*HD + j);
    s0 += Ce * (a.x + f*(b.x - a.x)) * xv.x;
    s1 += Ce * (a.y + f*(b.y - a.y)) * xv.y;
  }
  unsigned pack = (unsigned)(unsigned short)f2b(s0) | ((unsigned)(unsigned short)f2b(s1) << 16);
  *(unsigned*)&msgb[(size_t)node*WCOL + j] = pack;
}

// ---------------- node GEMM: split-K MFMA, 64x64 tile, grid (16,10,2) ----------------
__global__ __launch_bounds__(256) void mfma_nk(
    const short* __restrict__ A, const short* __restrict__ Bw,
    float* __restrict__ P0, float* __restrict__ P1) {
  __shared__ __align__(16) short As[64*40];
  __shared__ __align__(16) short Bs[64*40];
  int tid = threadIdx.x;
  int lane = tid & 63, wv = tid >> 6;
  int wr = wv >> 1, wc = wv & 1;
  int col = lane & 15, quad = lane >> 4;
  int m0 = blockIdx.x * 64;
  int n0 = blockIdx.y * 64;
  int kz = blockIdx.z;
  int k0 = kz ? 320 : 0;
  int kend = kz ? 608 : 320;
  float* __restrict__ P = kz ? P1 : P0;
  f32x4 acc[2][2] = {};
  int row = tid >> 2, seg = tid & 3;
  for (int kk = k0; kk < kend; kk += 32) {
    *(short8*)&As[row*40 + seg*8] =
        *(const short8*)(A + (size_t)(m0 + row)*WCOL + kk + seg*8);
    *(short8*)&Bs[row*40 + seg*8] =
        *(const short8*)(Bw + (size_t)(n0 + row)*WCOL + kk + seg*8);
    __syncthreads();
    short8 af[2], bf[2];
    #pragma unroll
    for (int mt = 0; mt < 2; ++mt)
      af[mt] = *(const short8*)&As[(wr*32 + mt*16 + col)*40 + quad*8];
    #pragma unroll
    for (int jt = 0; jt < 2; ++jt)
      bf[jt] = *(const short8*)&Bs[(wc*32 + jt*16 + col)*40 + quad*8];
    #pragma unroll
    for (int mt = 0; mt < 2; ++mt)
      #pragma unroll
      for (int jt = 0; jt < 2; ++jt)
        acc[mt][jt] = __builtin_amdgcn_mfma_f32_16x16x32_bf16(af[mt], bf[jt], acc[mt][jt], 0, 0, 0);
    __syncthreads();
  }
  #pragma unroll
  for (int jt = 0; jt < 2; ++jt) {
    int j = n0 + wc*32 + jt*16 + col;
    if (j >= HD) continue;
    #pragma unroll
    for (int mt = 0; mt < 2; ++mt)
      #pragma unroll
      for (int r = 0; r < 4; ++r) {
        int rw = m0 + wr*32 + mt*16 + quad*4 + r;
        P[(size_t)rw*HD + j] = acc[mt][jt][r];
      }
  }
}

// ---------------- node epilogues ----------------
__global__ __launch_bounds__(256) void ep_x1_k(const float* __restrict__ p0,
    const float* __restrict__ p1, float* __restrict__ x1) {
  int idx = blockIdx.x*256 + threadIdx.x;
  if (idx >= NN*HD) return;
  x1[idx] = p0[idx] + p1[idx];
}
__global__ __launch_bounds__(256) void ep_ssp_k(const float* __restrict__ p0,
    const float* __restrict__ p1, const float* __restrict__ bias,
    short* __restrict__ outb) {
  int idx = blockIdx.x*256 + threadIdx.x;
  if (idx >= NN*WCOL) return;
  int row = idx / WCOL, j = idx - row*WCOL;
  short v = 0;
  if (j < HD) {
    size_t o = (size_t)row*HD + j;
    v = f2b(ssp_fast(p0[o] + p1[o] + bias[j]));
  }
  outb[idx] = v;
}
__global__ __launch_bounds__(256) void ep_res_k(const float* __restrict__ p0,
    const float* __restrict__ p1, const float* __restrict__ bias,
    float* __restrict__ h, short* __restrict__ hb) {
  int idx = blockIdx.x*256 + threadIdx.x;
  if (idx >= NN*WCOL) return;
  int row = idx / WCOL, j = idx - row*WCOL;
  short v = 0;
  if (j < HD) {
    size_t o = (size_t)row*HD + j;
    float nv = h[o] + p0[o] + p1[o] + bias[j];
    h[o] = nv;
    v = f2b(nv);
  }
  hb[idx] = v;
}

// ---------------- pooling + output ----------------
__global__ __launch_bounds__(256) void pool_mean_k(const float* __restrict__ h,
                                                   float* __restrict__ pooled) {
  int b = blockIdx.x;
  int c = blockIdx.y*256 + threadIdx.x;
  if (c >= HD) return;
  float s = 0.0f;
  for (int n = 0; n < NPG; ++n) s += h[(size_t)(b*NPG + n)*HD + c];
  pooled[(size_t)b*HD + c] = s * (1.0f/128.0f);
}

// grid (3, 8); pooled row in LDS, pw reads coalesced across lanes
__global__ __launch_bounds__(256) void pool_out_k(const float* __restrict__ pooled,
    const float* __restrict__ pw, const float* __restrict__ pb,
    float* __restrict__ out) {
  __shared__ float ps[HD];
  int b = blockIdx.y;
  int tid = threadIdx.x;
  for (int c = tid; c < HD; c += 256) ps[c] = pooled[(size_t)b*HD + c];
  __syncthreads();
  int j = blockIdx.x*256 + tid;
  if (j >= HD) return;
  float s = pb[j];
  #pragma unroll 4
  for (int c = 0; c < HD; ++c) s += ps[c] * pw[(size_t)c*HD + j];
  out[(size_t)b*HD + j] = s;
}

// ---------------- launch ----------------
extern "C" void kernel_launch(void* const* d_in, const int* in_sizes, int n_in,
                              void* d_out, int out_size, void* d_ws, size_t ws_size,
                              hipStream_t stream) {
  const int*   z    = (const int*)d_in[0];
  const float* pos  = (const float*)d_in[1];
  const float* emb  = (const float*)d_in[2];
  const float* w1   = (const float*)d_in[3];
  const float* b1   = (const float*)d_in[4];
  const float* w2   = (const float*)d_in[5];
  const float* b2   = (const float*)d_in[6];
  const float* l1w  = (const float*)d_in[7];
  const float* l2w  = (const float*)d_in[8];
  const float* l2b  = (const float*)d_in[9];
  const float* ilw  = (const float*)d_in[10];
  const float* ilb  = (const float*)d_in[11];
  const float* pw   = (const float*)d_in[12];
  const float* pb   = (const float*)d_in[13];
  float* ws = (float*)d_ws;
  // workspace layout (float offsets) — total 19,562,496 f = 78.2 MB (ws >= 106 MB proven R4)
  int*   nbr   = (int*)ws;                   // 65536
  float* cv    = ws + 65536;                 // 65536
  float* dist  = ws + 131072;                // 65536
  float* pooled= ws + 196608;                // 8192
  float* h     = ws + 204800;                // 614400
  float* x1    = ws + 819200;                // 614400
  short* h_b   = (short*)(ws + 1433600);     // 311296 f
  short* msg_b = (short*)(ws + 1744896);     // 311296 f
  short* mtmp_b= (short*)(ws + 2056192);     // 311296 f
  short* basis = (short*)(ws + 2367488);     // 2048*64 sh = 65536 f
  short* ttab  = (short*)(ws + 2433024);     // 6*2048*608 sh = 3735552 f
  float* wtab  = ws + 6168576;               // 6*2048*600 f = 7372800 f
  short* w1b   = (short*)(ws + 13541376);    // 6*640*64 sh = 122880 f
  short* nwall = (short*)(ws + 13664256);    // 24*640*608 sh = 4669440 f
  float* p0    = ws + 18333696;              // 614400
  float* p1    = ws + 18948096;              // 614400
  float* out   = (float*)d_out;

  const size_t WSZ = (size_t)WROW*WCOL;

  build_graph_k<<<NN, 128, 0, stream>>>(pos, nbr, dist, cv);
  dsamp_k<<<(NKNOT*64 + 255)/256, 256, 0, stream>>>(basis);
  conv_w1_k<<<(LL*WROW*64 + 255)/256, 256, 0, stream>>>(w1, w1b);
  conv_all_k<<<(24*WROW*WCOL + 255)/256, 256, 0, stream>>>(l1w, l2w, ilw, w2, nwall);
  embed_k<<<NN, 256, 0, stream>>>(z, emb, h, h_b);

  // batched W(d) tables for all layers (independent of h)
  tabA_k<<<dim3(LL*(NKNOT/128), 5), 256, 0, stream>>>(basis, w1b, b1, ttab);
  tabB_k<<<dim3(LL*(NKNOT/64), 10), 256, 0, stream>>>(ttab, nwall, b2, wtab);

  dim3 gnode(16, 10, 2);
  int epb608 = (NN*WCOL + 255)/256, epb600 = (NN*HD + 255)/256;
  for (int l = 0; l < LL; ++l) {
    // x1 = h @ lin1_w[l]
    mfma_nk<<<gnode, 256, 0, stream>>>(h_b, nwall + (size_t)(0*6 + l)*WSZ, p0, p1);
    ep_x1_k<<<epb600, 256, 0, stream>>>(p0, p1, x1);
    // msg_b[node] = bf16(sum_e C_e * Wtab(d_e) (.) x1[nbr_e])
    gather_k<<<NN, 320, 0, stream>>>(wtab + (size_t)l*NKNOT*HD, cv, nbr, dist, x1, msg_b);
    // mtmp_b = bf16(ssp(msg @ lin2_w[l] + lin2_b[l]))
    mfma_nk<<<gnode, 256, 0, stream>>>(msg_b, nwall + (size_t)(1*6 + l)*WSZ, p0, p1);
    ep_ssp_k<<<epb608, 256, 0, stream>>>(p0, p1, l2b + (size_t)l*HD, mtmp_b);
    // h += mtmp @ int_lin_w[l] + int_lin_b[l]; h_b = bf16(h)
    mfma_nk<<<gnode, 256, 0, stream>>>(mtmp_b, nwall + (size_t)(2*6 + l)*WSZ, p0, p1);
    ep_res_k<<<epb608, 256, 0, stream>>>(p0, p1, ilb + (size_t)l*HD, h, h_b);
  }
  pool_mean_k<<<dim3(NB, 3), 256, 0, stream>>>(h, pooled);
  pool_out_k<<<dim3(3, NB), 256, 0, stream>>>(pooled, pw, pb, out);
}

// Round 8
// 543.390 us; speedup vs baseline: 6.2227x; 1.1541x over previous
//
#include <hip/hip_runtime.h>
#include <cmath>

#define NB   8
#define NPG  128
#define NN   1024
#define KNB  64
#define HD   600
#define GG   50
#define LL   6
#define EE   (NN*KNB)     // 65536 edges
#define WROW 640          // padded weight rows (n)
#define WCOL 608          // padded weight cols (k)
#define NKNOT 2048        // W(d) table knots over [0,10]

typedef __attribute__((ext_vector_type(8))) short short8;
typedef __attribute__((ext_vector_type(4))) short short4v;
typedef __attribute__((ext_vector_type(4))) float f32x4;

__device__ __forceinline__ short f2b(float f) {
  union { float f; unsigned u; } v; v.f = f;
  unsigned u = v.u;
  u += 0x7fffu + ((u >> 16) & 1u);
  return (short)(u >> 16);
}

// fast shifted softplus: max(x,0)+log(1+e^-|x|)-ln2
__device__ __forceinline__ float ssp_fast(float x) {
  return fmaxf(x, 0.0f) + __logf(1.0f + __expf(-fabsf(x))) - 0.69314718055994531f;
}

// ---------------- graph build: one block per node ----------------
__global__ __launch_bounds__(128) void build_graph_k(const float* __restrict__ pos,
        int* __restrict__ nbr, float* __restrict__ dist, float* __restrict__ cval) {
#pragma clang fp contract(off)
  __shared__ float d2s[128];
  __shared__ int scnt;
  int i = blockIdx.x;
  int li = i & 127;
  int base = i - li;
  int j = threadIdx.x;
  if (j == 0) scnt = 0;
  float px = pos[3*i], py = pos[3*i+1], pz = pos[3*i+2];
  int gj = base + j;
  float dx = px - pos[3*gj], dy = py - pos[3*gj+1], dz = pz - pos[3*gj+2];
  float d2 = dx*dx + dy*dy + dz*dz;
  bool valid = (j != li) && (d2 <= 100.0f);
  d2s[j] = valid ? d2 : 3.0e38f;
  __syncthreads();
  if (valid) {
    atomicAdd(&scnt, 1);
    int rank = 0;
    for (int j2 = 0; j2 < 128; ++j2) {
      float o = d2s[j2];
      rank += (o < d2 || (o == d2 && j2 < j)) ? 1 : 0;
    }
    if (rank < KNB) {
      int e = i*KNB + rank;
      nbr[e] = gj;
      float d = sqrtf(d2);
      dist[e] = d;
      cval[e] = 0.5f * (cosf(d * 0.31415926535897931f) + 1.0f);
    }
  }
  __syncthreads();
  int cnt = scnt; if (cnt > KNB) cnt = KNB;
  if (j < KNB && j >= cnt) {
    int e = i*KNB + j;
    nbr[e] = i; dist[e] = 0.0f; cval[e] = 0.0f;
  }
}

// ---------------- d-sample gaussian basis: bf16 [NKNOT][64] ----------------
__global__ __launch_bounds__(256) void dsamp_k(short* __restrict__ basis) {
  int idx = blockIdx.x*256 + threadIdx.x;
  if (idx >= NKNOT*64) return;
  int i = idx >> 6, g = idx & 63;
  float v = 0.0f;
  if (g < GG) {
    const float step = 10.0f/49.0f;
    const float coeff = -0.5f/(step*step);
    float d = (float)i * (10.0f/(float)(NKNOT-1));
    float dd = d - step*(float)g;
    v = __expf(coeff*dd*dd);
  }
  basis[idx] = f2b(v);
}

// ---------------- w1: fp32 [50][600] -> bf16 [640][64], all layers ----------------
__global__ __launch_bounds__(256) void conv_w1_k(const float* __restrict__ w1,
                                                 short* __restrict__ w1b) {
  int idx = blockIdx.x*256 + threadIdx.x;
  if (idx >= LL*WROW*64) return;
  int l = idx / (WROW*64); int rem = idx - l*WROW*64;
  int n = rem >> 6, k = rem & 63;
  float v = (n < HD && k < GG) ? w1[(size_t)l*GG*HD + (size_t)k*HD + n] : 0.0f;
  w1b[idx] = f2b(v);
}

// ---------------- all node/w2 weights: LDS-tiled transpose ----------------
// kind (0=l1w,1=l2w,2=ilw,3=w2) major, layer minor; dst bf16 [24][640][608]
__global__ __launch_bounds__(256) void conv_all_k(const float* __restrict__ l1w,
    const float* __restrict__ l2w, const float* __restrict__ ilw,
    const float* __restrict__ w2, short* __restrict__ dst) {
  __shared__ float T[64][65];
  int w = blockIdx.x;
  int kind = w / 6, l = w - kind*6;
  const float* s = (kind == 0) ? l1w : (kind == 1) ? l2w : (kind == 2) ? ilw : w2;
  s += (size_t)l*360000;
  int n0 = blockIdx.y*64, k0 = blockIdx.z*64;
  int tid = threadIdx.x;
  int ta = tid & 63, tb = tid >> 6;
  #pragma unroll
  for (int p = 0; p < 16; ++p) {
    int k = k0 + p*4 + tb;
    int n = n0 + ta;
    T[p*4 + tb][ta] = (k < HD && n < HD) ? s[(size_t)k*HD + n] : 0.0f;
  }
  __syncthreads();
  #pragma unroll
  for (int p = 0; p < 16; ++p) {
    int n = n0 + p*4 + tb;
    int k = k0 + ta;
    if (k < WCOL)
      dst[(size_t)w*WROW*WCOL + (size_t)n*WCOL + k] = f2b(T[ta][p*4 + tb]);
  }
}

// ---------------- embedding: h fp32 + h_b bf16 ----------------
__global__ __launch_bounds__(256) void embed_k(const int* __restrict__ z,
        const float* __restrict__ emb, float* __restrict__ h, short* __restrict__ hb) {
  int i = blockIdx.x;
  int zi = z[i];
  for (int j = threadIdx.x; j < WCOL; j += 256) {
    float v = (j < HD) ? emb[(size_t)zi*HD + j] : 0.0f;
    if (j < HD) h[(size_t)i*HD + j] = v;
    hb[(size_t)i*WCOL + j] = f2b(v);
  }
}

// ---------------- tabA: ttab_all[l] = bf16(ssp(basis@w1[l]+b1[l])) ----------------
__global__ __launch_bounds__(256) void tabA_k(const short* __restrict__ basis,
    const short* __restrict__ w1b, const float* __restrict__ b1all,
    short* __restrict__ ttab_all) {
  const int MT = NKNOT/128;
  int l = blockIdx.x / MT;
  int mb = blockIdx.x - l*MT;
  const short* Bw = w1b + (size_t)l*WROW*64;
  short* outb = ttab_all + (size_t)l*NKNOT*WCOL;
  __shared__ __align__(16) short As[128*40];
  __shared__ __align__(16) short Bs[128*40];
  int tid = threadIdx.x;
  int lane = tid & 63, wv = tid >> 6;
  int wr = wv >> 1, wc = wv & 1;
  int col = lane & 15, quad = lane >> 4;
  int m0 = mb * 128;
  int n0 = blockIdx.y * 128;
  f32x4 acc[4][4] = {};
  for (int k0 = 0; k0 < 64; k0 += 32) {
    #pragma unroll
    for (int rep = 0; rep < 2; ++rep) {
      int s = tid + rep*256;
      int row = s >> 2, seg = s & 3;
      *(short8*)&As[row*40 + seg*8] =
          *(const short8*)(basis + (size_t)(m0 + row)*64 + k0 + seg*8);
      *(short8*)&Bs[row*40 + seg*8] =
          *(const short8*)(Bw + (size_t)(n0 + row)*64 + k0 + seg*8);
    }
    __syncthreads();
    short8 af[4], bf[4];
    #pragma unroll
    for (int mt = 0; mt < 4; ++mt)
      af[mt] = *(const short8*)&As[(wr*64 + mt*16 + col)*40 + quad*8];
    #pragma unroll
    for (int jt = 0; jt < 4; ++jt)
      bf[jt] = *(const short8*)&Bs[(wc*64 + jt*16 + col)*40 + quad*8];
    #pragma unroll
    for (int mt = 0; mt < 4; ++mt)
      #pragma unroll
      for (int jt = 0; jt < 4; ++jt)
        acc[mt][jt] = __builtin_amdgcn_mfma_f32_16x16x32_bf16(af[mt], bf[jt], acc[mt][jt], 0, 0, 0);
    __syncthreads();
  }
  #pragma unroll
  for (int jt = 0; jt < 4; ++jt) {
    int j = n0 + wc*64 + jt*16 + col;
    if (j >= WCOL) continue;
    float bj = (j < HD) ? b1all[(size_t)l*HD + j] : 0.0f;
    #pragma unroll
    for (int mt = 0; mt < 4; ++mt)
      #pragma unroll
      for (int r = 0; r < 4; ++r) {
        int row = m0 + wr*64 + mt*16 + quad*4 + r;
        short v = (j < HD) ? f2b(ssp_fast(acc[mt][jt][r] + bj)) : (short)0;
        outb[(size_t)row*WCOL + j] = v;
      }
  }
}

// ---------------- tabB: wtab_all[l] = ttab_all[l]@w2[l] + b2[l], fp32 ----------------
__global__ __launch_bounds__(256) void tabB_k(const short* __restrict__ ttab_all,
    const short* __restrict__ nwall, const float* __restrict__ b2all,
    float* __restrict__ wtab_all) {
  const int MT = NKNOT/64;
  int l = blockIdx.x / MT;
  int mb = blockIdx.x - l*MT;
  const short* A  = ttab_all + (size_t)l*NKNOT*WCOL;
  const short* Bw = nwall + (size_t)(18 + l)*WROW*WCOL;   // kind=3 (w2)
  float* P = wtab_all + (size_t)l*NKNOT*HD;
  __shared__ __align__(16) short As[64*40];
  __shared__ __align__(16) short Bs[64*40];
  int tid = threadIdx.x;
  int lane = tid & 63, wv = tid >> 6;
  int wr = wv >> 1, wc = wv & 1;
  int col = lane & 15, quad = lane >> 4;
  int m0 = mb * 64;
  int n0 = blockIdx.y * 64;
  f32x4 acc[2][2] = {};
  int row = tid >> 2, seg = tid & 3;
  for (int kk = 0; kk < WCOL; kk += 32) {
    *(short8*)&As[row*40 + seg*8] =
        *(const short8*)(A + (size_t)(m0 + row)*WCOL + kk + seg*8);
    *(short8*)&Bs[row*40 + seg*8] =
        *(const short8*)(Bw + (size_t)(n0 + row)*WCOL + kk + seg*8);
    __syncthreads();
    short8 af[2], bf[2];
    #pragma unroll
    for (int mt = 0; mt < 2; ++mt)
      af[mt] = *(const short8*)&As[(wr*32 + mt*16 + col)*40 + quad*8];
    #pragma unroll
    for (int jt = 0; jt < 2; ++jt)
      bf[jt] = *(const short8*)&Bs[(wc*32 + jt*16 + col)*40 + quad*8];
    #pragma unroll
    for (int mt = 0; mt < 2; ++mt)
      #pragma unroll
      for (int jt = 0; jt < 2; ++jt)
        acc[mt][jt] = __builtin_amdgcn_mfma_f32_16x16x32_bf16(af[mt], bf[jt], acc[mt][jt], 0, 0, 0);
    __syncthreads();
  }
  #pragma unroll
  for (int jt = 0; jt < 2; ++jt) {
    int j = n0 + wc*32 + jt*16 + col;
    if (j >= HD) continue;
    float bj = b2all[(size_t)l*HD + j];
    #pragma unroll
    for (int mt = 0; mt < 2; ++mt)
      #pragma unroll
      for (int r = 0; r < 4; ++r) {
        int rw = m0 + wr*32 + mt*16 + quad*4 + r;
        P[(size_t)rw*HD + j] = acc[mt][jt][r] + bj;
      }
  }
}

// ---------------- gather: msg_b[node] = bf16(sum_e C_e * Wtab(d_e) (.) x1[nbr_e]) ----------------
__global__ __launch_bounds__(320) void gather_k(const float* __restrict__ tab,
    const float* __restrict__ cval, const int* __restrict__ nbr,
    const float* __restrict__ dist, const float* __restrict__ x1,
    short* __restrict__ msgb) {
  __shared__ float cvs[64];
  __shared__ int nbs[64];
  __shared__ int tix[64];
  __shared__ float tfr[64];
  int node = blockIdx.x, tid = threadIdx.x;
  if (tid < 64) {
    int e = node*KNB + tid;
    cvs[tid] = cval[e];
    nbs[tid] = nbr[e];
    float u = dist[e] * ((float)(NKNOT-1)/10.0f);
    int i = (int)u;
    if (i > NKNOT-2) i = NKNOT-2;
    tix[tid] = i;
    tfr[tid] = u - (float)i;
  }
  __syncthreads();
  int j = tid*2;
  if (j >= WCOL) return;
  if (j >= HD) {
    *(unsigned*)&msgb[(size_t)node*WCOL + j] = 0u;
    return;
  }
  float s0 = 0.0f, s1 = 0.0f;
  #pragma unroll 4
  for (int e = 0; e < KNB; ++e) {
    float Ce = cvs[e];
    if (Ce == 0.0f) continue;
    const float* w0 = tab + (size_t)tix[e]*HD + j;
    float f = tfr[e];
    float2 a = *(const float2*)w0;
    float2 b = *(const float2*)(w0 + HD);
    float2 xv = *(const float2*)(x1 + (size_t)nbs[e]*HD + j);
    s0 += Ce * (a.x + f*(b.x - a.x)) * xv.x;
    s1 += Ce * (a.y + f*(b.y - a.y)) * xv.y;
  }
  unsigned pack = (unsigned)(unsigned short)f2b(s0) | ((unsigned)(unsigned short)f2b(s1) << 16);
  *(unsigned*)&msgb[(size_t)node*WCOL + j] = pack;
}

// ---------------- fused node GEMM: 32x64 tile, full K=608, epilogue in-register ----------------
// grid (32, 10). A bf16 [NN][WCOL], Bw bf16 [WROW][WCOL].
// MODE 0: outf[row*HD+j] = acc                       (x1)
// MODE 1: outb = bf16(ssp(acc+bias)), pads zero      (lin2 -> mtmp_b)
// MODE 2: hacc += acc+bias; outb = bf16(hacc')       (int_lin residual -> h, h_b)
template<int MODE>
__global__ __launch_bounds__(256) void gemm_node_k(
    const short* __restrict__ A, const short* __restrict__ Bw,
    const float* __restrict__ bias, float* __restrict__ outf,
    short* __restrict__ outb, float* __restrict__ hacc) {
  __shared__ __align__(16) short As[32*40];
  __shared__ __align__(16) short Bs[64*40];
  int tid = threadIdx.x;
  int lane = tid & 63, wv = tid >> 6;
  int col = lane & 15, quad = lane >> 4;
  int m0 = blockIdx.x * 32;
  int n0 = blockIdx.y * 64;
  int ar = tid >> 3, aseg = tid & 7;   // A: 32 rows x 8 segs of 4 shorts
  int br = tid >> 2, bseg = tid & 3;   // B: 64 rows x 4 segs of 8 shorts
  f32x4 acc[2] = {};
  short4v a_cur = *(const short4v*)(A + (size_t)(m0 + ar)*WCOL + aseg*4);
  short8  b_cur = *(const short8*) (Bw + (size_t)(n0 + br)*WCOL + bseg*8);
  for (int kk = 0; kk < 19; ++kk) {
    *(short4v*)&As[ar*40 + aseg*4] = a_cur;
    *(short8*)&Bs[br*40 + bseg*8] = b_cur;
    __syncthreads();
    if (kk < 18) {
      int k0 = (kk + 1)*32;
      a_cur = *(const short4v*)(A + (size_t)(m0 + ar)*WCOL + k0 + aseg*4);
      b_cur = *(const short8*) (Bw + (size_t)(n0 + br)*WCOL + k0 + bseg*8);
    }
    short8 bf = *(const short8*)&Bs[(wv*16 + col)*40 + quad*8];
    #pragma unroll
    for (int mt = 0; mt < 2; ++mt) {
      short8 af = *(const short8*)&As[(mt*16 + col)*40 + quad*8];
      acc[mt] = __builtin_amdgcn_mfma_f32_16x16x32_bf16(af, bf, acc[mt], 0, 0, 0);
    }
    __syncthreads();
  }
  int j = n0 + wv*16 + col;
  if (MODE == 0) {
    if (j < HD) {
      #pragma unroll
      for (int mt = 0; mt < 2; ++mt)
        #pragma unroll
        for (int r = 0; r < 4; ++r)
          outf[(size_t)(m0 + mt*16 + quad*4 + r)*HD + j] = acc[mt][r];
    }
  } else if (MODE == 1) {
    if (j < WCOL) {
      float bj = (j < HD) ? bias[j] : 0.0f;
      #pragma unroll
      for (int mt = 0; mt < 2; ++mt)
        #pragma unroll
        for (int r = 0; r < 4; ++r) {
          int row = m0 + mt*16 + quad*4 + r;
          outb[(size_t)row*WCOL + j] = (j < HD) ? f2b(ssp_fast(acc[mt][r] + bj)) : (short)0;
        }
    }
  } else {
    if (j < WCOL) {
      #pragma unroll
      for (int mt = 0; mt < 2; ++mt)
        #pragma unroll
        for (int r = 0; r < 4; ++r) {
          int row = m0 + mt*16 + quad*4 + r;
          if (j < HD) {
            float nv = hacc[(size_t)row*HD + j] + acc[mt][r] + bias[j];
            hacc[(size_t)row*HD + j] = nv;
            outb[(size_t)row*WCOL + j] = f2b(nv);
          } else {
            outb[(size_t)row*WCOL + j] = 0;
          }
        }
    }
  }
}

// ---------------- pooling + output ----------------
__global__ __launch_bounds__(256) void pool_mean_k(const float* __restrict__ h,
                                                   float* __restrict__ pooled) {
  int b = blockIdx.x;
  int c = blockIdx.y*256 + threadIdx.x;
  if (c >= HD) return;
  float s = 0.0f;
  for (int n = 0; n < NPG; ++n) s += h[(size_t)(b*NPG + n)*HD + c];
  pooled[(size_t)b*HD + c] = s * (1.0f/128.0f);
}

// grid (10, 8): 64 j per block, 4-way c-split, LDS reduce
__global__ __launch_bounds__(256) void pool_out_k(const float* __restrict__ pooled,
    const float* __restrict__ pw, const float* __restrict__ pb,
    float* __restrict__ out) {
  __shared__ float red[4][64];
  int b = blockIdx.y;
  int tid = threadIdx.x;
  int jl = tid & 63, q = tid >> 6;
  int j = blockIdx.x*64 + jl;
  float s = 0.0f;
  if (j < HD) {
    int c0 = q*150, c1 = c0 + 150;
    for (int c = c0; c < c1; ++c)
      s += pooled[(size_t)b*HD + c] * pw[(size_t)c*HD + j];
  }
  red[q][jl] = s;
  __syncthreads();
  if (q == 0 && j < HD)
    out[(size_t)b*HD + j] = red[0][jl] + red[1][jl] + red[2][jl] + red[3][jl] + pb[j];
}

// ---------------- launch ----------------
extern "C" void kernel_launch(void* const* d_in, const int* in_sizes, int n_in,
                              void* d_out, int out_size, void* d_ws, size_t ws_size,
                              hipStream_t stream) {
  const int*   z    = (const int*)d_in[0];
  const float* pos  = (const float*)d_in[1];
  const float* emb  = (const float*)d_in[2];
  const float* w1   = (const float*)d_in[3];
  const float* b1   = (const float*)d_in[4];
  const float* w2   = (const float*)d_in[5];
  const float* b2   = (const float*)d_in[6];
  const float* l1w  = (const float*)d_in[7];
  const float* l2w  = (const float*)d_in[8];
  const float* l2b  = (const float*)d_in[9];
  const float* ilw  = (const float*)d_in[10];
  const float* ilb  = (const float*)d_in[11];
  const float* pw   = (const float*)d_in[12];
  const float* pb   = (const float*)d_in[13];
  float* ws = (float*)d_ws;
  // workspace layout (float offsets) — total 18,333,696 f = 73.3 MB
  int*   nbr   = (int*)ws;                   // 65536
  float* cv    = ws + 65536;                 // 65536
  float* dist  = ws + 131072;                // 65536
  float* pooled= ws + 196608;                // 8192
  float* h     = ws + 204800;                // 614400
  float* x1    = ws + 819200;                // 614400
  short* h_b   = (short*)(ws + 1433600);     // 311296 f
  short* msg_b = (short*)(ws + 1744896);     // 311296 f
  short* mtmp_b= (short*)(ws + 2056192);     // 311296 f
  short* basis = (short*)(ws + 2367488);     // 65536 f
  short* ttab  = (short*)(ws + 2433024);     // 3735552 f
  float* wtab  = ws + 6168576;               // 7372800 f
  short* w1b   = (short*)(ws + 13541376);    // 122880 f
  short* nwall = (short*)(ws + 13664256);    // 4669440 f
  float* out   = (float*)d_out;

  const size_t WSZ = (size_t)WROW*WCOL;

  build_graph_k<<<NN, 128, 0, stream>>>(pos, nbr, dist, cv);
  dsamp_k<<<(NKNOT*64 + 255)/256, 256, 0, stream>>>(basis);
  conv_w1_k<<<(LL*WROW*64 + 255)/256, 256, 0, stream>>>(w1, w1b);
  conv_all_k<<<dim3(24, 10, 10), 256, 0, stream>>>(l1w, l2w, ilw, w2, nwall);
  embed_k<<<NN, 256, 0, stream>>>(z, emb, h, h_b);

  // batched W(d) tables for all layers
  tabA_k<<<dim3(LL*(NKNOT/128), 5), 256, 0, stream>>>(basis, w1b, b1, ttab);
  tabB_k<<<dim3(LL*(NKNOT/64), 10), 256, 0, stream>>>(ttab, nwall, b2, wtab);

  dim3 gn(32, 10);
  for (int l = 0; l < LL; ++l) {
    // x1 = h @ lin1_w[l]
    gemm_node_k<0><<<gn, 256, 0, stream>>>(h_b, nwall + (size_t)(0*6 + l)*WSZ,
        nullptr, x1, nullptr, nullptr);
    // msg_b[node] = bf16(sum_e C_e * Wtab(d_e) (.) x1[nbr_e])
    gather_k<<<NN, 320, 0, stream>>>(wtab + (size_t)l*NKNOT*HD, cv, nbr, dist, x1, msg_b);
    // mtmp_b = bf16(ssp(msg @ lin2_w[l] + lin2_b[l]))
    gemm_node_k<1><<<gn, 256, 0, stream>>>(msg_b, nwall + (size_t)(1*6 + l)*WSZ,
        l2b + (size_t)l*HD, nullptr, mtmp_b, nullptr);
    // h += mtmp @ int_lin_w[l] + int_lin_b[l]; h_b = bf16(h)
    gemm_node_k<2><<<gn, 256, 0, stream>>>(mtmp_b, nwall + (size_t)(2*6 + l)*WSZ,
        ilb + (size_t)l*HD, nullptr, h_b, h);
  }
  pool_mean_k<<<dim3(NB, 3), 256, 0, stream>>>(h, pooled);
  pool_out_k<<<dim3(10, NB), 256, 0, stream>>>(pooled, pw, pb, out);
}

// Round 10
// 543.131 us; speedup vs baseline: 6.2257x; 1.0005x over previous
//
#include <hip/hip_runtime.h>
#include <cmath>

#define NB   8
#define NPG  128
#define NN   1024
#define KNB  64
#define HD   600
#define GG   50
#define LL   6
#define EE   (NN*KNB)     // 65536 edges
#define WROW 640          // padded weight rows (n)
#define WCOL 608          // padded weight cols (k)
#define NKNOT 2048        // W(d) table knots over [0,10]

typedef __attribute__((ext_vector_type(8))) short short8;
typedef __attribute__((ext_vector_type(4))) short short4v;
typedef __attribute__((ext_vector_type(4))) float f32x4;

__device__ __forceinline__ short f2b(float f) {
  union { float f; unsigned u; } v; v.f = f;
  unsigned u = v.u;
  u += 0x7fffu + ((u >> 16) & 1u);
  return (short)(u >> 16);
}

// fast shifted softplus: max(x,0)+log(1+e^-|x|)-ln2
__device__ __forceinline__ float ssp_fast(float x) {
  return fmaxf(x, 0.0f) + __logf(1.0f + __expf(-fabsf(x))) - 0.69314718055994531f;
}

// ---------------- graph build: one block per node ----------------
__global__ __launch_bounds__(128) void build_graph_k(const float* __restrict__ pos,
        int* __restrict__ nbr, float* __restrict__ dist, float* __restrict__ cval) {
#pragma clang fp contract(off)
  __shared__ float d2s[128];
  __shared__ int scnt;
  int i = blockIdx.x;
  int li = i & 127;
  int base = i - li;
  int j = threadIdx.x;
  if (j == 0) scnt = 0;
  float px = pos[3*i], py = pos[3*i+1], pz = pos[3*i+2];
  int gj = base + j;
  float dx = px - pos[3*gj], dy = py - pos[3*gj+1], dz = pz - pos[3*gj+2];
  float d2 = dx*dx + dy*dy + dz*dz;
  bool valid = (j != li) && (d2 <= 100.0f);
  d2s[j] = valid ? d2 : 3.0e38f;
  __syncthreads();
  if (valid) {
    atomicAdd(&scnt, 1);
    int rank = 0;
    for (int j2 = 0; j2 < 128; ++j2) {
      float o = d2s[j2];
      rank += (o < d2 || (o == d2 && j2 < j)) ? 1 : 0;
    }
    if (rank < KNB) {
      int e = i*KNB + rank;
      nbr[e] = gj;
      float d = sqrtf(d2);
      dist[e] = d;
      cval[e] = 0.5f * (cosf(d * 0.31415926535897931f) + 1.0f);
    }
  }
  __syncthreads();
  int cnt = scnt; if (cnt > KNB) cnt = KNB;
  if (j < KNB && j >= cnt) {
    int e = i*KNB + j;
    nbr[e] = i; dist[e] = 0.0f; cval[e] = 0.0f;
  }
}

// ---------------- d-sample gaussian basis: bf16 [NKNOT][64] ----------------
__global__ __launch_bounds__(256) void dsamp_k(short* __restrict__ basis) {
  int idx = blockIdx.x*256 + threadIdx.x;
  if (idx >= NKNOT*64) return;
  int i = idx >> 6, g = idx & 63;
  float v = 0.0f;
  if (g < GG) {
    const float step = 10.0f/49.0f;
    const float coeff = -0.5f/(step*step);
    float d = (float)i * (10.0f/(float)(NKNOT-1));
    float dd = d - step*(float)g;
    v = __expf(coeff*dd*dd);
  }
  basis[idx] = f2b(v);
}

// ---------------- w1: fp32 [50][600] -> bf16 [640][64], all layers ----------------
__global__ __launch_bounds__(256) void conv_w1_k(const float* __restrict__ w1,
                                                 short* __restrict__ w1b) {
  int idx = blockIdx.x*256 + threadIdx.x;
  if (idx >= LL*WROW*64) return;
  int l = idx / (WROW*64); int rem = idx - l*WROW*64;
  int n = rem >> 6, k = rem & 63;
  float v = (n < HD && k < GG) ? w1[(size_t)l*GG*HD + (size_t)k*HD + n] : 0.0f;
  w1b[idx] = f2b(v);
}

// ---------------- all node/w2 weights: LDS-tiled transpose ----------------
// kind (0=l1w,1=l2w,2=ilw,3=w2) major, layer minor; dst bf16 [24][640][608]
__global__ __launch_bounds__(256) void conv_all_k(const float* __restrict__ l1w,
    const float* __restrict__ l2w, const float* __restrict__ ilw,
    const float* __restrict__ w2, short* __restrict__ dst) {
  __shared__ float T[64][65];
  int w = blockIdx.x;
  int kind = w / 6, l = w - kind*6;
  const float* s = (kind == 0) ? l1w : (kind == 1) ? l2w : (kind == 2) ? ilw : w2;
  s += (size_t)l*360000;
  int n0 = blockIdx.y*64, k0 = blockIdx.z*64;
  int tid = threadIdx.x;
  int ta = tid & 63, tb = tid >> 6;
  #pragma unroll
  for (int p = 0; p < 16; ++p) {
    int k = k0 + p*4 + tb;
    int n = n0 + ta;
    T[p*4 + tb][ta] = (k < HD && n < HD) ? s[(size_t)k*HD + n] : 0.0f;
  }
  __syncthreads();
  #pragma unroll
  for (int p = 0; p < 16; ++p) {
    int n = n0 + p*4 + tb;
    int k = k0 + ta;
    if (k < WCOL)
      dst[(size_t)w*WROW*WCOL + (size_t)n*WCOL + k] = f2b(T[ta][p*4 + tb]);
  }
}

// ---------------- embedding: h fp32 + h_b bf16 ----------------
__global__ __launch_bounds__(256) void embed_k(const int* __restrict__ z,
        const float* __restrict__ emb, float* __restrict__ h, short* __restrict__ hb) {
  int i = blockIdx.x;
  int zi = z[i];
  for (int j = threadIdx.x; j < WCOL; j += 256) {
    float v = (j < HD) ? emb[(size_t)zi*HD + j] : 0.0f;
    if (j < HD) h[(size_t)i*HD + j] = v;
    hb[(size_t)i*WCOL + j] = f2b(v);
  }
}

// ---------------- tabA: ttab_all[l] = bf16(ssp(basis@w1[l]+b1[l])) ----------------
__global__ __launch_bounds__(256) void tabA_k(const short* __restrict__ basis,
    const short* __restrict__ w1b, const float* __restrict__ b1all,
    short* __restrict__ ttab_all) {
  const int MT = NKNOT/128;
  int l = blockIdx.x / MT;
  int mb = blockIdx.x - l*MT;
  const short* Bw = w1b + (size_t)l*WROW*64;
  short* outb = ttab_all + (size_t)l*NKNOT*WCOL;
  __shared__ __align__(16) short As[128*40];
  __shared__ __align__(16) short Bs[128*40];
  int tid = threadIdx.x;
  int lane = tid & 63, wv = tid >> 6;
  int wr = wv >> 1, wc = wv & 1;
  int col = lane & 15, quad = lane >> 4;
  int m0 = mb * 128;
  int n0 = blockIdx.y * 128;
  f32x4 acc[4][4] = {};
  for (int k0 = 0; k0 < 64; k0 += 32) {
    #pragma unroll
    for (int rep = 0; rep < 2; ++rep) {
      int s = tid + rep*256;
      int row = s >> 2, seg = s & 3;
      *(short8*)&As[row*40 + seg*8] =
          *(const short8*)(basis + (size_t)(m0 + row)*64 + k0 + seg*8);
      *(short8*)&Bs[row*40 + seg*8] =
          *(const short8*)(Bw + (size_t)(n0 + row)*64 + k0 + seg*8);
    }
    __syncthreads();
    short8 af[4], bf[4];
    #pragma unroll
    for (int mt = 0; mt < 4; ++mt)
      af[mt] = *(const short8*)&As[(wr*64 + mt*16 + col)*40 + quad*8];
    #pragma unroll
    for (int jt = 0; jt < 4; ++jt)
      bf[jt] = *(const short8*)&Bs[(wc*64 + jt*16 + col)*40 + quad*8];
    #pragma unroll
    for (int mt = 0; mt < 4; ++mt)
      #pragma unroll
      for (int jt = 0; jt < 4; ++jt)
        acc[mt][jt] = __builtin_amdgcn_mfma_f32_16x16x32_bf16(af[mt], bf[jt], acc[mt][jt], 0, 0, 0);
    __syncthreads();
  }
  #pragma unroll
  for (int jt = 0; jt < 4; ++jt) {
    int j = n0 + wc*64 + jt*16 + col;
    if (j >= WCOL) continue;
    float bj = (j < HD) ? b1all[(size_t)l*HD + j] : 0.0f;
    #pragma unroll
    for (int mt = 0; mt < 4; ++mt)
      #pragma unroll
      for (int r = 0; r < 4; ++r) {
        int row = m0 + wr*64 + mt*16 + quad*4 + r;
        short v = (j < HD) ? f2b(ssp_fast(acc[mt][jt][r] + bj)) : (short)0;
        outb[(size_t)row*WCOL + j] = v;
      }
  }
}

// ---------------- tabB: wtab_all[l] = ttab_all[l]@w2[l] + b2[l], fp32; 128x128 tiles ----------------
// structurally = round-6 tab_gemm_k<2> (proven) with batched-layer grid
__global__ __launch_bounds__(256) void tabB_k(const short* __restrict__ ttab_all,
    const short* __restrict__ nwall, const float* __restrict__ b2all,
    float* __restrict__ wtab_all) {
  const int MT = NKNOT/128;
  int l = blockIdx.x / MT;
  int mb = blockIdx.x - l*MT;
  const short* A  = ttab_all + (size_t)l*NKNOT*WCOL;
  const short* Bw = nwall + (size_t)(18 + l)*WROW*WCOL;   // kind=3 (w2)
  float* P = wtab_all + (size_t)l*NKNOT*HD;
  __shared__ __align__(16) short As[128*40];
  __shared__ __align__(16) short Bs[128*40];
  int tid = threadIdx.x;
  int lane = tid & 63, wv = tid >> 6;
  int wr = wv >> 1, wc = wv & 1;
  int col = lane & 15, quad = lane >> 4;
  int m0 = mb * 128;
  int n0 = blockIdx.y * 128;
  f32x4 acc[4][4] = {};
  for (int k0 = 0; k0 < WCOL; k0 += 32) {
    #pragma unroll
    for (int rep = 0; rep < 2; ++rep) {
      int s = tid + rep*256;
      int row = s >> 2, seg = s & 3;
      *(short8*)&As[row*40 + seg*8] =
          *(const short8*)(A + (size_t)(m0 + row)*WCOL + k0 + seg*8);
      *(short8*)&Bs[row*40 + seg*8] =
          *(const short8*)(Bw + (size_t)(n0 + row)*WCOL + k0 + seg*8);
    }
    __syncthreads();
    short8 af[4], bf[4];
    #pragma unroll
    for (int mt = 0; mt < 4; ++mt)
      af[mt] = *(const short8*)&As[(wr*64 + mt*16 + col)*40 + quad*8];
    #pragma unroll
    for (int jt = 0; jt < 4; ++jt)
      bf[jt] = *(const short8*)&Bs[(wc*64 + jt*16 + col)*40 + quad*8];
    #pragma unroll
    for (int mt = 0; mt < 4; ++mt)
      #pragma unroll
      for (int jt = 0; jt < 4; ++jt)
        acc[mt][jt] = __builtin_amdgcn_mfma_f32_16x16x32_bf16(af[mt], bf[jt], acc[mt][jt], 0, 0, 0);
    __syncthreads();
  }
  #pragma unroll
  for (int jt = 0; jt < 4; ++jt) {
    int j = n0 + wc*64 + jt*16 + col;
    if (j >= HD) continue;
    float bj = b2all[(size_t)l*HD + j];
    #pragma unroll
    for (int mt = 0; mt < 4; ++mt)
      #pragma unroll
      for (int r = 0; r < 4; ++r) {
        int row = m0 + wr*64 + mt*16 + quad*4 + r;
        P[(size_t)row*HD + j] = acc[mt][jt][r] + bj;
      }
  }
}

// ---------------- gather: msg_b[node] = bf16(sum_e C_e * Wtab(d_e) (.) x1[nbr_e]) ----------------
__global__ __launch_bounds__(320) void gather_k(const float* __restrict__ tab,
    const float* __restrict__ cval, const int* __restrict__ nbr,
    const float* __restrict__ dist, const float* __restrict__ x1,
    short* __restrict__ msgb) {
  __shared__ float cvs[64];
  __shared__ int nbs[64];
  __shared__ int tix[64];
  __shared__ float tfr[64];
  int node = blockIdx.x, tid = threadIdx.x;
  if (tid < 64) {
    int e = node*KNB + tid;
    cvs[tid] = cval[e];
    nbs[tid] = nbr[e];
    float u = dist[e] * ((float)(NKNOT-1)/10.0f);
    int i = (int)u;
    if (i > NKNOT-2) i = NKNOT-2;
    tix[tid] = i;
    tfr[tid] = u - (float)i;
  }
  __syncthreads();
  int j = tid*2;
  if (j >= WCOL) return;
  if (j >= HD) {
    *(unsigned*)&msgb[(size_t)node*WCOL + j] = 0u;
    return;
  }
  float s0 = 0.0f, s1 = 0.0f;
  #pragma unroll 4
  for (int e = 0; e < KNB; ++e) {
    float Ce = cvs[e];
    if (Ce == 0.0f) continue;
    const float* w0 = tab + (size_t)tix[e]*HD + j;
    float f = tfr[e];
    float2 a = *(const float2*)w0;
    float2 b = *(const float2*)(w0 + HD);
    float2 xv = *(const float2*)(x1 + (size_t)nbs[e]*HD + j);
    s0 += Ce * (a.x + f*(b.x - a.x)) * xv.x;
    s1 += Ce * (a.y + f*(b.y - a.y)) * xv.y;
  }
  unsigned pack = (unsigned)(unsigned short)f2b(s0) | ((unsigned)(unsigned short)f2b(s1) << 16);
  *(unsigned*)&msgb[(size_t)node*WCOL + j] = pack;
}

// ---------------- fused node GEMM: 32x64 tile, full K=608, epilogue in-register ----------------
// grid (32, 10). A bf16 [NN][WCOL], Bw bf16 [WROW][WCOL].  (round-8 proven form)
// MODE 0: outf[row*HD+j] = acc                       (x1)
// MODE 1: outb = bf16(ssp(acc+bias)), pads zero      (lin2 -> mtmp_b)
// MODE 2: hacc += acc+bias; outb = bf16(hacc')       (int_lin residual -> h, h_b)
template<int MODE>
__global__ __launch_bounds__(256) void gemm_node_k(
    const short* __restrict__ A, const short* __restrict__ Bw,
    const float* __restrict__ bias, float* __restrict__ outf,
    short* __restrict__ outb, float* __restrict__ hacc) {
  __shared__ __align__(16) short As[32*40];
  __shared__ __align__(16) short Bs[64*40];
  int tid = threadIdx.x;
  int lane = tid & 63, wv = tid >> 6;
  int col = lane & 15, quad = lane >> 4;
  int m0 = blockIdx.x * 32;
  int n0 = blockIdx.y * 64;
  int ar = tid >> 3, aseg = tid & 7;   // A: 32 rows x 8 segs of 4 shorts
  int br = tid >> 2, bseg = tid & 3;   // B: 64 rows x 4 segs of 8 shorts
  f32x4 acc[2] = {};
  short4v a_cur = *(const short4v*)(A + (size_t)(m0 + ar)*WCOL + aseg*4);
  short8  b_cur = *(const short8*) (Bw + (size_t)(n0 + br)*WCOL + bseg*8);
  for (int kk = 0; kk < 19; ++kk) {
    *(short4v*)&As[ar*40 + aseg*4] = a_cur;
    *(short8*)&Bs[br*40 + bseg*8] = b_cur;
    __syncthreads();
    if (kk < 18) {
      int k0 = (kk + 1)*32;
      a_cur = *(const short4v*)(A + (size_t)(m0 + ar)*WCOL + k0 + aseg*4);
      b_cur = *(const short8*) (Bw + (size_t)(n0 + br)*WCOL + k0 + bseg*8);
    }
    short8 bf = *(const short8*)&Bs[(wv*16 + col)*40 + quad*8];
    #pragma unroll
    for (int mt = 0; mt < 2; ++mt) {
      short8 af = *(const short8*)&As[(mt*16 + col)*40 + quad*8];
      acc[mt] = __builtin_amdgcn_mfma_f32_16x16x32_bf16(af, bf, acc[mt], 0, 0, 0);
    }
    __syncthreads();
  }
  int j = n0 + wv*16 + col;
  if (MODE == 0) {
    if (j < HD) {
      #pragma unroll
      for (int mt = 0; mt < 2; ++mt)
        #pragma unroll
        for (int r = 0; r < 4; ++r)
          outf[(size_t)(m0 + mt*16 + quad*4 + r)*HD + j] = acc[mt][r];
    }
  } else if (MODE == 1) {
    if (j < WCOL) {
      float bj = (j < HD) ? bias[j] : 0.0f;
      #pragma unroll
      for (int mt = 0; mt < 2; ++mt)
        #pragma unroll
        for (int r = 0; r < 4; ++r) {
          int row = m0 + mt*16 + quad*4 + r;
          outb[(size_t)row*WCOL + j] = (j < HD) ? f2b(ssp_fast(acc[mt][r] + bj)) : (short)0;
        }
    }
  } else {
    if (j < WCOL) {
      #pragma unroll
      for (int mt = 0; mt < 2; ++mt)
        #pragma unroll
        for (int r = 0; r < 4; ++r) {
          int row = m0 + mt*16 + quad*4 + r;
          if (j < HD) {
            float nv = hacc[(size_t)row*HD + j] + acc[mt][r] + bias[j];
            hacc[(size_t)row*HD + j] = nv;
            outb[(size_t)row*WCOL + j] = f2b(nv);
          } else {
            outb[(size_t)row*WCOL + j] = 0;
          }
        }
    }
  }
}

// ---------------- pooling + output (round-8 proven forms) ----------------
__global__ __launch_bounds__(256) void pool_mean_k(const float* __restrict__ h,
                                                   float* __restrict__ pooled) {
  int b = blockIdx.x;
  int c = blockIdx.y*256 + threadIdx.x;
  if (c >= HD) return;
  float s = 0.0f;
  for (int n = 0; n < NPG; ++n) s += h[(size_t)(b*NPG + n)*HD + c];
  pooled[(size_t)b*HD + c] = s * (1.0f/128.0f);
}

// grid (10, 8): 64 j per block, 4-way c-split, LDS reduce
__global__ __launch_bounds__(256) void pool_out_k(const float* __restrict__ pooled,
    const float* __restrict__ pw, const float* __restrict__ pb,
    float* __restrict__ out) {
  __shared__ float red[4][64];
  int b = blockIdx.y;
  int tid = threadIdx.x;
  int jl = tid & 63, q = tid >> 6;
  int j = blockIdx.x*64 + jl;
  float s = 0.0f;
  if (j < HD) {
    int c0 = q*150, c1 = c0 + 150;
    for (int c = c0; c < c1; ++c)
      s += pooled[(size_t)b*HD + c] * pw[(size_t)c*HD + j];
  }
  red[q][jl] = s;
  __syncthreads();
  if (q == 0 && j < HD)
    out[(size_t)b*HD + j] = red[0][jl] + red[1][jl] + red[2][jl] + red[3][jl] + pb[j];
}

// ---------------- launch ----------------
extern "C" void kernel_launch(void* const* d_in, const int* in_sizes, int n_in,
                              void* d_out, int out_size, void* d_ws, size_t ws_size,
                              hipStream_t stream) {
  const int*   z    = (const int*)d_in[0];
  const float* pos  = (const float*)d_in[1];
  const float* emb  = (const float*)d_in[2];
  const float* w1   = (const float*)d_in[3];
  const float* b1   = (const float*)d_in[4];
  const float* w2   = (const float*)d_in[5];
  const float* b2   = (const float*)d_in[6];
  const float* l1w  = (const float*)d_in[7];
  const float* l2w  = (const float*)d_in[8];
  const float* l2b  = (const float*)d_in[9];
  const float* ilw  = (const float*)d_in[10];
  const float* ilb  = (const float*)d_in[11];
  const float* pw   = (const float*)d_in[12];
  const float* pb   = (const float*)d_in[13];
  float* ws = (float*)d_ws;
  // workspace layout (float offsets) — identical to round 8
  int*   nbr   = (int*)ws;                   // 65536
  float* cv    = ws + 65536;                 // 65536
  float* dist  = ws + 131072;                // 65536
  float* pooled= ws + 196608;                // 8192
  float* h     = ws + 204800;                // 614400
  float* x1    = ws + 819200;                // 614400
  short* h_b   = (short*)(ws + 1433600);     // 311296 f
  short* msg_b = (short*)(ws + 1744896);     // 311296 f
  short* mtmp_b= (short*)(ws + 2056192);     // 311296 f
  short* basis = (short*)(ws + 2367488);     // 65536 f
  short* ttab  = (short*)(ws + 2433024);     // 3735552 f
  float* wtab  = ws + 6168576;               // 7372800 f
  short* w1b   = (short*)(ws + 13541376);    // 122880 f
  short* nwall = (short*)(ws + 13664256);    // 4669440 f
  float* out   = (float*)d_out;

  const size_t WSZ = (size_t)WROW*WCOL;

  build_graph_k<<<NN, 128, 0, stream>>>(pos, nbr, dist, cv);
  dsamp_k<<<(NKNOT*64 + 255)/256, 256, 0, stream>>>(basis);
  conv_w1_k<<<(LL*WROW*64 + 255)/256, 256, 0, stream>>>(w1, w1b);
  conv_all_k<<<dim3(24, 10, 10), 256, 0, stream>>>(l1w, l2w, ilw, w2, nwall);
  embed_k<<<NN, 256, 0, stream>>>(z, emb, h, h_b);

  // batched W(d) tables for all layers
  tabA_k<<<dim3(LL*(NKNOT/128), 5), 256, 0, stream>>>(basis, w1b, b1, ttab);
  tabB_k<<<dim3(LL*(NKNOT/128), 5), 256, 0, stream>>>(ttab, nwall, b2, wtab);

  dim3 gn(32, 10);
  for (int l = 0; l < LL; ++l) {
    // x1 = h @ lin1_w[l]
    gemm_node_k<0><<<gn, 256, 0, stream>>>(h_b, nwall + (size_t)(0*6 + l)*WSZ,
        nullptr, x1, nullptr, nullptr);
    // msg_b[node] = bf16(sum_e C_e * Wtab(d_e) (.) x1[nbr_e])
    gather_k<<<NN, 320, 0, stream>>>(wtab + (size_t)l*NKNOT*HD, cv, nbr, dist, x1, msg_b);
    // mtmp_b = bf16(ssp(msg @ lin2_w[l] + lin2_b[l]))
    gemm_node_k<1><<<gn, 256, 0, stream>>>(msg_b, nwall + (size_t)(1*6 + l)*WSZ,
        l2b + (size_t)l*HD, nullptr, mtmp_b, nullptr);
    // h += mtmp @ int_lin_w[l] + int_lin_b[l]; h_b = bf16(h)
    gemm_node_k<2><<<gn, 256, 0, stream>>>(mtmp_b, nwall + (size_t)(2*6 + l)*WSZ,
        ilb + (size_t)l*HD, nullptr, h_b, h);
  }
  pool_mean_k<<<dim3(NB, 3), 256, 0, stream>>>(h, pooled);
  pool_out_k<<<dim3(10, NB), 256, 0, stream>>>(pooled, pw, pb, out);
}

// Round 11
// 506.856 us; speedup vs baseline: 6.6712x; 1.0716x over previous
//
#include <hip/hip_runtime.h>
#include <cmath>

#define NB   8
#define NPG  128
#define NN   1024
#define KNB  64
#define HD   600
#define GG   50
#define LL   6
#define EE   (NN*KNB)     // 65536 edges
#define WROW 640          // padded weight rows (n)
#define WCOL 608          // padded weight cols (k)
#define NKNOT 2048        // W(d) table knots over [0,10]

typedef __attribute__((ext_vector_type(8))) short short8;
typedef __attribute__((ext_vector_type(4))) short short4v;
typedef __attribute__((ext_vector_type(4))) float f32x4;

__device__ __forceinline__ short f2b(float f) {
  union { float f; unsigned u; } v; v.f = f;
  unsigned u = v.u;
  u += 0x7fffu + ((u >> 16) & 1u);
  return (short)(u >> 16);
}

__device__ __forceinline__ float b2f(unsigned us) {
  union { unsigned u; float f; } v; v.u = us << 16; return v.f;
}

// fast shifted softplus: max(x,0)+log(1+e^-|x|)-ln2
__device__ __forceinline__ float ssp_fast(float x) {
  return fmaxf(x, 0.0f) + __logf(1.0f + __expf(-fabsf(x))) - 0.69314718055994531f;
}

// ---------------- graph build: one block per node ----------------
__global__ __launch_bounds__(128) void build_graph_k(const float* __restrict__ pos,
        int* __restrict__ nbr, float* __restrict__ dist, float* __restrict__ cval) {
#pragma clang fp contract(off)
  __shared__ float d2s[128];
  __shared__ int scnt;
  int i = blockIdx.x;
  int li = i & 127;
  int base = i - li;
  int j = threadIdx.x;
  if (j == 0) scnt = 0;
  float px = pos[3*i], py = pos[3*i+1], pz = pos[3*i+2];
  int gj = base + j;
  float dx = px - pos[3*gj], dy = py - pos[3*gj+1], dz = pz - pos[3*gj+2];
  float d2 = dx*dx + dy*dy + dz*dz;
  bool valid = (j != li) && (d2 <= 100.0f);
  d2s[j] = valid ? d2 : 3.0e38f;
  __syncthreads();
  if (valid) {
    atomicAdd(&scnt, 1);
    int rank = 0;
    for (int j2 = 0; j2 < 128; ++j2) {
      float o = d2s[j2];
      rank += (o < d2 || (o == d2 && j2 < j)) ? 1 : 0;
    }
    if (rank < KNB) {
      int e = i*KNB + rank;
      nbr[e] = gj;
      float d = sqrtf(d2);
      dist[e] = d;
      cval[e] = 0.5f * (cosf(d * 0.31415926535897931f) + 1.0f);
    }
  }
  __syncthreads();
  int cnt = scnt; if (cnt > KNB) cnt = KNB;
  if (j < KNB && j >= cnt) {
    int e = i*KNB + j;
    nbr[e] = i; dist[e] = 0.0f; cval[e] = 0.0f;
  }
}

// ---------------- d-sample gaussian basis: bf16 [NKNOT][64] ----------------
__global__ __launch_bounds__(256) void dsamp_k(short* __restrict__ basis) {
  int idx = blockIdx.x*256 + threadIdx.x;
  if (idx >= NKNOT*64) return;
  int i = idx >> 6, g = idx & 63;
  float v = 0.0f;
  if (g < GG) {
    const float step = 10.0f/49.0f;
    const float coeff = -0.5f/(step*step);
    float d = (float)i * (10.0f/(float)(NKNOT-1));
    float dd = d - step*(float)g;
    v = __expf(coeff*dd*dd);
  }
  basis[idx] = f2b(v);
}

// ---------------- w1: fp32 [50][600] -> bf16 [640][64], all layers ----------------
__global__ __launch_bounds__(256) void conv_w1_k(const float* __restrict__ w1,
                                                 short* __restrict__ w1b) {
  int idx = blockIdx.x*256 + threadIdx.x;
  if (idx >= LL*WROW*64) return;
  int l = idx / (WROW*64); int rem = idx - l*WROW*64;
  int n = rem >> 6, k = rem & 63;
  float v = (n < HD && k < GG) ? w1[(size_t)l*GG*HD + (size_t)k*HD + n] : 0.0f;
  w1b[idx] = f2b(v);
}

// ---------------- all node/w2 weights: LDS-tiled transpose ----------------
__global__ __launch_bounds__(256) void conv_all_k(const float* __restrict__ l1w,
    const float* __restrict__ l2w, const float* __restrict__ ilw,
    const float* __restrict__ w2, short* __restrict__ dst) {
  __shared__ float T[64][65];
  int w = blockIdx.x;
  int kind = w / 6, l = w - kind*6;
  const float* s = (kind == 0) ? l1w : (kind == 1) ? l2w : (kind == 2) ? ilw : w2;
  s += (size_t)l*360000;
  int n0 = blockIdx.y*64, k0 = blockIdx.z*64;
  int tid = threadIdx.x;
  int ta = tid & 63, tb = tid >> 6;
  #pragma unroll
  for (int p = 0; p < 16; ++p) {
    int k = k0 + p*4 + tb;
    int n = n0 + ta;
    T[p*4 + tb][ta] = (k < HD && n < HD) ? s[(size_t)k*HD + n] : 0.0f;
  }
  __syncthreads();
  #pragma unroll
  for (int p = 0; p < 16; ++p) {
    int n = n0 + p*4 + tb;
    int k = k0 + ta;
    if (k < WCOL)
      dst[(size_t)w*WROW*WCOL + (size_t)n*WCOL + k] = f2b(T[ta][p*4 + tb]);
  }
}

// ---------------- embedding: h fp32 + h_b bf16 ----------------
__global__ __launch_bounds__(256) void embed_k(const int* __restrict__ z,
        const float* __restrict__ emb, float* __restrict__ h, short* __restrict__ hb) {
  int i = blockIdx.x;
  int zi = z[i];
  for (int j = threadIdx.x; j < WCOL; j += 256) {
    float v = (j < HD) ? emb[(size_t)zi*HD + j] : 0.0f;
    if (j < HD) h[(size_t)i*HD + j] = v;
    hb[(size_t)i*WCOL + j] = f2b(v);
  }
}

// ---------------- tabA: ttab_all[l] = bf16(ssp(basis@w1[l]+b1[l])) ----------------
__global__ __launch_bounds__(256) void tabA_k(const short* __restrict__ basis,
    const short* __restrict__ w1b, const float* __restrict__ b1all,
    short* __restrict__ ttab_all) {
  const int MT = NKNOT/128;
  int l = blockIdx.x / MT;
  int mb = blockIdx.x - l*MT;
  const short* Bw = w1b + (size_t)l*WROW*64;
  short* outb = ttab_all + (size_t)l*NKNOT*WCOL;
  __shared__ __align__(16) short As[128*40];
  __shared__ __align__(16) short Bs[128*40];
  int tid = threadIdx.x;
  int lane = tid & 63, wv = tid >> 6;
  int wr = wv >> 1, wc = wv & 1;
  int col = lane & 15, quad = lane >> 4;
  int m0 = mb * 128;
  int n0 = blockIdx.y * 128;
  f32x4 acc[4][4] = {};
  for (int k0 = 0; k0 < 64; k0 += 32) {
    #pragma unroll
    for (int rep = 0; rep < 2; ++rep) {
      int s = tid + rep*256;
      int row = s >> 2, seg = s & 3;
      *(short8*)&As[row*40 + seg*8] =
          *(const short8*)(basis + (size_t)(m0 + row)*64 + k0 + seg*8);
      *(short8*)&Bs[row*40 + seg*8] =
          *(const short8*)(Bw + (size_t)(n0 + row)*64 + k0 + seg*8);
    }
    __syncthreads();
    short8 af[4], bf[4];
    #pragma unroll
    for (int mt = 0; mt < 4; ++mt)
      af[mt] = *(const short8*)&As[(wr*64 + mt*16 + col)*40 + quad*8];
    #pragma unroll
    for (int jt = 0; jt < 4; ++jt)
      bf[jt] = *(const short8*)&Bs[(wc*64 + jt*16 + col)*40 + quad*8];
    #pragma unroll
    for (int mt = 0; mt < 4; ++mt)
      #pragma unroll
      for (int jt = 0; jt < 4; ++jt)
        acc[mt][jt] = __builtin_amdgcn_mfma_f32_16x16x32_bf16(af[mt], bf[jt], acc[mt][jt], 0, 0, 0);
    __syncthreads();
  }
  #pragma unroll
  for (int jt = 0; jt < 4; ++jt) {
    int j = n0 + wc*64 + jt*16 + col;
    if (j >= WCOL) continue;
    float bj = (j < HD) ? b1all[(size_t)l*HD + j] : 0.0f;
    #pragma unroll
    for (int mt = 0; mt < 4; ++mt)
      #pragma unroll
      for (int r = 0; r < 4; ++r) {
        int row = m0 + wr*64 + mt*16 + quad*4 + r;
        short v = (j < HD) ? f2b(ssp_fast(acc[mt][jt][r] + bj)) : (short)0;
        outb[(size_t)row*WCOL + j] = v;
      }
  }
}

// ---------------- tabB: wtab_b[l] = bf16(ttab_all[l]@w2[l] + b2[l]); 128x128 tiles ----------------
__global__ __launch_bounds__(256) void tabB_k(const short* __restrict__ ttab_all,
    const short* __restrict__ nwall, const float* __restrict__ b2all,
    short* __restrict__ wtab_b) {
  const int MT = NKNOT/128;
  int l = blockIdx.x / MT;
  int mb = blockIdx.x - l*MT;
  const short* A  = ttab_all + (size_t)l*NKNOT*WCOL;
  const short* Bw = nwall + (size_t)(18 + l)*WROW*WCOL;   // kind=3 (w2)
  short* P = wtab_b + (size_t)l*NKNOT*HD;
  __shared__ __align__(16) short As[128*40];
  __shared__ __align__(16) short Bs[128*40];
  int tid = threadIdx.x;
  int lane = tid & 63, wv = tid >> 6;
  int wr = wv >> 1, wc = wv & 1;
  int col = lane & 15, quad = lane >> 4;
  int m0 = mb * 128;
  int n0 = blockIdx.y * 128;
  f32x4 acc[4][4] = {};
  for (int k0 = 0; k0 < WCOL; k0 += 32) {
    #pragma unroll
    for (int rep = 0; rep < 2; ++rep) {
      int s = tid + rep*256;
      int row = s >> 2, seg = s & 3;
      *(short8*)&As[row*40 + seg*8] =
          *(const short8*)(A + (size_t)(m0 + row)*WCOL + k0 + seg*8);
      *(short8*)&Bs[row*40 + seg*8] =
          *(const short8*)(Bw + (size_t)(n0 + row)*WCOL + k0 + seg*8);
    }
    __syncthreads();
    short8 af[4], bf[4];
    #pragma unroll
    for (int mt = 0; mt < 4; ++mt)
      af[mt] = *(const short8*)&As[(wr*64 + mt*16 + col)*40 + quad*8];
    #pragma unroll
    for (int jt = 0; jt < 4; ++jt)
      bf[jt] = *(const short8*)&Bs[(wc*64 + jt*16 + col)*40 + quad*8];
    #pragma unroll
    for (int mt = 0; mt < 4; ++mt)
      #pragma unroll
      for (int jt = 0; jt < 4; ++jt)
        acc[mt][jt] = __builtin_amdgcn_mfma_f32_16x16x32_bf16(af[mt], bf[jt], acc[mt][jt], 0, 0, 0);
    __syncthreads();
  }
  #pragma unroll
  for (int jt = 0; jt < 4; ++jt) {
    int j = n0 + wc*64 + jt*16 + col;
    if (j >= HD) continue;
    float bj = b2all[(size_t)l*HD + j];
    #pragma unroll
    for (int mt = 0; mt < 4; ++mt)
      #pragma unroll
      for (int r = 0; r < 4; ++r) {
        int row = m0 + wr*64 + mt*16 + quad*4 + r;
        P[(size_t)row*HD + j] = f2b(acc[mt][jt][r] + bj);
      }
  }
}

// ---------------- gather: msg_b[node] = bf16(sum_e C_e * Wtab(d_e) (.) x1[nbr_e]) ----------------
// wtab_b bf16 [NKNOT][600]; x1_b bf16 [NN][608]; all uint (2-col) loads
__global__ __launch_bounds__(320) void gather_k(const short* __restrict__ tabb,
    const float* __restrict__ cval, const int* __restrict__ nbr,
    const float* __restrict__ dist, const short* __restrict__ x1b,
    short* __restrict__ msgb) {
  __shared__ float cvs[64];
  __shared__ int nbs[64];
  __shared__ int tix[64];
  __shared__ float tfr[64];
  int node = blockIdx.x, tid = threadIdx.x;
  if (tid < 64) {
    int e = node*KNB + tid;
    cvs[tid] = cval[e];
    nbs[tid] = nbr[e];
    float u = dist[e] * ((float)(NKNOT-1)/10.0f);
    int i = (int)u;
    if (i > NKNOT-2) i = NKNOT-2;
    tix[tid] = i;
    tfr[tid] = u - (float)i;
  }
  __syncthreads();
  int j = tid*2;
  if (j >= WCOL) return;
  if (j >= HD) {
    *(unsigned*)&msgb[(size_t)node*WCOL + j] = 0u;
    return;
  }
  float s0 = 0.0f, s1 = 0.0f;
  #pragma unroll 4
  for (int e = 0; e < KNB; ++e) {
    float Ce = cvs[e];
    if (Ce == 0.0f) continue;
    const short* w0 = tabb + (size_t)tix[e]*HD + j;
    float f = tfr[e];
    unsigned wa = *(const unsigned*)w0;
    unsigned wb = *(const unsigned*)(w0 + HD);
    unsigned xv = *(const unsigned*)(x1b + (size_t)nbs[e]*WCOL + j);
    float a0 = b2f(wa & 0xffffu), a1 = b2f(wa >> 16);
    float b0 = b2f(wb & 0xffffu), b1 = b2f(wb >> 16);
    float x0 = b2f(xv & 0xffffu), x1v = b2f(xv >> 16);
    s0 += Ce * (a0 + f*(b0 - a0)) * x0;
    s1 += Ce * (a1 + f*(b1 - a1)) * x1v;
  }
  unsigned pack = (unsigned)(unsigned short)f2b(s0) | ((unsigned)(unsigned short)f2b(s1) << 16);
  *(unsigned*)&msgb[(size_t)node*WCOL + j] = pack;
}

// ---------------- fused node GEMM: 32x64 tile, full K=608, epilogue in-register ----------------
// grid (32, 10). A bf16 [NN][WCOL], Bw bf16 [WROW][WCOL].
// MODE 0: outb = bf16(acc), pads zero               (x1 -> x1_b)
// MODE 1: outb = bf16(ssp(acc+bias)), pads zero     (lin2 -> mtmp_b)
// MODE 2: hacc += acc+bias; outb = bf16(hacc')      (int_lin residual -> h, h_b)
template<int MODE>
__global__ __launch_bounds__(256) void gemm_node_k(
    const short* __restrict__ A, const short* __restrict__ Bw,
    const float* __restrict__ bias, float* __restrict__ outf,
    short* __restrict__ outb, float* __restrict__ hacc) {
  __shared__ __align__(16) short As[32*40];
  __shared__ __align__(16) short Bs[64*40];
  int tid = threadIdx.x;
  int lane = tid & 63, wv = tid >> 6;
  int col = lane & 15, quad = lane >> 4;
  int m0 = blockIdx.x * 32;
  int n0 = blockIdx.y * 64;
  int ar = tid >> 3, aseg = tid & 7;   // A: 32 rows x 8 segs of 4 shorts
  int br = tid >> 2, bseg = tid & 3;   // B: 64 rows x 4 segs of 8 shorts
  f32x4 acc[2] = {};
  short4v a_cur = *(const short4v*)(A + (size_t)(m0 + ar)*WCOL + aseg*4);
  short8  b_cur = *(const short8*) (Bw + (size_t)(n0 + br)*WCOL + bseg*8);
  for (int kk = 0; kk < 19; ++kk) {
    *(short4v*)&As[ar*40 + aseg*4] = a_cur;
    *(short8*)&Bs[br*40 + bseg*8] = b_cur;
    __syncthreads();
    if (kk < 18) {
      int k0 = (kk + 1)*32;
      a_cur = *(const short4v*)(A + (size_t)(m0 + ar)*WCOL + k0 + aseg*4);
      b_cur = *(const short8*) (Bw + (size_t)(n0 + br)*WCOL + k0 + bseg*8);
    }
    short8 bf = *(const short8*)&Bs[(wv*16 + col)*40 + quad*8];
    #pragma unroll
    for (int mt = 0; mt < 2; ++mt) {
      short8 af = *(const short8*)&As[(mt*16 + col)*40 + quad*8];
      acc[mt] = __builtin_amdgcn_mfma_f32_16x16x32_bf16(af, bf, acc[mt], 0, 0, 0);
    }
    __syncthreads();
  }
  int j = n0 + wv*16 + col;
  if (MODE == 0) {
    if (j < WCOL) {
      #pragma unroll
      for (int mt = 0; mt < 2; ++mt)
        #pragma unroll
        for (int r = 0; r < 4; ++r) {
          int row = m0 + mt*16 + quad*4 + r;
          outb[(size_t)row*WCOL + j] = (j < HD) ? f2b(acc[mt][r]) : (short)0;
        }
    }
  } else if (MODE == 1) {
    if (j < WCOL) {
      float bj = (j < HD) ? bias[j] : 0.0f;
      #pragma unroll
      for (int mt = 0; mt < 2; ++mt)
        #pragma unroll
        for (int r = 0; r < 4; ++r) {
          int row = m0 + mt*16 + quad*4 + r;
          outb[(size_t)row*WCOL + j] = (j < HD) ? f2b(ssp_fast(acc[mt][r] + bj)) : (short)0;
        }
    }
  } else {
    if (j < WCOL) {
      #pragma unroll
      for (int mt = 0; mt < 2; ++mt)
        #pragma unroll
        for (int r = 0; r < 4; ++r) {
          int row = m0 + mt*16 + quad*4 + r;
          if (j < HD) {
            float nv = hacc[(size_t)row*HD + j] + acc[mt][r] + bias[j];
            hacc[(size_t)row*HD + j] = nv;
            outb[(size_t)row*WCOL + j] = f2b(nv);
          } else {
            outb[(size_t)row*WCOL + j] = 0;
          }
        }
    }
  }
}

// ---------------- pooling + output ----------------
__global__ __launch_bounds__(256) void pool_mean_k(const float* __restrict__ h,
                                                   float* __restrict__ pooled) {
  int b = blockIdx.x;
  int c = blockIdx.y*256 + threadIdx.x;
  if (c >= HD) return;
  float s = 0.0f;
  for (int n = 0; n < NPG; ++n) s += h[(size_t)(b*NPG + n)*HD + c];
  pooled[(size_t)b*HD + c] = s * (1.0f/128.0f);
}

// grid (10, 8): 64 j per block, 4-way c-split, LDS reduce
__global__ __launch_bounds__(256) void pool_out_k(const float* __restrict__ pooled,
    const float* __restrict__ pw, const float* __restrict__ pb,
    float* __restrict__ out) {
  __shared__ float red[4][64];
  int b = blockIdx.y;
  int tid = threadIdx.x;
  int jl = tid & 63, q = tid >> 6;
  int j = blockIdx.x*64 + jl;
  float s = 0.0f;
  if (j < HD) {
    int c0 = q*150, c1 = c0 + 150;
    for (int c = c0; c < c1; ++c)
      s += pooled[(size_t)b*HD + c] * pw[(size_t)c*HD + j];
  }
  red[q][jl] = s;
  __syncthreads();
  if (q == 0 && j < HD)
    out[(size_t)b*HD + j] = red[0][jl] + red[1][jl] + red[2][jl] + red[3][jl] + pb[j];
}

// ---------------- launch ----------------
extern "C" void kernel_launch(void* const* d_in, const int* in_sizes, int n_in,
                              void* d_out, int out_size, void* d_ws, size_t ws_size,
                              hipStream_t stream) {
  const int*   z    = (const int*)d_in[0];
  const float* pos  = (const float*)d_in[1];
  const float* emb  = (const float*)d_in[2];
  const float* w1   = (const float*)d_in[3];
  const float* b1   = (const float*)d_in[4];
  const float* w2   = (const float*)d_in[5];
  const float* b2   = (const float*)d_in[6];
  const float* l1w  = (const float*)d_in[7];
  const float* l2w  = (const float*)d_in[8];
  const float* l2b  = (const float*)d_in[9];
  const float* ilw  = (const float*)d_in[10];
  const float* ilb  = (const float*)d_in[11];
  const float* pw   = (const float*)d_in[12];
  const float* pb   = (const float*)d_in[13];
  float* ws = (float*)d_ws;
  // workspace layout (float offsets) — total ~14.3M f = 57.4 MB
  int*   nbr   = (int*)ws;                   // 65536
  float* cv    = ws + 65536;                 // 65536
  float* dist  = ws + 131072;                // 65536
  float* pooled= ws + 196608;                // 8192
  float* h     = ws + 204800;                // 614400
  short* h_b   = (short*)(ws + 819200);      // 311296 f
  short* msg_b = (short*)(ws + 1130496);     // 311296 f
  short* mtmp_b= (short*)(ws + 1441792);     // 311296 f
  short* x1_b  = (short*)(ws + 1753088);     // 311296 f
  short* basis = (short*)(ws + 2064384);     // 65536 f
  short* ttab  = (short*)(ws + 2129920);     // 3735552 f
  short* wtab_b= (short*)(ws + 5865472);     // 6*2048*600 sh = 3686400 f
  short* w1b   = (short*)(ws + 9551872);     // 122880 f
  short* nwall = (short*)(ws + 9674752);     // 4669440 f
  float* out   = (float*)d_out;

  const size_t WSZ = (size_t)WROW*WCOL;

  build_graph_k<<<NN, 128, 0, stream>>>(pos, nbr, dist, cv);
  dsamp_k<<<(NKNOT*64 + 255)/256, 256, 0, stream>>>(basis);
  conv_w1_k<<<(LL*WROW*64 + 255)/256, 256, 0, stream>>>(w1, w1b);
  conv_all_k<<<dim3(24, 10, 10), 256, 0, stream>>>(l1w, l2w, ilw, w2, nwall);
  embed_k<<<NN, 256, 0, stream>>>(z, emb, h, h_b);

  // batched W(d) tables for all layers
  tabA_k<<<dim3(LL*(NKNOT/128), 5), 256, 0, stream>>>(basis, w1b, b1, ttab);
  tabB_k<<<dim3(LL*(NKNOT/128), 5), 256, 0, stream>>>(ttab, nwall, b2, wtab_b);

  dim3 gn(32, 10);
  for (int l = 0; l < LL; ++l) {
    // x1_b = bf16(h @ lin1_w[l])
    gemm_node_k<0><<<gn, 256, 0, stream>>>(h_b, nwall + (size_t)(0*6 + l)*WSZ,
        nullptr, nullptr, x1_b, nullptr);
    // msg_b[node] = bf16(sum_e C_e * Wtab(d_e) (.) x1[nbr_e])
    gather_k<<<NN, 320, 0, stream>>>(wtab_b + (size_t)l*NKNOT*HD, cv, nbr, dist, x1_b, msg_b);
    // mtmp_b = bf16(ssp(msg @ lin2_w[l] + lin2_b[l]))
    gemm_node_k<1><<<gn, 256, 0, stream>>>(msg_b, nwall + (size_t)(1*6 + l)*WSZ,
        l2b + (size_t)l*HD, nullptr, mtmp_b, nullptr);
    // h += mtmp @ int_lin_w[l] + int_lin_b[l]; h_b = bf16(h)
    gemm_node_k<2><<<gn, 256, 0, stream>>>(mtmp_b, nwall + (size_t)(2*6 + l)*WSZ,
        ilb + (size_t)l*HD, nullptr, h_b, h);
  }
  pool_mean_k<<<dim3(NB, 3), 256, 0, stream>>>(h, pooled);
  pool_out_k<<<dim3(10, NB), 256, 0, stream>>>(pooled, pw, pb, out);
}

// Round 12
// 503.760 us; speedup vs baseline: 6.7122x; 1.0061x over previous
//
#include <hip/hip_runtime.h>
#include <cmath>

#define NB   8
#define NPG  128
#define NN   1024
#define KNB  64
#define HD   600
#define GG   50
#define LL   6
#define EE   (NN*KNB)     // 65536 edges
#define WROW 640          // padded weight rows (n)
#define WCOL 608          // padded weight cols (k)
#define NKNOT 2048        // W(d) table knots over [0,10]

typedef __attribute__((ext_vector_type(8))) short short8;
typedef __attribute__((ext_vector_type(4))) short short4v;
typedef __attribute__((ext_vector_type(4))) float f32x4;

__device__ __forceinline__ short f2b(float f) {
  union { float f; unsigned u; } v; v.f = f;
  unsigned u = v.u;
  u += 0x7fffu + ((u >> 16) & 1u);
  return (short)(u >> 16);
}

__device__ __forceinline__ float b2f(unsigned us) {
  union { unsigned u; float f; } v; v.u = us << 16; return v.f;
}

// fast shifted softplus: max(x,0)+log(1+e^-|x|)-ln2
__device__ __forceinline__ float ssp_fast(float x) {
  return fmaxf(x, 0.0f) + __logf(1.0f + __expf(-fabsf(x))) - 0.69314718055994531f;
}

// ---------------- graph build: one block per node ----------------
__global__ __launch_bounds__(128) void build_graph_k(const float* __restrict__ pos,
        int* __restrict__ nbr, float* __restrict__ dist, float* __restrict__ cval) {
#pragma clang fp contract(off)
  __shared__ float d2s[128];
  __shared__ int scnt;
  int i = blockIdx.x;
  int li = i & 127;
  int base = i - li;
  int j = threadIdx.x;
  if (j == 0) scnt = 0;
  float px = pos[3*i], py = pos[3*i+1], pz = pos[3*i+2];
  int gj = base + j;
  float dx = px - pos[3*gj], dy = py - pos[3*gj+1], dz = pz - pos[3*gj+2];
  float d2 = dx*dx + dy*dy + dz*dz;
  bool valid = (j != li) && (d2 <= 100.0f);
  d2s[j] = valid ? d2 : 3.0e38f;
  __syncthreads();
  if (valid) {
    atomicAdd(&scnt, 1);
    int rank = 0;
    for (int j2 = 0; j2 < 128; ++j2) {
      float o = d2s[j2];
      rank += (o < d2 || (o == d2 && j2 < j)) ? 1 : 0;
    }
    if (rank < KNB) {
      int e = i*KNB + rank;
      nbr[e] = gj;
      float d = sqrtf(d2);
      dist[e] = d;
      cval[e] = 0.5f * (cosf(d * 0.31415926535897931f) + 1.0f);
    }
  }
  __syncthreads();
  int cnt = scnt; if (cnt > KNB) cnt = KNB;
  if (j < KNB && j >= cnt) {
    int e = i*KNB + j;
    nbr[e] = i; dist[e] = 0.0f; cval[e] = 0.0f;
  }
}

// ---------------- d-sample gaussian basis: bf16 [NKNOT][64] ----------------
__global__ __launch_bounds__(256) void dsamp_k(short* __restrict__ basis) {
  int idx = blockIdx.x*256 + threadIdx.x;
  if (idx >= NKNOT*64) return;
  int i = idx >> 6, g = idx & 63;
  float v = 0.0f;
  if (g < GG) {
    const float step = 10.0f/49.0f;
    const float coeff = -0.5f/(step*step);
    float d = (float)i * (10.0f/(float)(NKNOT-1));
    float dd = d - step*(float)g;
    v = __expf(coeff*dd*dd);
  }
  basis[idx] = f2b(v);
}

// ---------------- w1: fp32 [50][600] -> bf16 [640][64], all layers ----------------
__global__ __launch_bounds__(256) void conv_w1_k(const float* __restrict__ w1,
                                                 short* __restrict__ w1b) {
  int idx = blockIdx.x*256 + threadIdx.x;
  if (idx >= LL*WROW*64) return;
  int l = idx / (WROW*64); int rem = idx - l*WROW*64;
  int n = rem >> 6, k = rem & 63;
  float v = (n < HD && k < GG) ? w1[(size_t)l*GG*HD + (size_t)k*HD + n] : 0.0f;
  w1b[idx] = f2b(v);
}

// ---------------- all node/w2 weights: LDS-tiled transpose ----------------
__global__ __launch_bounds__(256) void conv_all_k(const float* __restrict__ l1w,
    const float* __restrict__ l2w, const float* __restrict__ ilw,
    const float* __restrict__ w2, short* __restrict__ dst) {
  __shared__ float T[64][65];
  int w = blockIdx.x;
  int kind = w / 6, l = w - kind*6;
  const float* s = (kind == 0) ? l1w : (kind == 1) ? l2w : (kind == 2) ? ilw : w2;
  s += (size_t)l*360000;
  int n0 = blockIdx.y*64, k0 = blockIdx.z*64;
  int tid = threadIdx.x;
  int ta = tid & 63, tb = tid >> 6;
  #pragma unroll
  for (int p = 0; p < 16; ++p) {
    int k = k0 + p*4 + tb;
    int n = n0 + ta;
    T[p*4 + tb][ta] = (k < HD && n < HD) ? s[(size_t)k*HD + n] : 0.0f;
  }
  __syncthreads();
  #pragma unroll
  for (int p = 0; p < 16; ++p) {
    int n = n0 + p*4 + tb;
    int k = k0 + ta;
    if (k < WCOL)
      dst[(size_t)w*WROW*WCOL + (size_t)n*WCOL + k] = f2b(T[ta][p*4 + tb]);
  }
}

// ---------------- embedding: h fp32 + h_b bf16 ----------------
__global__ __launch_bounds__(256) void embed_k(const int* __restrict__ z,
        const float* __restrict__ emb, float* __restrict__ h, short* __restrict__ hb) {
  int i = blockIdx.x;
  int zi = z[i];
  for (int j = threadIdx.x; j < WCOL; j += 256) {
    float v = (j < HD) ? emb[(size_t)zi*HD + j] : 0.0f;
    if (j < HD) h[(size_t)i*HD + j] = v;
    hb[(size_t)i*WCOL + j] = f2b(v);
  }
}

// ---------------- tabA: ttab_all[l] = bf16(ssp(basis@w1[l]+b1[l])) ----------------
__global__ __launch_bounds__(256) void tabA_k(const short* __restrict__ basis,
    const short* __restrict__ w1b, const float* __restrict__ b1all,
    short* __restrict__ ttab_all) {
  const int MT = NKNOT/128;
  int l = blockIdx.x / MT;
  int mb = blockIdx.x - l*MT;
  const short* Bw = w1b + (size_t)l*WROW*64;
  short* outb = ttab_all + (size_t)l*NKNOT*WCOL;
  __shared__ __align__(16) short As[128*40];
  __shared__ __align__(16) short Bs[128*40];
  int tid = threadIdx.x;
  int lane = tid & 63, wv = tid >> 6;
  int wr = wv >> 1, wc = wv & 1;
  int col = lane & 15, quad = lane >> 4;
  int m0 = mb * 128;
  int n0 = blockIdx.y * 128;
  f32x4 acc[4][4] = {};
  for (int k0 = 0; k0 < 64; k0 += 32) {
    #pragma unroll
    for (int rep = 0; rep < 2; ++rep) {
      int s = tid + rep*256;
      int row = s >> 2, seg = s & 3;
      *(short8*)&As[row*40 + seg*8] =
          *(const short8*)(basis + (size_t)(m0 + row)*64 + k0 + seg*8);
      *(short8*)&Bs[row*40 + seg*8] =
          *(const short8*)(Bw + (size_t)(n0 + row)*64 + k0 + seg*8);
    }
    __syncthreads();
    short8 af[4], bf[4];
    #pragma unroll
    for (int mt = 0; mt < 4; ++mt)
      af[mt] = *(const short8*)&As[(wr*64 + mt*16 + col)*40 + quad*8];
    #pragma unroll
    for (int jt = 0; jt < 4; ++jt)
      bf[jt] = *(const short8*)&Bs[(wc*64 + jt*16 + col)*40 + quad*8];
    #pragma unroll
    for (int mt = 0; mt < 4; ++mt)
      #pragma unroll
      for (int jt = 0; jt < 4; ++jt)
        acc[mt][jt] = __builtin_amdgcn_mfma_f32_16x16x32_bf16(af[mt], bf[jt], acc[mt][jt], 0, 0, 0);
    __syncthreads();
  }
  #pragma unroll
  for (int jt = 0; jt < 4; ++jt) {
    int j = n0 + wc*64 + jt*16 + col;
    if (j >= WCOL) continue;
    float bj = (j < HD) ? b1all[(size_t)l*HD + j] : 0.0f;
    #pragma unroll
    for (int mt = 0; mt < 4; ++mt)
      #pragma unroll
      for (int r = 0; r < 4; ++r) {
        int row = m0 + wr*64 + mt*16 + quad*4 + r;
        short v = (j < HD) ? f2b(ssp_fast(acc[mt][jt][r] + bj)) : (short)0;
        outb[(size_t)row*WCOL + j] = v;
      }
  }
}

// ---------------- tabB: wtab_b[l] = bf16(ttab_all[l]@w2[l] + b2[l]); 128x128 tiles ----------------
__global__ __launch_bounds__(256) void tabB_k(const short* __restrict__ ttab_all,
    const short* __restrict__ nwall, const float* __restrict__ b2all,
    short* __restrict__ wtab_b) {
  const int MT = NKNOT/128;
  int l = blockIdx.x / MT;
  int mb = blockIdx.x - l*MT;
  const short* A  = ttab_all + (size_t)l*NKNOT*WCOL;
  const short* Bw = nwall + (size_t)(18 + l)*WROW*WCOL;   // kind=3 (w2)
  short* P = wtab_b + (size_t)l*NKNOT*HD;
  __shared__ __align__(16) short As[128*40];
  __shared__ __align__(16) short Bs[128*40];
  int tid = threadIdx.x;
  int lane = tid & 63, wv = tid >> 6;
  int wr = wv >> 1, wc = wv & 1;
  int col = lane & 15, quad = lane >> 4;
  int m0 = mb * 128;
  int n0 = blockIdx.y * 128;
  f32x4 acc[4][4] = {};
  for (int k0 = 0; k0 < WCOL; k0 += 32) {
    #pragma unroll
    for (int rep = 0; rep < 2; ++rep) {
      int s = tid + rep*256;
      int row = s >> 2, seg = s & 3;
      *(short8*)&As[row*40 + seg*8] =
          *(const short8*)(A + (size_t)(m0 + row)*WCOL + k0 + seg*8);
      *(short8*)&Bs[row*40 + seg*8] =
          *(const short8*)(Bw + (size_t)(n0 + row)*WCOL + k0 + seg*8);
    }
    __syncthreads();
    short8 af[4], bf[4];
    #pragma unroll
    for (int mt = 0; mt < 4; ++mt)
      af[mt] = *(const short8*)&As[(wr*64 + mt*16 + col)*40 + quad*8];
    #pragma unroll
    for (int jt = 0; jt < 4; ++jt)
      bf[jt] = *(const short8*)&Bs[(wc*64 + jt*16 + col)*40 + quad*8];
    #pragma unroll
    for (int mt = 0; mt < 4; ++mt)
      #pragma unroll
      for (int jt = 0; jt < 4; ++jt)
        acc[mt][jt] = __builtin_amdgcn_mfma_f32_16x16x32_bf16(af[mt], bf[jt], acc[mt][jt], 0, 0, 0);
    __syncthreads();
  }
  #pragma unroll
  for (int jt = 0; jt < 4; ++jt) {
    int j = n0 + wc*64 + jt*16 + col;
    if (j >= HD) continue;
    float bj = b2all[(size_t)l*HD + j];
    #pragma unroll
    for (int mt = 0; mt < 4; ++mt)
      #pragma unroll
      for (int r = 0; r < 4; ++r) {
        int row = m0 + wr*64 + mt*16 + quad*4 + r;
        P[(size_t)row*HD + j] = f2b(acc[mt][jt][r] + bj);
      }
  }
}

// ---------------- gather: msg_b[node] = bf16(sum_e C_e * Wtab(d_e) (.) x1[nbr_e]) ----------------
// wtab_b bf16 [NKNOT][600]; x1_b bf16 [NN][608]; 8B (4-col) loads, 192 thr (152 active)
__global__ __launch_bounds__(192) void gather_k(const short* __restrict__ tabb,
    const float* __restrict__ cval, const int* __restrict__ nbr,
    const float* __restrict__ dist, const short* __restrict__ x1b,
    short* __restrict__ msgb) {
  __shared__ float cvs[64];
  __shared__ int nbs[64];
  __shared__ int tix[64];
  __shared__ float tfr[64];
  int node = blockIdx.x, tid = threadIdx.x;
  if (tid < 64) {
    int e = node*KNB + tid;
    cvs[tid] = cval[e];
    nbs[tid] = nbr[e];
    float u = dist[e] * ((float)(NKNOT-1)/10.0f);
    int i = (int)u;
    if (i > NKNOT-2) i = NKNOT-2;
    tix[tid] = i;
    tfr[tid] = u - (float)i;
  }
  __syncthreads();
  int j = tid*4;
  if (j >= WCOL) return;
  if (j >= HD) {                   // j = 600 or 604: zero the bf16 pads (8B each)
    *(uint2*)&msgb[(size_t)node*WCOL + j] = make_uint2(0u, 0u);
    return;
  }
  float s[4] = {0.f, 0.f, 0.f, 0.f};
  #pragma unroll 4
  for (int e = 0; e < KNB; ++e) {
    float Ce = cvs[e];
    if (Ce == 0.0f) continue;
    const short* w0 = tabb + (size_t)tix[e]*HD + j;
    float f = tfr[e];
    uint2 wa = *(const uint2*)w0;
    uint2 wb = *(const uint2*)(w0 + HD);
    uint2 xv = *(const uint2*)(x1b + (size_t)nbs[e]*WCOL + j);
    float a0 = b2f(wa.x & 0xffffu), a1 = b2f(wa.x >> 16);
    float a2 = b2f(wa.y & 0xffffu), a3 = b2f(wa.y >> 16);
    float b0 = b2f(wb.x & 0xffffu), b1 = b2f(wb.x >> 16);
    float b2v = b2f(wb.y & 0xffffu), b3 = b2f(wb.y >> 16);
    float x0 = b2f(xv.x & 0xffffu), x1v = b2f(xv.x >> 16);
    float x2 = b2f(xv.y & 0xffffu), x3 = b2f(xv.y >> 16);
    s[0] += Ce * (a0 + f*(b0 - a0)) * x0;
    s[1] += Ce * (a1 + f*(b1 - a1)) * x1v;
    s[2] += Ce * (a2 + f*(b2v - a2)) * x2;
    s[3] += Ce * (a3 + f*(b3 - a3)) * x3;
  }
  uint2 pack;
  pack.x = (unsigned)(unsigned short)f2b(s[0]) | ((unsigned)(unsigned short)f2b(s[1]) << 16);
  pack.y = (unsigned)(unsigned short)f2b(s[2]) | ((unsigned)(unsigned short)f2b(s[3]) << 16);
  *(uint2*)&msgb[(size_t)node*WCOL + j] = pack;
}

// ---------------- fused node GEMM: 32x64 tile, single-barrier LDS double-buffer ----------------
// grid (32, 10). A bf16 [NN][WCOL], Bw bf16 [WROW][WCOL].
// MODE 0: outb = bf16(acc), pads zero               (x1 -> x1_b)
// MODE 1: outb = bf16(ssp(acc+bias)), pads zero     (lin2 -> mtmp_b)
// MODE 2: hacc += acc+bias; outb = bf16(hacc')      (int_lin residual -> h, h_b)
template<int MODE>
__global__ __launch_bounds__(256) void gemm_node_k(
    const short* __restrict__ A, const short* __restrict__ Bw,
    const float* __restrict__ bias, float* __restrict__ outf,
    short* __restrict__ outb, float* __restrict__ hacc) {
  __shared__ __align__(16) short As[2][32*40];
  __shared__ __align__(16) short Bs[2][64*40];
  int tid = threadIdx.x;
  int lane = tid & 63, wv = tid >> 6;
  int col = lane & 15, quad = lane >> 4;
  int m0 = blockIdx.x * 32;
  int n0 = blockIdx.y * 64;
  int ar = tid >> 3, aseg = tid & 7;   // A: 32 rows x 8 segs of 4 shorts
  int br = tid >> 2, bseg = tid & 3;   // B: 64 rows x 4 segs of 8 shorts
  const short* Aptr = A  + (size_t)(m0 + ar)*WCOL + aseg*4;
  const short* Bptr = Bw + (size_t)(n0 + br)*WCOL + bseg*8;
  f32x4 acc[2] = {};
  // prologue: stage k=0 into buffer 0
  {
    short4v a0 = *(const short4v*)Aptr;
    short8  b0 = *(const short8*)Bptr;
    *(short4v*)&As[0][ar*40 + aseg*4] = a0;
    *(short8*)&Bs[0][br*40 + bseg*8] = b0;
  }
  __syncthreads();
  for (int kk = 0; kk < 19; ++kk) {
    int cur = kk & 1, nxt = cur ^ 1;
    short4v a_n; short8 b_n;
    if (kk < 18) {              // issue next-K loads (latency overlapped by MFMA below)
      a_n = *(const short4v*)(Aptr + (kk + 1)*32);
      b_n = *(const short8*) (Bptr + (kk + 1)*32);
    }
    short8 bf = *(const short8*)&Bs[cur][(wv*16 + col)*40 + quad*8];
    #pragma unroll
    for (int mt = 0; mt < 2; ++mt) {
      short8 af = *(const short8*)&As[cur][(mt*16 + col)*40 + quad*8];
      acc[mt] = __builtin_amdgcn_mfma_f32_16x16x32_bf16(af, bf, acc[mt], 0, 0, 0);
    }
    if (kk < 18) {              // write next buffer (readers of it finished before prev barrier)
      *(short4v*)&As[nxt][ar*40 + aseg*4] = a_n;
      *(short8*)&Bs[nxt][br*40 + bseg*8] = b_n;
    }
    __syncthreads();
  }
  int j = n0 + wv*16 + col;
  if (MODE == 0) {
    if (j < WCOL) {
      #pragma unroll
      for (int mt = 0; mt < 2; ++mt)
        #pragma unroll
        for (int r = 0; r < 4; ++r) {
          int row = m0 + mt*16 + quad*4 + r;
          outb[(size_t)row*WCOL + j] = (j < HD) ? f2b(acc[mt][r]) : (short)0;
        }
    }
  } else if (MODE == 1) {
    if (j < WCOL) {
      float bj = (j < HD) ? bias[j] : 0.0f;
      #pragma unroll
      for (int mt = 0; mt < 2; ++mt)
        #pragma unroll
        for (int r = 0; r < 4; ++r) {
          int row = m0 + mt*16 + quad*4 + r;
          outb[(size_t)row*WCOL + j] = (j < HD) ? f2b(ssp_fast(acc[mt][r] + bj)) : (short)0;
        }
    }
  } else {
    if (j < WCOL) {
      #pragma unroll
      for (int mt = 0; mt < 2; ++mt)
        #pragma unroll
        for (int r = 0; r < 4; ++r) {
          int row = m0 + mt*16 + quad*4 + r;
          if (j < HD) {
            float nv = hacc[(size_t)row*HD + j] + acc[mt][r] + bias[j];
            hacc[(size_t)row*HD + j] = nv;
            outb[(size_t)row*WCOL + j] = f2b(nv);
          } else {
            outb[(size_t)row*WCOL + j] = 0;
          }
        }
    }
  }
}

// ---------------- pooling + output ----------------
__global__ __launch_bounds__(256) void pool_mean_k(const float* __restrict__ h,
                                                   float* __restrict__ pooled) {
  int b = blockIdx.x;
  int c = blockIdx.y*256 + threadIdx.x;
  if (c >= HD) return;
  float s = 0.0f;
  for (int n = 0; n < NPG; ++n) s += h[(size_t)(b*NPG + n)*HD + c];
  pooled[(size_t)b*HD + c] = s * (1.0f/128.0f);
}

// grid (10, 8): 64 j per block, 4-way c-split, LDS reduce
__global__ __launch_bounds__(256) void pool_out_k(const float* __restrict__ pooled,
    const float* __restrict__ pw, const float* __restrict__ pb,
    float* __restrict__ out) {
  __shared__ float red[4][64];
  int b = blockIdx.y;
  int tid = threadIdx.x;
  int jl = tid & 63, q = tid >> 6;
  int j = blockIdx.x*64 + jl;
  float s = 0.0f;
  if (j < HD) {
    int c0 = q*150, c1 = c0 + 150;
    for (int c = c0; c < c1; ++c)
      s += pooled[(size_t)b*HD + c] * pw[(size_t)c*HD + j];
  }
  red[q][jl] = s;
  __syncthreads();
  if (q == 0 && j < HD)
    out[(size_t)b*HD + j] = red[0][jl] + red[1][jl] + red[2][jl] + red[3][jl] + pb[j];
}

// ---------------- launch ----------------
extern "C" void kernel_launch(void* const* d_in, const int* in_sizes, int n_in,
                              void* d_out, int out_size, void* d_ws, size_t ws_size,
                              hipStream_t stream) {
  const int*   z    = (const int*)d_in[0];
  const float* pos  = (const float*)d_in[1];
  const float* emb  = (const float*)d_in[2];
  const float* w1   = (const float*)d_in[3];
  const float* b1   = (const float*)d_in[4];
  const float* w2   = (const float*)d_in[5];
  const float* b2   = (const float*)d_in[6];
  const float* l1w  = (const float*)d_in[7];
  const float* l2w  = (const float*)d_in[8];
  const float* l2b  = (const float*)d_in[9];
  const float* ilw  = (const float*)d_in[10];
  const float* ilb  = (const float*)d_in[11];
  const float* pw   = (const float*)d_in[12];
  const float* pb   = (const float*)d_in[13];
  float* ws = (float*)d_ws;
  // workspace layout (float offsets) — total ~14.3M f = 57.4 MB
  int*   nbr   = (int*)ws;                   // 65536
  float* cv    = ws + 65536;                 // 65536
  float* dist  = ws + 131072;                // 65536
  float* pooled= ws + 196608;                // 8192
  float* h     = ws + 204800;                // 614400
  short* h_b   = (short*)(ws + 819200);      // 311296 f
  short* msg_b = (short*)(ws + 1130496);     // 311296 f
  short* mtmp_b= (short*)(ws + 1441792);     // 311296 f
  short* x1_b  = (short*)(ws + 1753088);     // 311296 f
  short* basis = (short*)(ws + 2064384);     // 65536 f
  short* ttab  = (short*)(ws + 2129920);     // 3735552 f
  short* wtab_b= (short*)(ws + 5865472);     // 3686400 f
  short* w1b   = (short*)(ws + 9551872);     // 122880 f
  short* nwall = (short*)(ws + 9674752);     // 4669440 f
  float* out   = (float*)d_out;

  const size_t WSZ = (size_t)WROW*WCOL;

  build_graph_k<<<NN, 128, 0, stream>>>(pos, nbr, dist, cv);
  dsamp_k<<<(NKNOT*64 + 255)/256, 256, 0, stream>>>(basis);
  conv_w1_k<<<(LL*WROW*64 + 255)/256, 256, 0, stream>>>(w1, w1b);
  conv_all_k<<<dim3(24, 10, 10), 256, 0, stream>>>(l1w, l2w, ilw, w2, nwall);
  embed_k<<<NN, 256, 0, stream>>>(z, emb, h, h_b);

  // batched W(d) tables for all layers
  tabA_k<<<dim3(LL*(NKNOT/128), 5), 256, 0, stream>>>(basis, w1b, b1, ttab);
  tabB_k<<<dim3(LL*(NKNOT/128), 5), 256, 0, stream>>>(ttab, nwall, b2, wtab_b);

  dim3 gn(32, 10);
  for (int l = 0; l < LL; ++l) {
    // x1_b = bf16(h @ lin1_w[l])
    gemm_node_k<0><<<gn, 256, 0, stream>>>(h_b, nwall + (size_t)(0*6 + l)*WSZ,
        nullptr, nullptr, x1_b, nullptr);
    // msg_b[node] = bf16(sum_e C_e * Wtab(d_e) (.) x1[nbr_e])
    gather_k<<<NN, 192, 0, stream>>>(wtab_b + (size_t)l*NKNOT*HD, cv, nbr, dist, x1_b, msg_b);
    // mtmp_b = bf16(ssp(msg @ lin2_w[l] + lin2_b[l]))
    gemm_node_k<1><<<gn, 256, 0, stream>>>(msg_b, nwall + (size_t)(1*6 + l)*WSZ,
        l2b + (size_t)l*HD, nullptr, mtmp_b, nullptr);
    // h += mtmp @ int_lin_w[l] + int_lin_b[l]; h_b = bf16(h)
    gemm_node_k<2><<<gn, 256, 0, stream>>>(mtmp_b, nwall + (size_t)(2*6 + l)*WSZ,
        ilb + (size_t)l*HD, nullptr, h_b, h);
  }
  pool_mean_k<<<dim3(NB, 3), 256, 0, stream>>>(h, pooled);
  pool_out_k<<<dim3(10, NB), 256, 0, stream>>>(pooled, pw, pb, out);
}

// Round 13
// 501.844 us; speedup vs baseline: 6.7379x; 1.0038x over previous
//
#include <hip/hip_runtime.h>
#include <cmath>

#define NB   8
#define NPG  128
#define NN   1024
#define KNB  64
#define HD   600
#define GG   50
#define LL   6
#define EE   (NN*KNB)     // 65536 edges
#define WROW 640          // padded weight rows (n)
#define WCOL 608          // padded weight cols (k)
#define NKNOT 1024        // W(d) table knots over [0,10]

typedef __attribute__((ext_vector_type(8))) short short8;
typedef __attribute__((ext_vector_type(4))) short short4v;
typedef __attribute__((ext_vector_type(4))) float f32x4;

__device__ __forceinline__ short f2b(float f) {
  union { float f; unsigned u; } v; v.f = f;
  unsigned u = v.u;
  u += 0x7fffu + ((u >> 16) & 1u);
  return (short)(u >> 16);
}

__device__ __forceinline__ float b2f(unsigned us) {
  union { unsigned u; float f; } v; v.u = us << 16; return v.f;
}

// fast shifted softplus: max(x,0)+log(1+e^-|x|)-ln2
__device__ __forceinline__ float ssp_fast(float x) {
  return fmaxf(x, 0.0f) + __logf(1.0f + __expf(-fabsf(x))) - 0.69314718055994531f;
}

// ---------------- graph build: one block per node ----------------
__global__ __launch_bounds__(128) void build_graph_k(const float* __restrict__ pos,
        int* __restrict__ nbr, float* __restrict__ dist, float* __restrict__ cval) {
#pragma clang fp contract(off)
  __shared__ float d2s[128];
  __shared__ int scnt;
  int i = blockIdx.x;
  int li = i & 127;
  int base = i - li;
  int j = threadIdx.x;
  if (j == 0) scnt = 0;
  float px = pos[3*i], py = pos[3*i+1], pz = pos[3*i+2];
  int gj = base + j;
  float dx = px - pos[3*gj], dy = py - pos[3*gj+1], dz = pz - pos[3*gj+2];
  float d2 = dx*dx + dy*dy + dz*dz;
  bool valid = (j != li) && (d2 <= 100.0f);
  d2s[j] = valid ? d2 : 3.0e38f;
  __syncthreads();
  if (valid) {
    atomicAdd(&scnt, 1);
    int rank = 0;
    for (int j2 = 0; j2 < 128; ++j2) {
      float o = d2s[j2];
      rank += (o < d2 || (o == d2 && j2 < j)) ? 1 : 0;
    }
    if (rank < KNB) {
      int e = i*KNB + rank;
      nbr[e] = gj;
      float d = sqrtf(d2);
      dist[e] = d;
      cval[e] = 0.5f * (cosf(d * 0.31415926535897931f) + 1.0f);
    }
  }
  __syncthreads();
  int cnt = scnt; if (cnt > KNB) cnt = KNB;
  if (j < KNB && j >= cnt) {
    int e = i*KNB + j;
    nbr[e] = i; dist[e] = 0.0f; cval[e] = 0.0f;
  }
}

// ---------------- prep: gaussian basis [NKNOT][64] + w1 conv [6][640][64] ----------------
__global__ __launch_bounds__(256) void prep_k(const float* __restrict__ w1,
    short* __restrict__ basis, short* __restrict__ w1b) {
  int idx = blockIdx.x*256 + threadIdx.x;
  if (idx < NKNOT*64) {
    int i = idx >> 6, g = idx & 63;
    float v = 0.0f;
    if (g < GG) {
      const float step = 10.0f/49.0f;
      const float coeff = -0.5f/(step*step);
      float d = (float)i * (10.0f/(float)(NKNOT-1));
      float dd = d - step*(float)g;
      v = __expf(coeff*dd*dd);
    }
    basis[idx] = f2b(v);
  } else {
    int r = idx - NKNOT*64;
    if (r >= LL*WROW*64) return;
    int l = r / (WROW*64); int rem = r - l*WROW*64;
    int n = rem >> 6, k = rem & 63;
    float v = (n < HD && k < GG) ? w1[(size_t)l*GG*HD + (size_t)k*HD + n] : 0.0f;
    w1b[r] = f2b(v);
  }
}

// ---------------- all node/w2 weights: LDS-tiled transpose ----------------
__global__ __launch_bounds__(256) void conv_all_k(const float* __restrict__ l1w,
    const float* __restrict__ l2w, const float* __restrict__ ilw,
    const float* __restrict__ w2, short* __restrict__ dst) {
  __shared__ float T[64][65];
  int w = blockIdx.x;
  int kind = w / 6, l = w - kind*6;
  const float* s = (kind == 0) ? l1w : (kind == 1) ? l2w : (kind == 2) ? ilw : w2;
  s += (size_t)l*360000;
  int n0 = blockIdx.y*64, k0 = blockIdx.z*64;
  int tid = threadIdx.x;
  int ta = tid & 63, tb = tid >> 6;
  #pragma unroll
  for (int p = 0; p < 16; ++p) {
    int k = k0 + p*4 + tb;
    int n = n0 + ta;
    T[p*4 + tb][ta] = (k < HD && n < HD) ? s[(size_t)k*HD + n] : 0.0f;
  }
  __syncthreads();
  #pragma unroll
  for (int p = 0; p < 16; ++p) {
    int n = n0 + p*4 + tb;
    int k = k0 + ta;
    if (k < WCOL)
      dst[(size_t)w*WROW*WCOL + (size_t)n*WCOL + k] = f2b(T[ta][p*4 + tb]);
  }
}

// ---------------- embedding: h fp32 + h_b bf16 ----------------
__global__ __launch_bounds__(256) void embed_k(const int* __restrict__ z,
        const float* __restrict__ emb, float* __restrict__ h, short* __restrict__ hb) {
  int i = blockIdx.x;
  int zi = z[i];
  for (int j = threadIdx.x; j < WCOL; j += 256) {
    float v = (j < HD) ? emb[(size_t)zi*HD + j] : 0.0f;
    if (j < HD) h[(size_t)i*HD + j] = v;
    hb[(size_t)i*WCOL + j] = f2b(v);
  }
}

// ---------------- tabA: ttab_all[l] = bf16(ssp(basis@w1[l]+b1[l])) ----------------
__global__ __launch_bounds__(256) void tabA_k(const short* __restrict__ basis,
    const short* __restrict__ w1b, const float* __restrict__ b1all,
    short* __restrict__ ttab_all) {
  const int MT = NKNOT/128;
  int l = blockIdx.x / MT;
  int mb = blockIdx.x - l*MT;
  const short* Bw = w1b + (size_t)l*WROW*64;
  short* outb = ttab_all + (size_t)l*NKNOT*WCOL;
  __shared__ __align__(16) short As[128*40];
  __shared__ __align__(16) short Bs[128*40];
  int tid = threadIdx.x;
  int lane = tid & 63, wv = tid >> 6;
  int wr = wv >> 1, wc = wv & 1;
  int col = lane & 15, quad = lane >> 4;
  int m0 = mb * 128;
  int n0 = blockIdx.y * 128;
  f32x4 acc[4][4] = {};
  for (int k0 = 0; k0 < 64; k0 += 32) {
    #pragma unroll
    for (int rep = 0; rep < 2; ++rep) {
      int s = tid + rep*256;
      int row = s >> 2, seg = s & 3;
      *(short8*)&As[row*40 + seg*8] =
          *(const short8*)(basis + (size_t)(m0 + row)*64 + k0 + seg*8);
      *(short8*)&Bs[row*40 + seg*8] =
          *(const short8*)(Bw + (size_t)(n0 + row)*64 + k0 + seg*8);
    }
    __syncthreads();
    short8 af[4], bf[4];
    #pragma unroll
    for (int mt = 0; mt < 4; ++mt)
      af[mt] = *(const short8*)&As[(wr*64 + mt*16 + col)*40 + quad*8];
    #pragma unroll
    for (int jt = 0; jt < 4; ++jt)
      bf[jt] = *(const short8*)&Bs[(wc*64 + jt*16 + col)*40 + quad*8];
    #pragma unroll
    for (int mt = 0; mt < 4; ++mt)
      #pragma unroll
      for (int jt = 0; jt < 4; ++jt)
        acc[mt][jt] = __builtin_amdgcn_mfma_f32_16x16x32_bf16(af[mt], bf[jt], acc[mt][jt], 0, 0, 0);
    __syncthreads();
  }
  #pragma unroll
  for (int jt = 0; jt < 4; ++jt) {
    int j = n0 + wc*64 + jt*16 + col;
    if (j >= WCOL) continue;
    float bj = (j < HD) ? b1all[(size_t)l*HD + j] : 0.0f;
    #pragma unroll
    for (int mt = 0; mt < 4; ++mt)
      #pragma unroll
      for (int r = 0; r < 4; ++r) {
        int row = m0 + wr*64 + mt*16 + quad*4 + r;
        short v = (j < HD) ? f2b(ssp_fast(acc[mt][jt][r] + bj)) : (short)0;
        outb[(size_t)row*WCOL + j] = v;
      }
  }
}

// ---------------- tabB: wtab_b[l] = bf16(ttab_all[l]@w2[l] + b2[l]); 128x128 tiles ----------------
__global__ __launch_bounds__(256) void tabB_k(const short* __restrict__ ttab_all,
    const short* __restrict__ nwall, const float* __restrict__ b2all,
    short* __restrict__ wtab_b) {
  const int MT = NKNOT/128;
  int l = blockIdx.x / MT;
  int mb = blockIdx.x - l*MT;
  const short* A  = ttab_all + (size_t)l*NKNOT*WCOL;
  const short* Bw = nwall + (size_t)(18 + l)*WROW*WCOL;   // kind=3 (w2)
  short* P = wtab_b + (size_t)l*NKNOT*HD;
  __shared__ __align__(16) short As[128*40];
  __shared__ __align__(16) short Bs[128*40];
  int tid = threadIdx.x;
  int lane = tid & 63, wv = tid >> 6;
  int wr = wv >> 1, wc = wv & 1;
  int col = lane & 15, quad = lane >> 4;
  int m0 = mb * 128;
  int n0 = blockIdx.y * 128;
  f32x4 acc[4][4] = {};
  for (int k0 = 0; k0 < WCOL; k0 += 32) {
    #pragma unroll
    for (int rep = 0; rep < 2; ++rep) {
      int s = tid + rep*256;
      int row = s >> 2, seg = s & 3;
      *(short8*)&As[row*40 + seg*8] =
          *(const short8*)(A + (size_t)(m0 + row)*WCOL + k0 + seg*8);
      *(short8*)&Bs[row*40 + seg*8] =
          *(const short8*)(Bw + (size_t)(n0 + row)*WCOL + k0 + seg*8);
    }
    __syncthreads();
    short8 af[4], bf[4];
    #pragma unroll
    for (int mt = 0; mt < 4; ++mt)
      af[mt] = *(const short8*)&As[(wr*64 + mt*16 + col)*40 + quad*8];
    #pragma unroll
    for (int jt = 0; jt < 4; ++jt)
      bf[jt] = *(const short8*)&Bs[(wc*64 + jt*16 + col)*40 + quad*8];
    #pragma unroll
    for (int mt = 0; mt < 4; ++mt)
      #pragma unroll
      for (int jt = 0; jt < 4; ++jt)
        acc[mt][jt] = __builtin_amdgcn_mfma_f32_16x16x32_bf16(af[mt], bf[jt], acc[mt][jt], 0, 0, 0);
    __syncthreads();
  }
  #pragma unroll
  for (int jt = 0; jt < 4; ++jt) {
    int j = n0 + wc*64 + jt*16 + col;
    if (j >= HD) continue;
    float bj = b2all[(size_t)l*HD + j];
    #pragma unroll
    for (int mt = 0; mt < 4; ++mt)
      #pragma unroll
      for (int r = 0; r < 4; ++r) {
        int row = m0 + wr*64 + mt*16 + quad*4 + r;
        P[(size_t)row*HD + j] = f2b(acc[mt][jt][r] + bj);
      }
  }
}

// ---------------- gather: msg_b[node] = bf16(sum_e C_e * Wtab(d_e) (.) x1[nbr_e]) ----------------
// wtab_b bf16 [NKNOT][600]; x1_b bf16 [NN][608]; 8B (4-col) loads, 192 thr (152 active)
__global__ __launch_bounds__(192) void gather_k(const short* __restrict__ tabb,
    const float* __restrict__ cval, const int* __restrict__ nbr,
    const float* __restrict__ dist, const short* __restrict__ x1b,
    short* __restrict__ msgb) {
  __shared__ float cvs[64];
  __shared__ int nbs[64];
  __shared__ int tix[64];
  __shared__ float tfr[64];
  int node = blockIdx.x, tid = threadIdx.x;
  if (tid < 64) {
    int e = node*KNB + tid;
    cvs[tid] = cval[e];
    nbs[tid] = nbr[e];
    float u = dist[e] * ((float)(NKNOT-1)/10.0f);
    int i = (int)u;
    if (i > NKNOT-2) i = NKNOT-2;
    tix[tid] = i;
    tfr[tid] = u - (float)i;
  }
  __syncthreads();
  int j = tid*4;
  if (j >= WCOL) return;
  if (j >= HD) {                   // j = 600 or 604: zero the bf16 pads (8B each)
    *(uint2*)&msgb[(size_t)node*WCOL + j] = make_uint2(0u, 0u);
    return;
  }
  float s[4] = {0.f, 0.f, 0.f, 0.f};
  #pragma unroll 4
  for (int e = 0; e < KNB; ++e) {
    float Ce = cvs[e];
    if (Ce == 0.0f) continue;
    const short* w0 = tabb + (size_t)tix[e]*HD + j;
    float f = tfr[e];
    uint2 wa = *(const uint2*)w0;
    uint2 wb = *(const uint2*)(w0 + HD);
    uint2 xv = *(const uint2*)(x1b + (size_t)nbs[e]*WCOL + j);
    float a0 = b2f(wa.x & 0xffffu), a1 = b2f(wa.x >> 16);
    float a2 = b2f(wa.y & 0xffffu), a3 = b2f(wa.y >> 16);
    float b0 = b2f(wb.x & 0xffffu), b1 = b2f(wb.x >> 16);
    float b2v = b2f(wb.y & 0xffffu), b3 = b2f(wb.y >> 16);
    float x0 = b2f(xv.x & 0xffffu), x1v = b2f(xv.x >> 16);
    float x2 = b2f(xv.y & 0xffffu), x3 = b2f(xv.y >> 16);
    s[0] += Ce * (a0 + f*(b0 - a0)) * x0;
    s[1] += Ce * (a1 + f*(b1 - a1)) * x1v;
    s[2] += Ce * (a2 + f*(b2v - a2)) * x2;
    s[3] += Ce * (a3 + f*(b3 - a3)) * x3;
  }
  uint2 pack;
  pack.x = (unsigned)(unsigned short)f2b(s[0]) | ((unsigned)(unsigned short)f2b(s[1]) << 16);
  pack.y = (unsigned)(unsigned short)f2b(s[2]) | ((unsigned)(unsigned short)f2b(s[3]) << 16);
  *(uint2*)&msgb[(size_t)node*WCOL + j] = pack;
}

// ---------------- fused node GEMM: 32x64 tile, single-barrier LDS double-buffer ----------------
// grid (32, 10). A bf16 [NN][WCOL], Bw bf16 [WROW][WCOL].
// MODE 0: outb = bf16(acc), pads zero               (x1 -> x1_b)
// MODE 1: outb = bf16(ssp(acc+bias)), pads zero     (lin2 -> mtmp_b)
// MODE 2: hacc += acc+bias; outb = bf16(hacc')      (int_lin residual -> h, h_b)
template<int MODE>
__global__ __launch_bounds__(256) void gemm_node_k(
    const short* __restrict__ A, const short* __restrict__ Bw,
    const float* __restrict__ bias, float* __restrict__ outf,
    short* __restrict__ outb, float* __restrict__ hacc) {
  __shared__ __align__(16) short As[2][32*40];
  __shared__ __align__(16) short Bs[2][64*40];
  int tid = threadIdx.x;
  int lane = tid & 63, wv = tid >> 6;
  int col = lane & 15, quad = lane >> 4;
  int m0 = blockIdx.x * 32;
  int n0 = blockIdx.y * 64;
  int ar = tid >> 3, aseg = tid & 7;   // A: 32 rows x 8 segs of 4 shorts
  int br = tid >> 2, bseg = tid & 3;   // B: 64 rows x 4 segs of 8 shorts
  const short* Aptr = A  + (size_t)(m0 + ar)*WCOL + aseg*4;
  const short* Bptr = Bw + (size_t)(n0 + br)*WCOL + bseg*8;
  f32x4 acc[2] = {};
  {
    short4v a0 = *(const short4v*)Aptr;
    short8  b0 = *(const short8*)Bptr;
    *(short4v*)&As[0][ar*40 + aseg*4] = a0;
    *(short8*)&Bs[0][br*40 + bseg*8] = b0;
  }
  __syncthreads();
  for (int kk = 0; kk < 19; ++kk) {
    int cur = kk & 1, nxt = cur ^ 1;
    short4v a_n; short8 b_n;
    if (kk < 18) {
      a_n = *(const short4v*)(Aptr + (kk + 1)*32);
      b_n = *(const short8*) (Bptr + (kk + 1)*32);
    }
    short8 bf = *(const short8*)&Bs[cur][(wv*16 + col)*40 + quad*8];
    #pragma unroll
    for (int mt = 0; mt < 2; ++mt) {
      short8 af = *(const short8*)&As[cur][(mt*16 + col)*40 + quad*8];
      acc[mt] = __builtin_amdgcn_mfma_f32_16x16x32_bf16(af, bf, acc[mt], 0, 0, 0);
    }
    if (kk < 18) {
      *(short4v*)&As[nxt][ar*40 + aseg*4] = a_n;
      *(short8*)&Bs[nxt][br*40 + bseg*8] = b_n;
    }
    __syncthreads();
  }
  int j = n0 + wv*16 + col;
  if (MODE == 0) {
    if (j < WCOL) {
      #pragma unroll
      for (int mt = 0; mt < 2; ++mt)
        #pragma unroll
        for (int r = 0; r < 4; ++r) {
          int row = m0 + mt*16 + quad*4 + r;
          outb[(size_t)row*WCOL + j] = (j < HD) ? f2b(acc[mt][r]) : (short)0;
        }
    }
  } else if (MODE == 1) {
    if (j < WCOL) {
      float bj = (j < HD) ? bias[j] : 0.0f;
      #pragma unroll
      for (int mt = 0; mt < 2; ++mt)
        #pragma unroll
        for (int r = 0; r < 4; ++r) {
          int row = m0 + mt*16 + quad*4 + r;
          outb[(size_t)row*WCOL + j] = (j < HD) ? f2b(ssp_fast(acc[mt][r] + bj)) : (short)0;
        }
    }
  } else {
    if (j < WCOL) {
      #pragma unroll
      for (int mt = 0; mt < 2; ++mt)
        #pragma unroll
        for (int r = 0; r < 4; ++r) {
          int row = m0 + mt*16 + quad*4 + r;
          if (j < HD) {
            float nv = hacc[(size_t)row*HD + j] + acc[mt][r] + bias[j];
            hacc[(size_t)row*HD + j] = nv;
            outb[(size_t)row*WCOL + j] = f2b(nv);
          } else {
            outb[(size_t)row*WCOL + j] = 0;
          }
        }
    }
  }
}

// ---------------- pooling + output ----------------
__global__ __launch_bounds__(256) void pool_mean_k(const float* __restrict__ h,
                                                   float* __restrict__ pooled) {
  int b = blockIdx.x;
  int c = blockIdx.y*256 + threadIdx.x;
  if (c >= HD) return;
  float s = 0.0f;
  for (int n = 0; n < NPG; ++n) s += h[(size_t)(b*NPG + n)*HD + c];
  pooled[(size_t)b*HD + c] = s * (1.0f/128.0f);
}

// grid (10, 8): 64 j per block, 4-way c-split, LDS reduce
__global__ __launch_bounds__(256) void pool_out_k(const float* __restrict__ pooled,
    const float* __restrict__ pw, const float* __restrict__ pb,
    float* __restrict__ out) {
  __shared__ float red[4][64];
  int b = blockIdx.y;
  int tid = threadIdx.x;
  int jl = tid & 63, q = tid >> 6;
  int j = blockIdx.x*64 + jl;
  float s = 0.0f;
  if (j < HD) {
    int c0 = q*150, c1 = c0 + 150;
    for (int c = c0; c < c1; ++c)
      s += pooled[(size_t)b*HD + c] * pw[(size_t)c*HD + j];
  }
  red[q][jl] = s;
  __syncthreads();
  if (q == 0 && j < HD)
    out[(size_t)b*HD + j] = red[0][jl] + red[1][jl] + red[2][jl] + red[3][jl] + pb[j];
}

// ---------------- launch ----------------
extern "C" void kernel_launch(void* const* d_in, const int* in_sizes, int n_in,
                              void* d_out, int out_size, void* d_ws, size_t ws_size,
                              hipStream_t stream) {
  const int*   z    = (const int*)d_in[0];
  const float* pos  = (const float*)d_in[1];
  const float* emb  = (const float*)d_in[2];
  const float* w1   = (const float*)d_in[3];
  const float* b1   = (const float*)d_in[4];
  const float* w2   = (const float*)d_in[5];
  const float* b2   = (const float*)d_in[6];
  const float* l1w  = (const float*)d_in[7];
  const float* l2w  = (const float*)d_in[8];
  const float* l2b  = (const float*)d_in[9];
  const float* ilw  = (const float*)d_in[10];
  const float* ilb  = (const float*)d_in[11];
  const float* pw   = (const float*)d_in[12];
  const float* pb   = (const float*)d_in[13];
  float* ws = (float*)d_ws;
  // workspace layout (float offsets) — total ~10.6M f = 42.4 MB
  int*   nbr   = (int*)ws;                   // 65536
  float* cv    = ws + 65536;                 // 65536
  float* dist  = ws + 131072;                // 65536
  float* pooled= ws + 196608;                // 8192
  float* h     = ws + 204800;                // 614400
  short* h_b   = (short*)(ws + 819200);      // 311296 f
  short* msg_b = (short*)(ws + 1130496);     // 311296 f
  short* mtmp_b= (short*)(ws + 1441792);     // 311296 f
  short* x1_b  = (short*)(ws + 1753088);     // 311296 f
  short* basis = (short*)(ws + 2064384);     // 1024*64 sh = 32768 f
  short* ttab  = (short*)(ws + 2097152);     // 6*1024*608 sh = 1867776 f
  short* wtab_b= (short*)(ws + 3964928);     // 6*1024*600 sh = 1843200 f
  short* w1b   = (short*)(ws + 5808128);     // 122880 f
  short* nwall = (short*)(ws + 5931008);     // 4669440 f
  float* out   = (float*)d_out;

  const size_t WSZ = (size_t)WROW*WCOL;

  build_graph_k<<<NN, 128, 0, stream>>>(pos, nbr, dist, cv);
  prep_k<<<(NKNOT*64 + LL*WROW*64 + 255)/256, 256, 0, stream>>>(w1, basis, w1b);
  conv_all_k<<<dim3(24, 10, 10), 256, 0, stream>>>(l1w, l2w, ilw, w2, nwall);
  embed_k<<<NN, 256, 0, stream>>>(z, emb, h, h_b);

  // batched W(d) tables for all layers
  tabA_k<<<dim3(LL*(NKNOT/128), 5), 256, 0, stream>>>(basis, w1b, b1, ttab);
  tabB_k<<<dim3(LL*(NKNOT/128), 5), 256, 0, stream>>>(ttab, nwall, b2, wtab_b);

  dim3 gn(32, 10);
  for (int l = 0; l < LL; ++l) {
    // x1_b = bf16(h @ lin1_w[l])
    gemm_node_k<0><<<gn, 256, 0, stream>>>(h_b, nwall + (size_t)(0*6 + l)*WSZ,
        nullptr, nullptr, x1_b, nullptr);
    // msg_b[node] = bf16(sum_e C_e * Wtab(d_e) (.) x1[nbr_e])
    gather_k<<<NN, 192, 0, stream>>>(wtab_b + (size_t)l*NKNOT*HD, cv, nbr, dist, x1_b, msg_b);
    // mtmp_b = bf16(ssp(msg @ lin2_w[l] + lin2_b[l]))
    gemm_node_k<1><<<gn, 256, 0, stream>>>(msg_b, nwall + (size_t)(1*6 + l)*WSZ,
        l2b + (size_t)l*HD, nullptr, mtmp_b, nullptr);
    // h += mtmp @ int_lin_w[l] + int_lin_b[l]; h_b = bf16(h)
    gemm_node_k<2><<<gn, 256, 0, stream>>>(mtmp_b, nwall + (size_t)(2*6 + l)*WSZ,
        ilb + (size_t)l*HD, nullptr, h_b, h);
  }
  pool_mean_k<<<dim3(NB, 3), 256, 0, stream>>>(h, pooled);
  pool_out_k<<<dim3(10, NB), 256, 0, stream>>>(pooled, pw, pb, out);
}